// Round 1
// baseline (477.894 us; speedup 1.0000x reference)
//
#include <hip/hip_runtime.h>
#include <hip/hip_bf16.h>
#include <cstdint>
#include <cstddef>

#define AS1 __attribute__((address_space(1)))
#define AS3 __attribute__((address_space(3)))

typedef __attribute__((ext_vector_type(8))) short bf16x8;
typedef __attribute__((ext_vector_type(4))) float f32x4;

__device__ __forceinline__ void gload_lds16(const void* g, void* l) {
  __builtin_amdgcn_global_load_lds((const AS1 void*)g, (AS3 void*)l, 16, 0, 0);
}

#define MFMA_BF16(A, B, C) __builtin_amdgcn_mfma_f32_16x16x32_bf16((A), (B), (C), 0, 0, 0)

// ---------------- cast f32 -> bf16 ----------------
__global__ __launch_bounds__(256) void cast_bf16_kernel(const float* __restrict__ in,
                                                        __hip_bfloat16* __restrict__ out,
                                                        int n4) {
  int i = blockIdx.x * 256 + threadIdx.x;
  if (i < n4) {
    float4 v = ((const float4*)in)[i];
    __hip_bfloat16* o = out + (size_t)i * 4;
    o[0] = __float2bfloat16(v.x);
    o[1] = __float2bfloat16(v.y);
    o[2] = __float2bfloat16(v.z);
    o[3] = __float2bfloat16(v.w);
  }
}

// ---------------- transpose + cast: out[c][r] = in[r][c] ----------------
// grid: (cols/32, rows/32), block (32,8). All dims multiples of 32.
__global__ __launch_bounds__(256) void transpose_cast_kernel(const float* __restrict__ in,
                                                             __hip_bfloat16* __restrict__ out,
                                                             int in_stride, int out_stride) {
  __shared__ float tile[32][33];
  int c0 = blockIdx.x * 32, r0 = blockIdx.y * 32;
  int tx = threadIdx.x, ty = threadIdx.y;
#pragma unroll
  for (int i = 0; i < 32; i += 8)
    tile[ty + i][tx] = in[(size_t)(r0 + ty + i) * in_stride + c0 + tx];
  __syncthreads();
#pragma unroll
  for (int i = 0; i < 32; i += 8)
    out[(size_t)(c0 + ty + i) * out_stride + r0 + tx] = __float2bfloat16(tile[tx][ty + i]);
}

// ---------------- bf16 GEMM: C(MxN,f32) = A(MxK) * Bt(NxK)^T ----------------
// m97 structure: 128x128 tile, BK=32, 4 waves (2x2), global_load_lds width 16.
__global__ __launch_bounds__(256) void gemm_bf16_kernel(const __hip_bfloat16* __restrict__ A,
                                                        const __hip_bfloat16* __restrict__ Bt,
                                                        float* __restrict__ C,
                                                        int M, int N, int K) {
  __shared__ __align__(16) __hip_bfloat16 As[128 * 32];
  __shared__ __align__(16) __hip_bfloat16 Bs[128 * 32];
  const int tid = threadIdx.x;
  const int lane = tid & 63;
  const int wid = tid >> 6;
  const int wm = wid >> 1, wn = wid & 1;
  const int ntile = N >> 7;
  const int tm = blockIdx.x / ntile, tn = blockIdx.x % ntile;
  const int row0 = tm << 7, col0 = tn << 7;

  const int fr = lane & 15;
  const int kg = (lane >> 4) * 8;

  f32x4 acc[4][4] = {};

  for (int k0 = 0; k0 < K; k0 += 32) {
    __syncthreads();
#pragma unroll
    for (int i = 0; i < 2; ++i) {
      int f = i * 256 + tid;
      int r = f >> 2, s = f & 3;
      gload_lds16(A + (size_t)(row0 + r) * K + k0 + s * 8,
                  (char*)As + (i * 256 + wid * 64) * 16);
      gload_lds16(Bt + (size_t)(col0 + r) * K + k0 + s * 8,
                  (char*)Bs + (i * 256 + wid * 64) * 16);
    }
    __syncthreads();
    bf16x8 af[4], bfr[4];
#pragma unroll
    for (int m = 0; m < 4; ++m)
      af[m] = *(const bf16x8*)(As + (wm * 64 + m * 16 + fr) * 32 + kg);
#pragma unroll
    for (int n = 0; n < 4; ++n)
      bfr[n] = *(const bf16x8*)(Bs + (wn * 64 + n * 16 + fr) * 32 + kg);
#pragma unroll
    for (int m = 0; m < 4; ++m)
#pragma unroll
      for (int n = 0; n < 4; ++n)
        acc[m][n] = MFMA_BF16(af[m], bfr[n], acc[m][n]);
  }

  const int cr = (lane >> 4) * 4;
#pragma unroll
  for (int m = 0; m < 4; ++m)
#pragma unroll
    for (int n = 0; n < 4; ++n) {
      int col = col0 + wn * 64 + n * 16 + fr;
#pragma unroll
      for (int r = 0; r < 4; ++r) {
        int row = row0 + wm * 64 + m * 16 + cr + r;
        C[(size_t)row * N + col] = acc[m][n][r];
      }
    }
}

// ---------------- RoPE + RMS, write q/k transposed to (B,Hx,T,HD) bf16 ----------------
// one wave per (b,t,head); tasks: j<16 -> q head j ; 16<=j<20 -> k head j-16
__global__ __launch_bounds__(256) void rope_rms_kernel(const float* __restrict__ qkv,
                                                       const float* __restrict__ cosb,
                                                       const float* __restrict__ sinb,
                                                       __hip_bfloat16* __restrict__ qT,
                                                       __hip_bfloat16* __restrict__ kT) {
  int lane = threadIdx.x & 63, wid = threadIdx.x >> 6;
  int task = blockIdx.x * 4 + wid;
  int bt = task / 20, j = task - bt * 20;
  int b = bt >> 11, t = bt & 2047;
  const float* src;
  __hip_bfloat16* dst;
  if (j < 16) {
    src = qkv + (size_t)bt * 3072 + j * 128;
    dst = qT + ((size_t)(b * 16 + j) * 2048 + t) * 128;
  } else {
    src = qkv + (size_t)bt * 3072 + 2048 + (j - 16) * 128;
    dst = kT + ((size_t)(b * 4 + (j - 16)) * 2048 + t) * 128;
  }
  float x1 = src[lane], x2 = src[lane + 64];
  float c = cosb[t * 64 + lane], s = sinb[t * 64 + lane];
  float o1 = x1 * c - x2 * s;
  float o2 = x1 * s + x2 * c;
  float ss = o1 * o1 + o2 * o2;
#pragma unroll
  for (int off = 1; off < 64; off <<= 1) ss += __shfl_xor(ss, off);
  float rn = rsqrtf(ss * (1.f / 128.f) + 1e-6f);
  dst[lane] = __float2bfloat16(o1 * rn);
  dst[lane + 64] = __float2bfloat16(o2 * rn);
}

// ---------------- attention pass 1: y1 = softmax(qk^T) v (flash, online) ----------------
// grid: B*H*(T/64); 4 waves, each owns 16 q rows. K/V staged in LDS (XOR-swizzled).
__global__ __launch_bounds__(256) void attn_pass1_kernel(
    const __hip_bfloat16* __restrict__ qT,   // (B,H,T,HD)
    const __hip_bfloat16* __restrict__ kT,   // (B,HK,T,HD)
    const __hip_bfloat16* __restrict__ vt,   // (B,HK,HD,T)
    __hip_bfloat16* __restrict__ y1n,        // (B,H,T,HD)
    __hip_bfloat16* __restrict__ y1t,        // (B,H,HD,T)
    float* __restrict__ Mb,                  // (B,H,T)
    float* __restrict__ Lb) {
  __shared__ __align__(16) __hip_bfloat16 Ks[64 * 128];
  __shared__ __align__(16) __hip_bfloat16 Vs[128 * 64];
  __shared__ __align__(16) __hip_bfloat16 Ps[4][16 * 64];
  const int tid = threadIdx.x, lane = tid & 63, wid = tid >> 6;
  const int qt = blockIdx.x & 31;
  const int bh = blockIdx.x >> 5;
  const int h = bh & 15, b = bh >> 4;
  const int kvh = h >> 2;
  const __hip_bfloat16* Qp = qT + ((size_t)bh * 2048 + qt * 64 + wid * 16) * 128;
  const __hip_bfloat16* Kp = kT + (size_t)(b * 4 + kvh) * 2048 * 128;
  const __hip_bfloat16* Vp = vt + (size_t)(b * 4 + kvh) * 128 * 2048;

  const int fr = lane & 15;
  const int kg = (lane >> 4) * 8;
  bf16x8 qf[4];
#pragma unroll
  for (int dc = 0; dc < 4; ++dc)
    qf[dc] = *(const bf16x8*)(Qp + fr * 128 + dc * 32 + kg);

  f32x4 accO[8] = {};
  float mrun[4], lrun[4];
#pragma unroll
  for (int r = 0; r < 4; ++r) { mrun[r] = -1e30f; lrun[r] = 0.f; }

  const float scale = 0.08838834764831845f;
  const int qg = qt * 64 + wid * 16 + (lane >> 4) * 4;
  __hip_bfloat16* Pw = Ps[wid];

  const int nkt = qt + 1;
  for (int kt = 0; kt < nkt; ++kt) {
    const int k0 = kt * 64;
    __syncthreads();
#pragma unroll
    for (int i = 0; i < 4; ++i) {   // K tile 64x128, swizzled source
      int f = i * 256 + tid;
      int r = f >> 4, s = f & 15, sx = s ^ (r & 7);
      gload_lds16(Kp + (size_t)(k0 + r) * 128 + sx * 8,
                  (char*)Ks + (i * 256 + wid * 64) * 16);
    }
#pragma unroll
    for (int i = 0; i < 4; ++i) {   // V^T tile 128x64, swizzled source
      int f = i * 256 + tid;
      int r = f >> 3, s = f & 7, sx = s ^ (r & 7);
      gload_lds16(Vp + (size_t)r * 2048 + k0 + sx * 8,
                  (char*)Vs + (i * 256 + wid * 64) * 16);
    }
    __syncthreads();

    f32x4 sf[4] = {};
#pragma unroll
    for (int c = 0; c < 4; ++c) {
      const int krow = c * 16 + fr;
#pragma unroll
      for (int dc = 0; dc < 4; ++dc) {
        int slot = (dc * 4 + (lane >> 4)) ^ (krow & 7);
        bf16x8 kf = *(const bf16x8*)((const char*)Ks + krow * 256 + slot * 16);
        sf[c] = MFMA_BF16(qf[dc], kf, sf[c]);
      }
    }

    float rmax[4];
#pragma unroll
    for (int r = 0; r < 4; ++r) rmax[r] = -1e30f;
#pragma unroll
    for (int c = 0; c < 4; ++c) {
      int kcol = k0 + c * 16 + fr;
#pragma unroll
      for (int r = 0; r < 4; ++r) {
        float sv = sf[c][r] * scale;
        sv = (kcol <= qg + r) ? sv : -1e30f;
        sf[c][r] = sv;
        rmax[r] = fmaxf(rmax[r], sv);
      }
    }
#pragma unroll
    for (int r = 0; r < 4; ++r) {
      float v = rmax[r];
      v = fmaxf(v, __shfl_xor(v, 1));
      v = fmaxf(v, __shfl_xor(v, 2));
      v = fmaxf(v, __shfl_xor(v, 4));
      v = fmaxf(v, __shfl_xor(v, 8));
      rmax[r] = v;
    }
    float alpha[4], rsum[4];
#pragma unroll
    for (int r = 0; r < 4; ++r) {
      float mnew = fmaxf(mrun[r], rmax[r]);
      alpha[r] = __expf(mrun[r] - mnew);
      mrun[r] = mnew;
      rsum[r] = 0.f;
    }
#pragma unroll
    for (int c = 0; c < 4; ++c)
#pragma unroll
      for (int r = 0; r < 4; ++r) {
        float p = __expf(sf[c][r] - mrun[r]);
        sf[c][r] = p;
        rsum[r] += p;
      }
#pragma unroll
    for (int r = 0; r < 4; ++r) {
      float v = rsum[r];
      v += __shfl_xor(v, 1);
      v += __shfl_xor(v, 2);
      v += __shfl_xor(v, 4);
      v += __shfl_xor(v, 8);
      lrun[r] = lrun[r] * alpha[r] + v;
    }
#pragma unroll
    for (int f = 0; f < 8; ++f)
#pragma unroll
      for (int r = 0; r < 4; ++r) accO[f][r] *= alpha[r];

    // P -> LDS (bf16, swizzled), wave-local
#pragma unroll
    for (int c = 0; c < 4; ++c) {
      int col = c * 16 + fr;
      int sseg = col >> 3;
#pragma unroll
      for (int r = 0; r < 4; ++r) {
        int prow = (lane >> 4) * 4 + r;
        int slot = sseg ^ (prow & 7);
        Pw[prow * 64 + slot * 8 + (col & 7)] = __float2bfloat16(sf[c][r]);
      }
    }
    // accO += P @ V
#pragma unroll
    for (int kc = 0; kc < 2; ++kc) {
      int slot = (kc * 4 + (lane >> 4)) ^ (fr & 7);
      bf16x8 pf = *(const bf16x8*)(Pw + fr * 64 + slot * 8);
#pragma unroll
      for (int f = 0; f < 8; ++f) {
        int vrow = f * 16 + fr;
        int vslot = (kc * 4 + (lane >> 4)) ^ (vrow & 7);
        bf16x8 vf = *(const bf16x8*)(Vs + vrow * 64 + vslot * 8);
        accO[f] = MFMA_BF16(pf, vf, accO[f]);
      }
    }
  }

  float rl[4];
#pragma unroll
  for (int r = 0; r < 4; ++r) rl[r] = 1.f / lrun[r];
  const size_t qbase = (size_t)bh * 2048 + qt * 64 + wid * 16;
#pragma unroll
  for (int f = 0; f < 8; ++f) {
    int d = f * 16 + fr;
#pragma unroll
    for (int r = 0; r < 4; ++r) {
      int ql = (lane >> 4) * 4 + r;
      __hip_bfloat16 yb = __float2bfloat16(accO[f][r] * rl[r]);
      y1n[(qbase + ql) * 128 + d] = yb;
      y1t[((size_t)bh * 128 + d) * 2048 + qt * 64 + wid * 16 + ql] = yb;
    }
  }
  if (fr == 0) {
#pragma unroll
    for (int r = 0; r < 4; ++r) {
      int ql = (lane >> 4) * 4 + r;
      Mb[qbase + ql] = mrun[r];
      Lb[qbase + ql] = lrun[r];
    }
  }
}

// ---------------- attention pass 2: y2 = att @ y1 ; ymix = mix1*y1 + mix2*y2 ----------------
__global__ __launch_bounds__(256) void attn_pass2_kernel(
    const __hip_bfloat16* __restrict__ qT,
    const __hip_bfloat16* __restrict__ kT,
    const __hip_bfloat16* __restrict__ y1t,  // (B,H,HD,T)
    const __hip_bfloat16* __restrict__ y1n,  // (B,H,T,HD)
    const float* __restrict__ Mb,
    const float* __restrict__ Lb,
    const float* __restrict__ mix1p,
    const float* __restrict__ mix2p,
    __hip_bfloat16* __restrict__ ymix) {     // (B,T,C)
  __shared__ __align__(16) __hip_bfloat16 Ks[64 * 128];
  __shared__ __align__(16) __hip_bfloat16 Vs[128 * 64];
  __shared__ __align__(16) __hip_bfloat16 Ps[4][16 * 64];
  const int tid = threadIdx.x, lane = tid & 63, wid = tid >> 6;
  const int qt = blockIdx.x & 31;
  const int bh = blockIdx.x >> 5;
  const int h = bh & 15, b = bh >> 4;
  const int kvh = h >> 2;
  const __hip_bfloat16* Qp = qT + ((size_t)bh * 2048 + qt * 64 + wid * 16) * 128;
  const __hip_bfloat16* Kp = kT + (size_t)(b * 4 + kvh) * 2048 * 128;
  const __hip_bfloat16* Yp = y1t + (size_t)bh * 128 * 2048;

  const int fr = lane & 15;
  const int kg = (lane >> 4) * 8;
  bf16x8 qf[4];
#pragma unroll
  for (int dc = 0; dc < 4; ++dc)
    qf[dc] = *(const bf16x8*)(Qp + fr * 128 + dc * 32 + kg);

  const size_t qbase = (size_t)bh * 2048 + qt * 64 + wid * 16;
  float mrow[4], rlrow[4];
#pragma unroll
  for (int r = 0; r < 4; ++r) {
    int ql = (lane >> 4) * 4 + r;
    mrow[r] = Mb[qbase + ql];
    rlrow[r] = 1.f / Lb[qbase + ql];
  }

  f32x4 accO[8] = {};
  const float scale = 0.08838834764831845f;
  const int qg = qt * 64 + wid * 16 + (lane >> 4) * 4;
  __hip_bfloat16* Pw = Ps[wid];

  const int nkt = qt + 1;
  for (int kt = 0; kt < nkt; ++kt) {
    const int k0 = kt * 64;
    __syncthreads();
#pragma unroll
    for (int i = 0; i < 4; ++i) {
      int f = i * 256 + tid;
      int r = f >> 4, s = f & 15, sx = s ^ (r & 7);
      gload_lds16(Kp + (size_t)(k0 + r) * 128 + sx * 8,
                  (char*)Ks + (i * 256 + wid * 64) * 16);
    }
#pragma unroll
    for (int i = 0; i < 4; ++i) {
      int f = i * 256 + tid;
      int r = f >> 3, s = f & 7, sx = s ^ (r & 7);
      gload_lds16(Yp + (size_t)r * 2048 + k0 + sx * 8,
                  (char*)Vs + (i * 256 + wid * 64) * 16);
    }
    __syncthreads();

    f32x4 sf[4] = {};
#pragma unroll
    for (int c = 0; c < 4; ++c) {
      const int krow = c * 16 + fr;
#pragma unroll
      for (int dc = 0; dc < 4; ++dc) {
        int slot = (dc * 4 + (lane >> 4)) ^ (krow & 7);
        bf16x8 kf = *(const bf16x8*)((const char*)Ks + krow * 256 + slot * 16);
        sf[c] = MFMA_BF16(qf[dc], kf, sf[c]);
      }
    }
#pragma unroll
    for (int c = 0; c < 4; ++c) {
      int kcol = k0 + c * 16 + fr;
      int col = c * 16 + fr;
      int sseg = col >> 3;
#pragma unroll
      for (int r = 0; r < 4; ++r) {
        float p = (kcol <= qg + r) ? __expf(sf[c][r] * scale - mrow[r]) * rlrow[r] : 0.f;
        int prow = (lane >> 4) * 4 + r;
        int slot = sseg ^ (prow & 7);
        Pw[prow * 64 + slot * 8 + (col & 7)] = __float2bfloat16(p);
      }
    }
#pragma unroll
    for (int kc = 0; kc < 2; ++kc) {
      int slot = (kc * 4 + (lane >> 4)) ^ (fr & 7);
      bf16x8 pf = *(const bf16x8*)(Pw + fr * 64 + slot * 8);
#pragma unroll
      for (int f = 0; f < 8; ++f) {
        int vrow = f * 16 + fr;
        int vslot = (kc * 4 + (lane >> 4)) ^ (vrow & 7);
        bf16x8 vf = *(const bf16x8*)(Vs + vrow * 64 + vslot * 8);
        accO[f] = MFMA_BF16(pf, vf, accO[f]);
      }
    }
  }

  const float m1 = *mix1p, m2 = *mix2p;
#pragma unroll
  for (int f = 0; f < 8; ++f) {
    int d = f * 16 + fr;
#pragma unroll
    for (int r = 0; r < 4; ++r) {
      int ql = (lane >> 4) * 4 + r;
      float y1v = __bfloat162float(y1n[(qbase + ql) * 128 + d]);
      float yv = m1 * y1v + m2 * accO[f][r];
      int q = qt * 64 + wid * 16 + ql;
      ymix[((size_t)b * 2048 + q) * 2048 + h * 128 + d] = __float2bfloat16(yv);
    }
  }
}

// ---------------- launch ----------------
extern "C" void kernel_launch(void* const* d_in, const int* in_sizes, int n_in,
                              void* d_out, int out_size, void* d_ws, size_t ws_size,
                              hipStream_t stream) {
  const float* x    = (const float*)d_in[0];
  const float* cosb = (const float*)d_in[1];
  const float* sinb = (const float*)d_in[2];
  const float* Wq   = (const float*)d_in[3];
  const float* Wk   = (const float*)d_in[4];
  const float* Wv   = (const float*)d_in[5];
  const float* Wp   = (const float*)d_in[6];
  const float* mix1 = (const float*)d_in[7];
  const float* mix2 = (const float*)d_in[8];
  float* out = (float*)d_out;
  char* ws = (char*)d_ws;

  // workspace layout (bytes); peak 113,246,208 (108 MiB)
  __hip_bfloat16* xb   = (__hip_bfloat16*)(ws + 0);           // 16.78 MB, reused as ymix
  __hip_bfloat16* WTa  = (__hip_bfloat16*)(ws + 16777216);    // 12.58 MB (3072x2048)
  __hip_bfloat16* WpT  = (__hip_bfloat16*)(ws + 29360128);    // 8.39 MB
  float*          qkv  = (float*)(ws + 37748736);             // 50.33 MB (4096x3072 f32)
  __hip_bfloat16* y1n  = (__hip_bfloat16*)(ws + 37748736);    // reuse qkv after rope/v-transpose
  __hip_bfloat16* y1t  = (__hip_bfloat16*)(ws + 54525952);
  float*          Mb   = (float*)(ws + 71303168);
  float*          Lb   = (float*)(ws + 71565312);
  __hip_bfloat16* qTb  = (__hip_bfloat16*)(ws + 88080384);    // (B,H,T,HD)
  __hip_bfloat16* kTb  = (__hip_bfloat16*)(ws + 104857600);   // (B,HK,T,HD)
  __hip_bfloat16* vtb  = (__hip_bfloat16*)(ws + 109051904);   // (B,HK,HD,T)
  __hip_bfloat16* ymix = (__hip_bfloat16*)(ws + 0);

  dim3 tb(32, 8);
  // casts / weight transposes
  cast_bf16_kernel<<<8192, 256, 0, stream>>>(x, xb, 2097152);
  transpose_cast_kernel<<<dim3(64, 64), tb, 0, stream>>>(Wq, WTa, 2048, 2048);
  transpose_cast_kernel<<<dim3(16, 64), tb, 0, stream>>>(Wk, WTa + (size_t)2048 * 2048, 512, 2048);
  transpose_cast_kernel<<<dim3(16, 64), tb, 0, stream>>>(Wv, WTa + (size_t)2560 * 2048, 512, 2048);
  transpose_cast_kernel<<<dim3(64, 64), tb, 0, stream>>>(Wp, WpT, 2048, 2048);

  // fused QKV projection: (4096x2048) @ (2048x3072) -> qkv f32
  gemm_bf16_kernel<<<32 * 24, 256, 0, stream>>>(xb, WTa, qkv, 4096, 3072, 2048);

  // rope+rms for q,k ; v transposed to (B,HK,HD,T)
  rope_rms_kernel<<<20480, 256, 0, stream>>>(qkv, cosb, sinb, qTb, kTb);
  transpose_cast_kernel<<<dim3(16, 64), tb, 0, stream>>>(qkv + 2560, vtb, 3072, 2048);
  transpose_cast_kernel<<<dim3(16, 64), tb, 0, stream>>>(qkv + (size_t)2048 * 3072 + 2560,
                                                         vtb + (size_t)512 * 2048, 3072, 2048);

  // attention
  attn_pass1_kernel<<<1024, 256, 0, stream>>>(qTb, kTb, vtb, y1n, y1t, Mb, Lb);
  attn_pass2_kernel<<<1024, 256, 0, stream>>>(qTb, kTb, y1t, y1n, Mb, Lb, mix1, mix2, ymix);

  // output projection -> d_out (f32)
  gemm_bf16_kernel<<<32 * 16, 256, 0, stream>>>(ymix, WpT, out, 4096, 2048, 2048);
}

// Round 2
// 399.837 us; speedup vs baseline: 1.1952x; 1.1952x over previous
//
#include <hip/hip_runtime.h>
#include <hip/hip_bf16.h>
#include <cstdint>
#include <cstddef>

#define AS1 __attribute__((address_space(1)))
#define AS3 __attribute__((address_space(3)))

typedef __attribute__((ext_vector_type(8))) short bf16x8;
typedef __attribute__((ext_vector_type(4))) float f32x4;

__device__ __forceinline__ void gload_lds16(const void* g, void* l) {
  __builtin_amdgcn_global_load_lds((const AS1 void*)g, (AS3 void*)l, 16, 0, 0);
}

#define MFMA_BF16(A, B, C) __builtin_amdgcn_mfma_f32_16x16x32_bf16((A), (B), (C), 0, 0, 0)

// (1/sqrt(128)) * log2(e) — folded into q at rope time; softmax runs in exp2 domain.
#define QSCALE 0.12751744f

// ---------------- cast f32 -> bf16 ----------------
__global__ __launch_bounds__(256) void cast_bf16_kernel(const float* __restrict__ in,
                                                        __hip_bfloat16* __restrict__ out,
                                                        int n4) {
  int i = blockIdx.x * 256 + threadIdx.x;
  if (i < n4) {
    float4 v = ((const float4*)in)[i];
    __hip_bfloat16* o = out + (size_t)i * 4;
    o[0] = __float2bfloat16(v.x);
    o[1] = __float2bfloat16(v.y);
    o[2] = __float2bfloat16(v.z);
    o[3] = __float2bfloat16(v.w);
  }
}

// ---------------- transpose + cast: out[c][r] = in[r][c] ----------------
__global__ __launch_bounds__(256) void transpose_cast_kernel(const float* __restrict__ in,
                                                             __hip_bfloat16* __restrict__ out,
                                                             int in_stride, int out_stride) {
  __shared__ float tile[32][33];
  int c0 = blockIdx.x * 32, r0 = blockIdx.y * 32;
  int tx = threadIdx.x, ty = threadIdx.y;
#pragma unroll
  for (int i = 0; i < 32; i += 8)
    tile[ty + i][tx] = in[(size_t)(r0 + ty + i) * in_stride + c0 + tx];
  __syncthreads();
#pragma unroll
  for (int i = 0; i < 32; i += 8)
    out[(size_t)(c0 + ty + i) * out_stride + r0 + tx] = __float2bfloat16(tile[tx][ty + i]);
}

// ---------------- bf16 GEMM (m97 structure) ----------------
__global__ __launch_bounds__(256) void gemm_bf16_kernel(const __hip_bfloat16* __restrict__ A,
                                                        const __hip_bfloat16* __restrict__ Bt,
                                                        float* __restrict__ C,
                                                        int M, int N, int K) {
  __shared__ __align__(16) __hip_bfloat16 As[128 * 32];
  __shared__ __align__(16) __hip_bfloat16 Bs[128 * 32];
  const int tid = threadIdx.x;
  const int lane = tid & 63;
  const int wid = tid >> 6;
  const int wm = wid >> 1, wn = wid & 1;
  const int ntile = N >> 7;
  const int tm = blockIdx.x / ntile, tn = blockIdx.x % ntile;
  const int row0 = tm << 7, col0 = tn << 7;

  const int fr = lane & 15;
  const int kg = (lane >> 4) * 8;

  f32x4 acc[4][4] = {};

  for (int k0 = 0; k0 < K; k0 += 32) {
    __syncthreads();
#pragma unroll
    for (int i = 0; i < 2; ++i) {
      int f = i * 256 + tid;
      int r = f >> 2, s = f & 3;
      gload_lds16(A + (size_t)(row0 + r) * K + k0 + s * 8,
                  (char*)As + (i * 256 + wid * 64) * 16);
      gload_lds16(Bt + (size_t)(col0 + r) * K + k0 + s * 8,
                  (char*)Bs + (i * 256 + wid * 64) * 16);
    }
    __syncthreads();
    bf16x8 af[4], bfr[4];
#pragma unroll
    for (int m = 0; m < 4; ++m)
      af[m] = *(const bf16x8*)(As + (wm * 64 + m * 16 + fr) * 32 + kg);
#pragma unroll
    for (int n = 0; n < 4; ++n)
      bfr[n] = *(const bf16x8*)(Bs + (wn * 64 + n * 16 + fr) * 32 + kg);
#pragma unroll
    for (int m = 0; m < 4; ++m)
#pragma unroll
      for (int n = 0; n < 4; ++n)
        acc[m][n] = MFMA_BF16(af[m], bfr[n], acc[m][n]);
  }

  const int cr = (lane >> 4) * 4;
#pragma unroll
  for (int m = 0; m < 4; ++m)
#pragma unroll
    for (int n = 0; n < 4; ++n) {
      int col = col0 + wn * 64 + n * 16 + fr;
#pragma unroll
      for (int r = 0; r < 4; ++r) {
        int row = row0 + wm * 64 + m * 16 + cr + r;
        C[(size_t)row * N + col] = acc[m][n][r];
      }
    }
}

// ---------------- RoPE + RMS; q gets QSCALE folded in ----------------
__global__ __launch_bounds__(256) void rope_rms_kernel(const float* __restrict__ qkv,
                                                       const float* __restrict__ cosb,
                                                       const float* __restrict__ sinb,
                                                       __hip_bfloat16* __restrict__ qT,
                                                       __hip_bfloat16* __restrict__ kT) {
  int lane = threadIdx.x & 63, wid = threadIdx.x >> 6;
  int task = blockIdx.x * 4 + wid;
  int bt = task / 20, j = task - bt * 20;
  int b = bt >> 11, t = bt & 2047;
  const float* src;
  __hip_bfloat16* dst;
  float oscale;
  if (j < 16) {
    src = qkv + (size_t)bt * 3072 + j * 128;
    dst = qT + ((size_t)(b * 16 + j) * 2048 + t) * 128;
    oscale = QSCALE;
  } else {
    src = qkv + (size_t)bt * 3072 + 2048 + (j - 16) * 128;
    dst = kT + ((size_t)(b * 4 + (j - 16)) * 2048 + t) * 128;
    oscale = 1.0f;
  }
  float x1 = src[lane], x2 = src[lane + 64];
  float c = cosb[t * 64 + lane], s = sinb[t * 64 + lane];
  float o1 = x1 * c - x2 * s;
  float o2 = x1 * s + x2 * c;
  float ss = o1 * o1 + o2 * o2;
#pragma unroll
  for (int off = 1; off < 64; off <<= 1) ss += __shfl_xor(ss, off);
  float rn = rsqrtf(ss * (1.f / 128.f) + 1e-6f) * oscale;
  dst[lane] = __float2bfloat16(o1 * rn);
  dst[lane + 64] = __float2bfloat16(o2 * rn);
}

// ---------------- attention pass 1 ----------------
// grid: B*H*16 = 512 blocks. Block handles q-tiles (pi, 31-pi): 33 k-tiles, balanced.
// Double-buffered K/V LDS, prefetch-before-compute, one __syncthreads per tile.
__global__ __launch_bounds__(256) void attn_pass1_kernel(
    const __hip_bfloat16* __restrict__ qT,   // (B,H,T,HD), q pre-scaled
    const __hip_bfloat16* __restrict__ kT,   // (B,HK,T,HD)
    const __hip_bfloat16* __restrict__ vt,   // (B,HK,HD,T)
    __hip_bfloat16* __restrict__ y1n,        // (B,H,T,HD)
    __hip_bfloat16* __restrict__ y1t,        // (B,H,HD,T)
    float* __restrict__ Mb,                  // (B,H,T)  (exp2 domain)
    float* __restrict__ Lb) {
  __shared__ __align__(16) __hip_bfloat16 Ks[2][64 * 128];
  __shared__ __align__(16) __hip_bfloat16 Vs[2][128 * 64];
  __shared__ __align__(16) __hip_bfloat16 Ps[4][16 * 64];
  const int tid = threadIdx.x, lane = tid & 63, wid = tid >> 6;
  const int pi = blockIdx.x & 15;
  const int bh = blockIdx.x >> 4;
  const int h = bh & 15, b = bh >> 4;
  const int kvh = h >> 2;
  const int qtA = pi, qtB = 31 - pi;
  const int ntA = qtA + 1;
  const __hip_bfloat16* Kp = kT + (size_t)(b * 4 + kvh) * 2048 * 128;
  const __hip_bfloat16* Vp = vt + (size_t)(b * 4 + kvh) * 128 * 2048;
  const int fr = lane & 15, hi = lane >> 4;
  const int kg = hi * 8;

  bf16x8 qfA[4], qfB[4];
  {
    const __hip_bfloat16* QA = qT + ((size_t)bh * 2048 + qtA * 64 + wid * 16) * 128;
#pragma unroll
    for (int dc = 0; dc < 4; ++dc)
      qfA[dc] = *(const bf16x8*)(QA + fr * 128 + dc * 32 + kg);
  }

  f32x4 accO[8] = {};
  float m[4], l[4];
#pragma unroll
  for (int r = 0; r < 4; ++r) { m[r] = -1e30f; l[r] = 0.f; }

  __hip_bfloat16* Pw = Ps[wid];

  auto STAGE = [&](int buf, int kt) {
    const int k0 = kt * 64;
#pragma unroll
    for (int i = 0; i < 4; ++i) {
      int f = i * 256 + tid;
      int r = f >> 4, s = f & 15, sx = s ^ (r & 7);
      gload_lds16(Kp + (size_t)(k0 + r) * 128 + sx * 8,
                  (char*)Ks[buf] + (i * 256 + wid * 64) * 16);
    }
#pragma unroll
    for (int i = 0; i < 4; ++i) {
      int f = i * 256 + tid;
      int r = f >> 3, s = f & 7, sx = s ^ (r & 7);
      gload_lds16(Vp + (size_t)r * 2048 + k0 + sx * 8,
                  (char*)Vs[buf] + (i * 256 + wid * 64) * 16);
    }
  };

  auto compute = [&](const bf16x8 (&qf)[4], int kt, int qt, int cur) {
    const char* Kc = (const char*)Ks[cur];
    const __hip_bfloat16* Vc = Vs[cur];
    f32x4 sf[4] = {};
#pragma unroll
    for (int c = 0; c < 4; ++c) {
      const int krow = c * 16 + fr;
#pragma unroll
      for (int dc = 0; dc < 4; ++dc) {
        int slot = (dc * 4 + hi) ^ (krow & 7);
        bf16x8 kf = *(const bf16x8*)(Kc + krow * 256 + slot * 16);
        sf[c] = MFMA_BF16(qf[dc], kf, sf[c]);
      }
    }
    float rmax[4];
#pragma unroll
    for (int r = 0; r < 4; ++r) rmax[r] = -1e30f;
    if (kt == qt) {
      const int qg = qt * 64 + wid * 16 + hi * 4;
#pragma unroll
      for (int c = 0; c < 4; ++c) {
        int kcol = kt * 64 + c * 16 + fr;
#pragma unroll
        for (int r = 0; r < 4; ++r) {
          float sv = (kcol <= qg + r) ? sf[c][r] : -1e30f;
          sf[c][r] = sv;
          rmax[r] = fmaxf(rmax[r], sv);
        }
      }
    } else {
#pragma unroll
      for (int c = 0; c < 4; ++c)
#pragma unroll
        for (int r = 0; r < 4; ++r) rmax[r] = fmaxf(rmax[r], sf[c][r]);
    }
#pragma unroll
    for (int r = 0; r < 4; ++r) {
      float v = rmax[r];
      v = fmaxf(v, __shfl_xor(v, 1));
      v = fmaxf(v, __shfl_xor(v, 2));
      v = fmaxf(v, __shfl_xor(v, 4));
      v = fmaxf(v, __shfl_xor(v, 8));
      rmax[r] = v;
    }
    bool grow = (rmax[0] > m[0]) | (rmax[1] > m[1]) | (rmax[2] > m[2]) | (rmax[3] > m[3]);
    if (__any(grow)) {   // exact: when skipped, alpha==1 for every row
#pragma unroll
      for (int r = 0; r < 4; ++r) {
        float mn = fmaxf(m[r], rmax[r]);
        float a = __builtin_amdgcn_exp2f(m[r] - mn);
        m[r] = mn;
        l[r] *= a;
#pragma unroll
        for (int f = 0; f < 8; ++f) accO[f][r] *= a;
      }
    }
    float rsum[4] = {0.f, 0.f, 0.f, 0.f};
#pragma unroll
    for (int c = 0; c < 4; ++c)
#pragma unroll
      for (int r = 0; r < 4; ++r) {
        float p = __builtin_amdgcn_exp2f(sf[c][r] - m[r]);
        sf[c][r] = p;
        rsum[r] += p;
      }
#pragma unroll
    for (int r = 0; r < 4; ++r) {
      float v = rsum[r];
      v += __shfl_xor(v, 1);
      v += __shfl_xor(v, 2);
      v += __shfl_xor(v, 4);
      v += __shfl_xor(v, 8);
      l[r] += v;
    }
    // P -> LDS (bf16, swizzled), wave-local
#pragma unroll
    for (int c = 0; c < 4; ++c) {
      int col = c * 16 + fr;
      int sseg = col >> 3;
#pragma unroll
      for (int r = 0; r < 4; ++r) {
        int prow = hi * 4 + r;
        int slot = sseg ^ (prow & 7);
        Pw[prow * 64 + slot * 8 + (col & 7)] = __float2bfloat16(sf[c][r]);
      }
    }
#pragma unroll
    for (int kc = 0; kc < 2; ++kc) {
      int slot = (kc * 4 + hi) ^ (fr & 7);
      bf16x8 pf = *(const bf16x8*)(Pw + fr * 64 + slot * 8);
#pragma unroll
      for (int f = 0; f < 8; ++f) {
        int vrow = f * 16 + fr;
        int vslot = (kc * 4 + hi) ^ (vrow & 7);
        bf16x8 vf = *(const bf16x8*)(Vc + vrow * 64 + vslot * 8);
        accO[f] = MFMA_BF16(pf, vf, accO[f]);
      }
    }
  };

  auto epilogue = [&](int qt) {
    float rl[4];
#pragma unroll
    for (int r = 0; r < 4; ++r) rl[r] = 1.f / l[r];
    const size_t qb = (size_t)bh * 2048 + qt * 64 + wid * 16;
#pragma unroll
    for (int f = 0; f < 8; ++f) {
      int d = f * 16 + fr;
#pragma unroll
      for (int r = 0; r < 4; ++r) {
        int ql = hi * 4 + r;
        __hip_bfloat16 yb = __float2bfloat16(accO[f][r] * rl[r]);
        y1n[(qb + ql) * 128 + d] = yb;
        y1t[((size_t)bh * 128 + d) * 2048 + qt * 64 + wid * 16 + ql] = yb;
      }
    }
    if (fr == 0) {
#pragma unroll
      for (int r = 0; r < 4; ++r) {
        Mb[qb + hi * 4 + r] = m[r];
        Lb[qb + hi * 4 + r] = l[r];
      }
    }
  };

  STAGE(0, 0);
  __syncthreads();
  int cur = 0;
  const int nsteps = 33;
  for (int s = 0; s < nsteps; ++s) {
    int snext = s + 1;
    if (snext < nsteps) STAGE(cur ^ 1, (snext < ntA) ? snext : snext - ntA);
    __builtin_amdgcn_sched_barrier(0);
    if (s < ntA) {
      compute(qfA, s, qtA, cur);
      if (s == ntA - 1) {
        epilogue(qtA);
#pragma unroll
        for (int f = 0; f < 8; ++f)
#pragma unroll
          for (int r = 0; r < 4; ++r) accO[f][r] = 0.f;
#pragma unroll
        for (int r = 0; r < 4; ++r) { m[r] = -1e30f; l[r] = 0.f; }
        const __hip_bfloat16* QB = qT + ((size_t)bh * 2048 + qtB * 64 + wid * 16) * 128;
#pragma unroll
        for (int dc = 0; dc < 4; ++dc)
          qfB[dc] = *(const bf16x8*)(QB + fr * 128 + dc * 32 + kg);
      }
    } else {
      compute(qfB, s - ntA, qtB, cur);
      if (s == nsteps - 1) epilogue(qtB);
    }
    __syncthreads();
    cur ^= 1;
  }
}

// ---------------- attention pass 2: y2 = att @ y1 ; ymix = mix1*y1 + mix2*y2 ----------------
__global__ __launch_bounds__(256) void attn_pass2_kernel(
    const __hip_bfloat16* __restrict__ qT,
    const __hip_bfloat16* __restrict__ kT,
    const __hip_bfloat16* __restrict__ y1t,  // (B,H,HD,T)
    const __hip_bfloat16* __restrict__ y1n,  // (B,H,T,HD)
    const float* __restrict__ Mb,
    const float* __restrict__ Lb,
    const float* __restrict__ mix1p,
    const float* __restrict__ mix2p,
    __hip_bfloat16* __restrict__ ymix) {     // (B,T,C)
  __shared__ __align__(16) __hip_bfloat16 Ks[2][64 * 128];
  __shared__ __align__(16) __hip_bfloat16 Vs[2][128 * 64];
  __shared__ __align__(16) __hip_bfloat16 Ps[4][16 * 64];
  const int tid = threadIdx.x, lane = tid & 63, wid = tid >> 6;
  const int pi = blockIdx.x & 15;
  const int bh = blockIdx.x >> 4;
  const int h = bh & 15, b = bh >> 4;
  const int kvh = h >> 2;
  const int qtA = pi, qtB = 31 - pi;
  const int ntA = qtA + 1;
  const __hip_bfloat16* Kp = kT + (size_t)(b * 4 + kvh) * 2048 * 128;
  const __hip_bfloat16* Yp = y1t + (size_t)bh * 128 * 2048;
  const int fr = lane & 15, hi = lane >> 4;
  const int kg = hi * 8;

  bf16x8 qfA[4], qfB[4];
  float mA[4], rlA[4], mB[4], rlB[4];
  {
    const __hip_bfloat16* QA = qT + ((size_t)bh * 2048 + qtA * 64 + wid * 16) * 128;
#pragma unroll
    for (int dc = 0; dc < 4; ++dc)
      qfA[dc] = *(const bf16x8*)(QA + fr * 128 + dc * 32 + kg);
    const size_t qbA = (size_t)bh * 2048 + qtA * 64 + wid * 16;
#pragma unroll
    for (int r = 0; r < 4; ++r) {
      mA[r] = Mb[qbA + hi * 4 + r];
      rlA[r] = 1.f / Lb[qbA + hi * 4 + r];
    }
  }

  f32x4 accO[8] = {};
  __hip_bfloat16* Pw = Ps[wid];

  auto STAGE = [&](int buf, int kt) {
    const int k0 = kt * 64;
#pragma unroll
    for (int i = 0; i < 4; ++i) {
      int f = i * 256 + tid;
      int r = f >> 4, s = f & 15, sx = s ^ (r & 7);
      gload_lds16(Kp + (size_t)(k0 + r) * 128 + sx * 8,
                  (char*)Ks[buf] + (i * 256 + wid * 64) * 16);
    }
#pragma unroll
    for (int i = 0; i < 4; ++i) {
      int f = i * 256 + tid;
      int r = f >> 3, s = f & 7, sx = s ^ (r & 7);
      gload_lds16(Yp + (size_t)r * 2048 + k0 + sx * 8,
                  (char*)Vs[buf] + (i * 256 + wid * 64) * 16);
    }
  };

  auto compute = [&](const bf16x8 (&qf)[4], const float (&mr)[4], const float (&rl)[4],
                     int kt, int qt, int cur) {
    const char* Kc = (const char*)Ks[cur];
    const __hip_bfloat16* Vc = Vs[cur];
    f32x4 sf[4] = {};
#pragma unroll
    for (int c = 0; c < 4; ++c) {
      const int krow = c * 16 + fr;
#pragma unroll
      for (int dc = 0; dc < 4; ++dc) {
        int slot = (dc * 4 + hi) ^ (krow & 7);
        bf16x8 kf = *(const bf16x8*)(Kc + krow * 256 + slot * 16);
        sf[c] = MFMA_BF16(qf[dc], kf, sf[c]);
      }
    }
    if (kt == qt) {
      const int qg = qt * 64 + wid * 16 + hi * 4;
#pragma unroll
      for (int c = 0; c < 4; ++c) {
        int kcol = kt * 64 + c * 16 + fr;
#pragma unroll
        for (int r = 0; r < 4; ++r)
          sf[c][r] = (kcol <= qg + r)
                         ? __builtin_amdgcn_exp2f(sf[c][r] - mr[r]) * rl[r] : 0.f;
      }
    } else {
#pragma unroll
      for (int c = 0; c < 4; ++c)
#pragma unroll
        for (int r = 0; r < 4; ++r)
          sf[c][r] = __builtin_amdgcn_exp2f(sf[c][r] - mr[r]) * rl[r];
    }
#pragma unroll
    for (int c = 0; c < 4; ++c) {
      int col = c * 16 + fr;
      int sseg = col >> 3;
#pragma unroll
      for (int r = 0; r < 4; ++r) {
        int prow = hi * 4 + r;
        int slot = sseg ^ (prow & 7);
        Pw[prow * 64 + slot * 8 + (col & 7)] = __float2bfloat16(sf[c][r]);
      }
    }
#pragma unroll
    for (int kc = 0; kc < 2; ++kc) {
      int slot = (kc * 4 + hi) ^ (fr & 7);
      bf16x8 pf = *(const bf16x8*)(Pw + fr * 64 + slot * 8);
#pragma unroll
      for (int f = 0; f < 8; ++f) {
        int vrow = f * 16 + fr;
        int vslot = (kc * 4 + hi) ^ (vrow & 7);
        bf16x8 vf = *(const bf16x8*)(Vc + vrow * 64 + vslot * 8);
        accO[f] = MFMA_BF16(pf, vf, accO[f]);
      }
    }
  };

  const float m1 = *mix1p, m2 = *mix2p;
  auto epilogue = [&](int qt) {
    const size_t qb = (size_t)bh * 2048 + qt * 64 + wid * 16;
#pragma unroll
    for (int f = 0; f < 8; ++f) {
      int d = f * 16 + fr;
#pragma unroll
      for (int r = 0; r < 4; ++r) {
        int ql = hi * 4 + r;
        float y1v = __bfloat162float(y1n[(qb + ql) * 128 + d]);
        float yv = m1 * y1v + m2 * accO[f][r];
        int q = qt * 64 + wid * 16 + ql;
        ymix[((size_t)b * 2048 + q) * 2048 + h * 128 + d] = __float2bfloat16(yv);
      }
    }
  };

  STAGE(0, 0);
  __syncthreads();
  int cur = 0;
  const int nsteps = 33;
  for (int s = 0; s < nsteps; ++s) {
    int snext = s + 1;
    if (snext < nsteps) STAGE(cur ^ 1, (snext < ntA) ? snext : snext - ntA);
    __builtin_amdgcn_sched_barrier(0);
    if (s < ntA) {
      compute(qfA, mA, rlA, s, qtA, cur);
      if (s == ntA - 1) {
        epilogue(qtA);
#pragma unroll
        for (int f = 0; f < 8; ++f)
#pragma unroll
          for (int r = 0; r < 4; ++r) accO[f][r] = 0.f;
        const __hip_bfloat16* QB = qT + ((size_t)bh * 2048 + qtB * 64 + wid * 16) * 128;
#pragma unroll
        for (int dc = 0; dc < 4; ++dc)
          qfB[dc] = *(const bf16x8*)(QB + fr * 128 + dc * 32 + kg);
        const size_t qbB = (size_t)bh * 2048 + qtB * 64 + wid * 16;
#pragma unroll
        for (int r = 0; r < 4; ++r) {
          mB[r] = Mb[qbB + hi * 4 + r];
          rlB[r] = 1.f / Lb[qbB + hi * 4 + r];
        }
      }
    } else {
      compute(qfB, mB, rlB, s - ntA, qtB, cur);
      if (s == nsteps - 1) epilogue(qtB);
    }
    __syncthreads();
    cur ^= 1;
  }
}

// ---------------- launch ----------------
extern "C" void kernel_launch(void* const* d_in, const int* in_sizes, int n_in,
                              void* d_out, int out_size, void* d_ws, size_t ws_size,
                              hipStream_t stream) {
  const float* x    = (const float*)d_in[0];
  const float* cosb = (const float*)d_in[1];
  const float* sinb = (const float*)d_in[2];
  const float* Wq   = (const float*)d_in[3];
  const float* Wk   = (const float*)d_in[4];
  const float* Wv   = (const float*)d_in[5];
  const float* Wp   = (const float*)d_in[6];
  const float* mix1 = (const float*)d_in[7];
  const float* mix2 = (const float*)d_in[8];
  float* out = (float*)d_out;
  char* ws = (char*)d_ws;

  __hip_bfloat16* xb   = (__hip_bfloat16*)(ws + 0);           // 16.78 MB, reused as ymix
  __hip_bfloat16* WTa  = (__hip_bfloat16*)(ws + 16777216);    // 12.58 MB (3072x2048)
  __hip_bfloat16* WpT  = (__hip_bfloat16*)(ws + 29360128);    // 8.39 MB
  float*          qkv  = (float*)(ws + 37748736);             // 50.33 MB (4096x3072 f32)
  __hip_bfloat16* y1n  = (__hip_bfloat16*)(ws + 37748736);    // reuse qkv after rope/v-transpose
  __hip_bfloat16* y1t  = (__hip_bfloat16*)(ws + 54525952);
  float*          Mb   = (float*)(ws + 71303168);
  float*          Lb   = (float*)(ws + 71565312);
  __hip_bfloat16* qTb  = (__hip_bfloat16*)(ws + 88080384);    // (B,H,T,HD)
  __hip_bfloat16* kTb  = (__hip_bfloat16*)(ws + 104857600);   // (B,HK,T,HD)
  __hip_bfloat16* vtb  = (__hip_bfloat16*)(ws + 109051904);   // (B,HK,HD,T)
  __hip_bfloat16* ymix = (__hip_bfloat16*)(ws + 0);

  dim3 tb(32, 8);
  cast_bf16_kernel<<<8192, 256, 0, stream>>>(x, xb, 2097152);
  transpose_cast_kernel<<<dim3(64, 64), tb, 0, stream>>>(Wq, WTa, 2048, 2048);
  transpose_cast_kernel<<<dim3(16, 64), tb, 0, stream>>>(Wk, WTa + (size_t)2048 * 2048, 512, 2048);
  transpose_cast_kernel<<<dim3(16, 64), tb, 0, stream>>>(Wv, WTa + (size_t)2560 * 2048, 512, 2048);
  transpose_cast_kernel<<<dim3(64, 64), tb, 0, stream>>>(Wp, WpT, 2048, 2048);

  gemm_bf16_kernel<<<32 * 24, 256, 0, stream>>>(xb, WTa, qkv, 4096, 3072, 2048);

  rope_rms_kernel<<<20480, 256, 0, stream>>>(qkv, cosb, sinb, qTb, kTb);
  transpose_cast_kernel<<<dim3(16, 64), tb, 0, stream>>>(qkv + 2560, vtb, 3072, 2048);
  transpose_cast_kernel<<<dim3(16, 64), tb, 0, stream>>>(qkv + (size_t)2048 * 3072 + 2560,
                                                         vtb + (size_t)512 * 2048, 3072, 2048);

  attn_pass1_kernel<<<512, 256, 0, stream>>>(qTb, kTb, vtb, y1n, y1t, Mb, Lb);
  attn_pass2_kernel<<<512, 256, 0, stream>>>(qTb, kTb, y1t, y1n, Mb, Lb, mix1, mix2, ymix);

  gemm_bf16_kernel<<<32 * 16, 256, 0, stream>>>(ymix, WpT, out, 4096, 2048, 2048);
}

// Round 3
// 333.701 us; speedup vs baseline: 1.4321x; 1.1982x over previous
//
#include <hip/hip_runtime.h>
#include <hip/hip_bf16.h>
#include <cstdint>
#include <cstddef>

#define AS1 __attribute__((address_space(1)))
#define AS3 __attribute__((address_space(3)))

typedef __attribute__((ext_vector_type(8))) short bf16x8;
typedef __attribute__((ext_vector_type(4))) float f32x4;

__device__ __forceinline__ void gload_lds16(const void* g, void* l) {
  __builtin_amdgcn_global_load_lds((const AS1 void*)g, (AS3 void*)l, 16, 0, 0);
}

#define MFMA_BF16(A, B, C) __builtin_amdgcn_mfma_f32_16x16x32_bf16((A), (B), (C), 0, 0, 0)

// (1/sqrt(128)) * log2(e) — folded into q at rope time; softmax runs in exp2 domain.
#define QSCALE 0.12751744f

// ---------------- cast f32 -> bf16 ----------------
__global__ __launch_bounds__(256) void cast_bf16_kernel(const float* __restrict__ in,
                                                        __hip_bfloat16* __restrict__ out,
                                                        int n4) {
  int i = blockIdx.x * 256 + threadIdx.x;
  if (i < n4) {
    float4 v = ((const float4*)in)[i];
    __hip_bfloat16* o = out + (size_t)i * 4;
    o[0] = __float2bfloat16(v.x);
    o[1] = __float2bfloat16(v.y);
    o[2] = __float2bfloat16(v.z);
    o[3] = __float2bfloat16(v.w);
  }
}

// ---------------- transpose + cast: out[c][r] = in[r][c] ----------------
__global__ __launch_bounds__(256) void transpose_cast_kernel(const float* __restrict__ in,
                                                             __hip_bfloat16* __restrict__ out,
                                                             int in_stride, int out_stride) {
  __shared__ float tile[32][33];
  int c0 = blockIdx.x * 32, r0 = blockIdx.y * 32;
  int tx = threadIdx.x, ty = threadIdx.y;
#pragma unroll
  for (int i = 0; i < 32; i += 8)
    tile[ty + i][tx] = in[(size_t)(r0 + ty + i) * in_stride + c0 + tx];
  __syncthreads();
#pragma unroll
  for (int i = 0; i < 32; i += 8)
    out[(size_t)(c0 + ty + i) * out_stride + r0 + tx] = __float2bfloat16(tile[tx][ty + i]);
}

// ---------------- bf16 GEMM (m97 structure) ----------------
__global__ __launch_bounds__(256) void gemm_bf16_kernel(const __hip_bfloat16* __restrict__ A,
                                                        const __hip_bfloat16* __restrict__ Bt,
                                                        float* __restrict__ C,
                                                        int M, int N, int K) {
  __shared__ __align__(16) __hip_bfloat16 As[128 * 32];
  __shared__ __align__(16) __hip_bfloat16 Bs[128 * 32];
  const int tid = threadIdx.x;
  const int lane = tid & 63;
  const int wid = tid >> 6;
  const int wm = wid >> 1, wn = wid & 1;
  const int ntile = N >> 7;
  const int tm = blockIdx.x / ntile, tn = blockIdx.x % ntile;
  const int row0 = tm << 7, col0 = tn << 7;

  const int fr = lane & 15;
  const int kg = (lane >> 4) * 8;

  f32x4 acc[4][4] = {};

  for (int k0 = 0; k0 < K; k0 += 32) {
    __syncthreads();
#pragma unroll
    for (int i = 0; i < 2; ++i) {
      int f = i * 256 + tid;
      int r = f >> 2, s = f & 3;
      gload_lds16(A + (size_t)(row0 + r) * K + k0 + s * 8,
                  (char*)As + (i * 256 + wid * 64) * 16);
      gload_lds16(Bt + (size_t)(col0 + r) * K + k0 + s * 8,
                  (char*)Bs + (i * 256 + wid * 64) * 16);
    }
    __syncthreads();
    bf16x8 af[4], bfr[4];
#pragma unroll
    for (int m = 0; m < 4; ++m)
      af[m] = *(const bf16x8*)(As + (wm * 64 + m * 16 + fr) * 32 + kg);
#pragma unroll
    for (int n = 0; n < 4; ++n)
      bfr[n] = *(const bf16x8*)(Bs + (wn * 64 + n * 16 + fr) * 32 + kg);
#pragma unroll
    for (int m = 0; m < 4; ++m)
#pragma unroll
      for (int n = 0; n < 4; ++n)
        acc[m][n] = MFMA_BF16(af[m], bfr[n], acc[m][n]);
  }

  const int cr = (lane >> 4) * 4;
#pragma unroll
  for (int m = 0; m < 4; ++m)
#pragma unroll
    for (int n = 0; n < 4; ++n) {
      int col = col0 + wn * 64 + n * 16 + fr;
#pragma unroll
      for (int r = 0; r < 4; ++r) {
        int row = row0 + wm * 64 + m * 16 + cr + r;
        C[(size_t)row * N + col] = acc[m][n][r];
      }
    }
}

// ---------------- RoPE + RMS; q gets QSCALE folded in ----------------
__global__ __launch_bounds__(256) void rope_rms_kernel(const float* __restrict__ qkv,
                                                       const float* __restrict__ cosb,
                                                       const float* __restrict__ sinb,
                                                       __hip_bfloat16* __restrict__ qT,
                                                       __hip_bfloat16* __restrict__ kT) {
  int lane = threadIdx.x & 63, wid = threadIdx.x >> 6;
  int task = blockIdx.x * 4 + wid;
  int bt = task / 20, j = task - bt * 20;
  int b = bt >> 11, t = bt & 2047;
  const float* src;
  __hip_bfloat16* dst;
  float oscale;
  if (j < 16) {
    src = qkv + (size_t)bt * 3072 + j * 128;
    dst = qT + ((size_t)(b * 16 + j) * 2048 + t) * 128;
    oscale = QSCALE;
  } else {
    src = qkv + (size_t)bt * 3072 + 2048 + (j - 16) * 128;
    dst = kT + ((size_t)(b * 4 + (j - 16)) * 2048 + t) * 128;
    oscale = 1.0f;
  }
  float x1 = src[lane], x2 = src[lane + 64];
  float c = cosb[t * 64 + lane], s = sinb[t * 64 + lane];
  float o1 = x1 * c - x2 * s;
  float o2 = x1 * s + x2 * c;
  float ss = o1 * o1 + o2 * o2;
#pragma unroll
  for (int off = 1; off < 64; off <<= 1) ss += __shfl_xor(ss, off);
  float rn = rsqrtf(ss * (1.f / 128.f) + 1e-6f) * oscale;
  dst[lane] = __float2bfloat16(o1 * rn);
  dst[lane + 64] = __float2bfloat16(o2 * rn);
}

// ---------------- attention pass 1 ----------------
// 256 blocks of 512 threads (8 waves x 16 q-rows = 128-row q-block).
// Block pairs 128-row q-blocks (j, 15-j): stream lengths (2j+2) + (32-2j) = 34, balanced.
// Per staged k-tile serves 128 q-rows (2x amortization vs round 2).
__global__ __launch_bounds__(512) void attn_pass1_kernel(
    const __hip_bfloat16* __restrict__ qT,   // (B,H,T,HD), q pre-scaled
    const __hip_bfloat16* __restrict__ kT,   // (B,HK,T,HD)
    const __hip_bfloat16* __restrict__ vt,   // (B,HK,HD,T)
    __hip_bfloat16* __restrict__ y1n,        // (B,H,T,HD)
    __hip_bfloat16* __restrict__ y1t,        // (B,H,HD,T)
    float* __restrict__ Mb,                  // (B,H,T)  (exp2 domain)
    float* __restrict__ Lb) {
  __shared__ __align__(16) __hip_bfloat16 Ks[2][64 * 128];
  __shared__ __align__(16) __hip_bfloat16 Vs[2][128 * 64];
  __shared__ __align__(16) __hip_bfloat16 Ps[8][16 * 64];
  const int tid = threadIdx.x, lane = tid & 63, wid = tid >> 6;   // wid 0..7
  const int j = blockIdx.x & 7;
  const int bh = blockIdx.x >> 3;
  const int h = bh & 15, b = bh >> 4;
  const int kvh = h >> 2;
  const int q0A = j * 128, q0B = (15 - j) * 128;
  const int ntA = 2 * j + 2;          // stream-A length (k-tiles)
  const int ntB = 32 - 2 * j;         // stream-B length; ntA+ntB = 34
  const int sdA = 2 * j + (wid >> 2);        // this wave's diagonal step in stream A
  const int sdB = 2 * (15 - j) + (wid >> 2); // ... stream B
  const __hip_bfloat16* Kp = kT + (size_t)(b * 4 + kvh) * 2048 * 128;
  const __hip_bfloat16* Vp = vt + (size_t)(b * 4 + kvh) * 128 * 2048;
  const int fr = lane & 15, hi = lane >> 4;
  const int kg = hi * 8;

  bf16x8 qfA[4], qfB[4];
  {
    const __hip_bfloat16* QA = qT + ((size_t)bh * 2048 + q0A + wid * 16) * 128;
#pragma unroll
    for (int dc = 0; dc < 4; ++dc)
      qfA[dc] = *(const bf16x8*)(QA + fr * 128 + dc * 32 + kg);
  }

  f32x4 accO[8] = {};
  float m[4], l[4];
#pragma unroll
  for (int r = 0; r < 4; ++r) { m[r] = -1e30f; l[r] = 0.f; }

  __hip_bfloat16* Pw = Ps[wid];

  auto STAGE = [&](int buf, int kt) {
    const int k0 = kt * 64;
#pragma unroll
    for (int i = 0; i < 2; ++i) {    // K tile 64x128, swizzled source
      int f = i * 512 + tid;
      int r = f >> 4, s = f & 15, sx = s ^ (r & 7);
      gload_lds16(Kp + (size_t)(k0 + r) * 128 + sx * 8,
                  (char*)Ks[buf] + (i * 512 + wid * 64) * 16);
    }
#pragma unroll
    for (int i = 0; i < 2; ++i) {    // V^T tile 128x64, swizzled source
      int f = i * 512 + tid;
      int r = f >> 3, s = f & 7, sx = s ^ (r & 7);
      gload_lds16(Vp + (size_t)r * 2048 + k0 + sx * 8,
                  (char*)Vs[buf] + (i * 512 + wid * 64) * 16);
    }
  };

  // s: local step (== k-tile index), sd: wave's diagonal step, q0: q-block base
  auto compute = [&](const bf16x8 (&qf)[4], int s, int sd, int q0, int cur) {
    const char* Kc = (const char*)Ks[cur];
    const __hip_bfloat16* Vc = Vs[cur];
    f32x4 sf[4] = {};
#pragma unroll
    for (int c = 0; c < 4; ++c) {
      const int krow = c * 16 + fr;
#pragma unroll
      for (int dc = 0; dc < 4; ++dc) {
        int slot = (dc * 4 + hi) ^ (krow & 7);
        bf16x8 kf = *(const bf16x8*)(Kc + krow * 256 + slot * 16);
        sf[c] = MFMA_BF16(qf[dc], kf, sf[c]);
      }
    }
    float rmax[4];
#pragma unroll
    for (int r = 0; r < 4; ++r) rmax[r] = -1e30f;
    if (s == sd) {
      const int qg = q0 + wid * 16 + hi * 4;
#pragma unroll
      for (int c = 0; c < 4; ++c) {
        int kcol = s * 64 + c * 16 + fr;
#pragma unroll
        for (int r = 0; r < 4; ++r) {
          float sv = (kcol <= qg + r) ? sf[c][r] : -1e30f;
          sf[c][r] = sv;
          rmax[r] = fmaxf(rmax[r], sv);
        }
      }
    } else {
#pragma unroll
      for (int c = 0; c < 4; ++c)
#pragma unroll
        for (int r = 0; r < 4; ++r) rmax[r] = fmaxf(rmax[r], sf[c][r]);
    }
#pragma unroll
    for (int r = 0; r < 4; ++r) {
      float v = rmax[r];
      v = fmaxf(v, __shfl_xor(v, 1));
      v = fmaxf(v, __shfl_xor(v, 2));
      v = fmaxf(v, __shfl_xor(v, 4));
      v = fmaxf(v, __shfl_xor(v, 8));
      rmax[r] = v;
    }
    bool grow = (rmax[0] > m[0]) | (rmax[1] > m[1]) | (rmax[2] > m[2]) | (rmax[3] > m[3]);
    if (__any(grow)) {   // exact: when skipped, alpha==1 for every row
#pragma unroll
      for (int r = 0; r < 4; ++r) {
        float mn = fmaxf(m[r], rmax[r]);
        float a = __builtin_amdgcn_exp2f(m[r] - mn);
        m[r] = mn;
        l[r] *= a;
#pragma unroll
        for (int f = 0; f < 8; ++f) accO[f][r] *= a;
      }
    }
    float rsum[4] = {0.f, 0.f, 0.f, 0.f};
#pragma unroll
    for (int c = 0; c < 4; ++c)
#pragma unroll
      for (int r = 0; r < 4; ++r) {
        float p = __builtin_amdgcn_exp2f(sf[c][r] - m[r]);
        sf[c][r] = p;
        rsum[r] += p;
      }
#pragma unroll
    for (int r = 0; r < 4; ++r) {
      float v = rsum[r];
      v += __shfl_xor(v, 1);
      v += __shfl_xor(v, 2);
      v += __shfl_xor(v, 4);
      v += __shfl_xor(v, 8);
      l[r] += v;
    }
    // P -> LDS (bf16, swizzled), wave-local
#pragma unroll
    for (int c = 0; c < 4; ++c) {
      int col = c * 16 + fr;
      int sseg = col >> 3;
#pragma unroll
      for (int r = 0; r < 4; ++r) {
        int prow = hi * 4 + r;
        int slot = sseg ^ (prow & 7);
        Pw[prow * 64 + slot * 8 + (col & 7)] = __float2bfloat16(sf[c][r]);
      }
    }
#pragma unroll
    for (int kc = 0; kc < 2; ++kc) {
      int slot = (kc * 4 + hi) ^ (fr & 7);
      bf16x8 pf = *(const bf16x8*)(Pw + fr * 64 + slot * 8);
#pragma unroll
      for (int f = 0; f < 8; ++f) {
        int vrow = f * 16 + fr;
        int vslot = (kc * 4 + hi) ^ (vrow & 7);
        bf16x8 vf = *(const bf16x8*)(Vc + vrow * 64 + vslot * 8);
        accO[f] = MFMA_BF16(pf, vf, accO[f]);
      }
    }
  };

  auto epilogue = [&](int q0) {
    float rl[4];
#pragma unroll
    for (int r = 0; r < 4; ++r) rl[r] = 1.f / l[r];
    const size_t qb = (size_t)bh * 2048 + q0 + wid * 16;
#pragma unroll
    for (int f = 0; f < 8; ++f) {
      int d = f * 16 + fr;
#pragma unroll
      for (int r = 0; r < 4; ++r) {
        int ql = hi * 4 + r;
        __hip_bfloat16 yb = __float2bfloat16(accO[f][r] * rl[r]);
        y1n[(qb + ql) * 128 + d] = yb;
        y1t[((size_t)bh * 128 + d) * 2048 + q0 + wid * 16 + ql] = yb;
      }
    }
    if (fr == 0) {
#pragma unroll
      for (int r = 0; r < 4; ++r) {
        Mb[qb + hi * 4 + r] = m[r];
        Lb[qb + hi * 4 + r] = l[r];
      }
    }
  };

  STAGE(0, 0);
  __syncthreads();
  int cur = 0;
  const int nsteps = 34;
  for (int s = 0; s < nsteps; ++s) {
    int snext = s + 1;
    if (snext < nsteps) STAGE(cur ^ 1, (snext < ntA) ? snext : snext - ntA);
    __builtin_amdgcn_sched_barrier(0);
    if (s < ntA) {
      if (s <= sdA) compute(qfA, s, sdA, q0A, cur);
      if (s == ntA - 1) {
        epilogue(q0A);
#pragma unroll
        for (int f = 0; f < 8; ++f)
#pragma unroll
          for (int r = 0; r < 4; ++r) accO[f][r] = 0.f;
#pragma unroll
        for (int r = 0; r < 4; ++r) { m[r] = -1e30f; l[r] = 0.f; }
        const __hip_bfloat16* QB = qT + ((size_t)bh * 2048 + q0B + wid * 16) * 128;
#pragma unroll
        for (int dc = 0; dc < 4; ++dc)
          qfB[dc] = *(const bf16x8*)(QB + fr * 128 + dc * 32 + kg);
      }
    } else {
      int s2 = s - ntA;
      if (s2 <= sdB) compute(qfB, s2, sdB, q0B, cur);
      if (s2 == ntB - 1) epilogue(q0B);
    }
    __syncthreads();
    cur ^= 1;
  }
}

// ---------------- attention pass 2: y2 = att @ y1 ; ymix = mix1*y1 + mix2*y2 ----------------
__global__ __launch_bounds__(512) void attn_pass2_kernel(
    const __hip_bfloat16* __restrict__ qT,
    const __hip_bfloat16* __restrict__ kT,
    const __hip_bfloat16* __restrict__ y1t,  // (B,H,HD,T)
    const __hip_bfloat16* __restrict__ y1n,  // (B,H,T,HD)
    const float* __restrict__ Mb,
    const float* __restrict__ Lb,
    const float* __restrict__ mix1p,
    const float* __restrict__ mix2p,
    __hip_bfloat16* __restrict__ ymix) {     // (B,T,C)
  __shared__ __align__(16) __hip_bfloat16 Ks[2][64 * 128];
  __shared__ __align__(16) __hip_bfloat16 Vs[2][128 * 64];
  __shared__ __align__(16) __hip_bfloat16 Ps[8][16 * 64];
  const int tid = threadIdx.x, lane = tid & 63, wid = tid >> 6;
  const int j = blockIdx.x & 7;
  const int bh = blockIdx.x >> 3;
  const int h = bh & 15, b = bh >> 4;
  const int kvh = h >> 2;
  const int q0A = j * 128, q0B = (15 - j) * 128;
  const int ntA = 2 * j + 2;
  const int ntB = 32 - 2 * j;
  const int sdA = 2 * j + (wid >> 2);
  const int sdB = 2 * (15 - j) + (wid >> 2);
  const __hip_bfloat16* Kp = kT + (size_t)(b * 4 + kvh) * 2048 * 128;
  const __hip_bfloat16* Yp = y1t + (size_t)bh * 128 * 2048;
  const int fr = lane & 15, hi = lane >> 4;
  const int kg = hi * 8;

  bf16x8 qfA[4], qfB[4];
  float mA[4], rlA[4], mB[4], rlB[4];
  {
    const __hip_bfloat16* QA = qT + ((size_t)bh * 2048 + q0A + wid * 16) * 128;
#pragma unroll
    for (int dc = 0; dc < 4; ++dc)
      qfA[dc] = *(const bf16x8*)(QA + fr * 128 + dc * 32 + kg);
    const size_t qbA = (size_t)bh * 2048 + q0A + wid * 16;
#pragma unroll
    for (int r = 0; r < 4; ++r) {
      mA[r] = Mb[qbA + hi * 4 + r];
      rlA[r] = 1.f / Lb[qbA + hi * 4 + r];
    }
  }

  f32x4 accO[8] = {};
  __hip_bfloat16* Pw = Ps[wid];

  auto STAGE = [&](int buf, int kt) {
    const int k0 = kt * 64;
#pragma unroll
    for (int i = 0; i < 2; ++i) {
      int f = i * 512 + tid;
      int r = f >> 4, s = f & 15, sx = s ^ (r & 7);
      gload_lds16(Kp + (size_t)(k0 + r) * 128 + sx * 8,
                  (char*)Ks[buf] + (i * 512 + wid * 64) * 16);
    }
#pragma unroll
    for (int i = 0; i < 2; ++i) {
      int f = i * 512 + tid;
      int r = f >> 3, s = f & 7, sx = s ^ (r & 7);
      gload_lds16(Yp + (size_t)r * 2048 + k0 + sx * 8,
                  (char*)Vs[buf] + (i * 512 + wid * 64) * 16);
    }
  };

  auto compute = [&](const bf16x8 (&qf)[4], const float (&mr)[4], const float (&rl)[4],
                     int s, int sd, int q0, int cur) {
    const char* Kc = (const char*)Ks[cur];
    const __hip_bfloat16* Vc = Vs[cur];
    f32x4 sf[4] = {};
#pragma unroll
    for (int c = 0; c < 4; ++c) {
      const int krow = c * 16 + fr;
#pragma unroll
      for (int dc = 0; dc < 4; ++dc) {
        int slot = (dc * 4 + hi) ^ (krow & 7);
        bf16x8 kf = *(const bf16x8*)(Kc + krow * 256 + slot * 16);
        sf[c] = MFMA_BF16(qf[dc], kf, sf[c]);
      }
    }
    if (s == sd) {
      const int qg = q0 + wid * 16 + hi * 4;
#pragma unroll
      for (int c = 0; c < 4; ++c) {
        int kcol = s * 64 + c * 16 + fr;
#pragma unroll
        for (int r = 0; r < 4; ++r)
          sf[c][r] = (kcol <= qg + r)
                         ? __builtin_amdgcn_exp2f(sf[c][r] - mr[r]) * rl[r] : 0.f;
      }
    } else {
#pragma unroll
      for (int c = 0; c < 4; ++c)
#pragma unroll
        for (int r = 0; r < 4; ++r)
          sf[c][r] = __builtin_amdgcn_exp2f(sf[c][r] - mr[r]) * rl[r];
    }
#pragma unroll
    for (int c = 0; c < 4; ++c) {
      int col = c * 16 + fr;
      int sseg = col >> 3;
#pragma unroll
      for (int r = 0; r < 4; ++r) {
        int prow = hi * 4 + r;
        int slot = sseg ^ (prow & 7);
        Pw[prow * 64 + slot * 8 + (col & 7)] = __float2bfloat16(sf[c][r]);
      }
    }
#pragma unroll
    for (int kc = 0; kc < 2; ++kc) {
      int slot = (kc * 4 + hi) ^ (fr & 7);
      bf16x8 pf = *(const bf16x8*)(Pw + fr * 64 + slot * 8);
#pragma unroll
      for (int f = 0; f < 8; ++f) {
        int vrow = f * 16 + fr;
        int vslot = (kc * 4 + hi) ^ (vrow & 7);
        bf16x8 vf = *(const bf16x8*)(Vc + vrow * 64 + vslot * 8);
        accO[f] = MFMA_BF16(pf, vf, accO[f]);
      }
    }
  };

  const float m1 = *mix1p, m2 = *mix2p;
  auto epilogue = [&](int q0) {
    const size_t qb = (size_t)bh * 2048 + q0 + wid * 16;
#pragma unroll
    for (int f = 0; f < 8; ++f) {
      int d = f * 16 + fr;
#pragma unroll
      for (int r = 0; r < 4; ++r) {
        int ql = hi * 4 + r;
        float y1v = __bfloat162float(y1n[(qb + ql) * 128 + d]);
        float yv = m1 * y1v + m2 * accO[f][r];
        int q = q0 + wid * 16 + ql;
        ymix[((size_t)b * 2048 + q) * 2048 + h * 128 + d] = __float2bfloat16(yv);
      }
    }
  };

  STAGE(0, 0);
  __syncthreads();
  int cur = 0;
  const int nsteps = 34;
  for (int s = 0; s < nsteps; ++s) {
    int snext = s + 1;
    if (snext < nsteps) STAGE(cur ^ 1, (snext < ntA) ? snext : snext - ntA);
    __builtin_amdgcn_sched_barrier(0);
    if (s < ntA) {
      if (s <= sdA) compute(qfA, mA, rlA, s, sdA, q0A, cur);
      if (s == ntA - 1) {
        epilogue(q0A);
#pragma unroll
        for (int f = 0; f < 8; ++f)
#pragma unroll
          for (int r = 0; r < 4; ++r) accO[f][r] = 0.f;
        const __hip_bfloat16* QB = qT + ((size_t)bh * 2048 + q0B + wid * 16) * 128;
#pragma unroll
        for (int dc = 0; dc < 4; ++dc)
          qfB[dc] = *(const bf16x8*)(QB + fr * 128 + dc * 32 + kg);
        const size_t qbB = (size_t)bh * 2048 + q0B + wid * 16;
#pragma unroll
        for (int r = 0; r < 4; ++r) {
          mB[r] = Mb[qbB + hi * 4 + r];
          rlB[r] = 1.f / Lb[qbB + hi * 4 + r];
        }
      }
    } else {
      int s2 = s - ntA;
      if (s2 <= sdB) compute(qfB, mB, rlB, s2, sdB, q0B, cur);
      if (s2 == ntB - 1) epilogue(q0B);
    }
    __syncthreads();
    cur ^= 1;
  }
}

// ---------------- launch ----------------
extern "C" void kernel_launch(void* const* d_in, const int* in_sizes, int n_in,
                              void* d_out, int out_size, void* d_ws, size_t ws_size,
                              hipStream_t stream) {
  const float* x    = (const float*)d_in[0];
  const float* cosb = (const float*)d_in[1];
  const float* sinb = (const float*)d_in[2];
  const float* Wq   = (const float*)d_in[3];
  const float* Wk   = (const float*)d_in[4];
  const float* Wv   = (const float*)d_in[5];
  const float* Wp   = (const float*)d_in[6];
  const float* mix1 = (const float*)d_in[7];
  const float* mix2 = (const float*)d_in[8];
  float* out = (float*)d_out;
  char* ws = (char*)d_ws;

  __hip_bfloat16* xb   = (__hip_bfloat16*)(ws + 0);           // 16.78 MB, reused as ymix
  __hip_bfloat16* WTa  = (__hip_bfloat16*)(ws + 16777216);    // 12.58 MB (3072x2048)
  __hip_bfloat16* WpT  = (__hip_bfloat16*)(ws + 29360128);    // 8.39 MB
  float*          qkv  = (float*)(ws + 37748736);             // 50.33 MB (4096x3072 f32)
  __hip_bfloat16* y1n  = (__hip_bfloat16*)(ws + 37748736);    // reuse qkv after rope/v-transpose
  __hip_bfloat16* y1t  = (__hip_bfloat16*)(ws + 54525952);
  float*          Mb   = (float*)(ws + 71303168);
  float*          Lb   = (float*)(ws + 71565312);
  __hip_bfloat16* qTb  = (__hip_bfloat16*)(ws + 88080384);    // (B,H,T,HD)
  __hip_bfloat16* kTb  = (__hip_bfloat16*)(ws + 104857600);   // (B,HK,T,HD)
  __hip_bfloat16* vtb  = (__hip_bfloat16*)(ws + 109051904);   // (B,HK,HD,T)
  __hip_bfloat16* ymix = (__hip_bfloat16*)(ws + 0);

  dim3 tb(32, 8);
  cast_bf16_kernel<<<8192, 256, 0, stream>>>(x, xb, 2097152);
  transpose_cast_kernel<<<dim3(64, 64), tb, 0, stream>>>(Wq, WTa, 2048, 2048);
  transpose_cast_kernel<<<dim3(16, 64), tb, 0, stream>>>(Wk, WTa + (size_t)2048 * 2048, 512, 2048);
  transpose_cast_kernel<<<dim3(16, 64), tb, 0, stream>>>(Wv, WTa + (size_t)2560 * 2048, 512, 2048);
  transpose_cast_kernel<<<dim3(64, 64), tb, 0, stream>>>(Wp, WpT, 2048, 2048);

  gemm_bf16_kernel<<<32 * 24, 256, 0, stream>>>(xb, WTa, qkv, 4096, 3072, 2048);

  rope_rms_kernel<<<20480, 256, 0, stream>>>(qkv, cosb, sinb, qTb, kTb);
  transpose_cast_kernel<<<dim3(16, 64), tb, 0, stream>>>(qkv + 2560, vtb, 3072, 2048);
  transpose_cast_kernel<<<dim3(16, 64), tb, 0, stream>>>(qkv + (size_t)2048 * 3072 + 2560,
                                                         vtb + (size_t)512 * 2048, 3072, 2048);

  attn_pass1_kernel<<<256, 512, 0, stream>>>(qTb, kTb, vtb, y1n, y1t, Mb, Lb);
  attn_pass2_kernel<<<256, 512, 0, stream>>>(qTb, kTb, y1t, y1n, Mb, Lb, mix1, mix2, ymix);

  gemm_bf16_kernel<<<32 * 16, 256, 0, stream>>>(ymix, WpT, out, 4096, 2048, 2048);
}

// Round 4
// 319.367 us; speedup vs baseline: 1.4964x; 1.0449x over previous
//
#include <hip/hip_runtime.h>
#include <hip/hip_bf16.h>
#include <cstdint>
#include <cstddef>

#define AS1 __attribute__((address_space(1)))
#define AS3 __attribute__((address_space(3)))

typedef __attribute__((ext_vector_type(8))) short bf16x8;
typedef __attribute__((ext_vector_type(4))) float f32x4;

__device__ __forceinline__ void gload_lds16(const void* g, void* l) {
  __builtin_amdgcn_global_load_lds((const AS1 void*)g, (AS3 void*)l, 16, 0, 0);
}

#define MFMA_BF16(A, B, C) __builtin_amdgcn_mfma_f32_16x16x32_bf16((A), (B), (C), 0, 0, 0)

// (1/sqrt(128)) * log2(e) — folded into q at rope time; softmax runs in exp2 domain.
#define QSCALE 0.12751744f

// DPP reduce over each 16-lane group: quad_perm xor1, xor2, row_half_mirror, row_mirror
__device__ __forceinline__ float red16_max(float v) {
  int x;
  x = __builtin_amdgcn_update_dpp(0, __builtin_bit_cast(int, v), 0xB1, 0xF, 0xF, true);
  v = fmaxf(v, __builtin_bit_cast(float, x));
  x = __builtin_amdgcn_update_dpp(0, __builtin_bit_cast(int, v), 0x4E, 0xF, 0xF, true);
  v = fmaxf(v, __builtin_bit_cast(float, x));
  x = __builtin_amdgcn_update_dpp(0, __builtin_bit_cast(int, v), 0x141, 0xF, 0xF, true);
  v = fmaxf(v, __builtin_bit_cast(float, x));
  x = __builtin_amdgcn_update_dpp(0, __builtin_bit_cast(int, v), 0x140, 0xF, 0xF, true);
  v = fmaxf(v, __builtin_bit_cast(float, x));
  return v;
}
__device__ __forceinline__ float red16_sum(float v) {
  int x;
  x = __builtin_amdgcn_update_dpp(0, __builtin_bit_cast(int, v), 0xB1, 0xF, 0xF, true);
  v += __builtin_bit_cast(float, x);
  x = __builtin_amdgcn_update_dpp(0, __builtin_bit_cast(int, v), 0x4E, 0xF, 0xF, true);
  v += __builtin_bit_cast(float, x);
  x = __builtin_amdgcn_update_dpp(0, __builtin_bit_cast(int, v), 0x141, 0xF, 0xF, true);
  v += __builtin_bit_cast(float, x);
  x = __builtin_amdgcn_update_dpp(0, __builtin_bit_cast(int, v), 0x140, 0xF, 0xF, true);
  v += __builtin_bit_cast(float, x);
  return v;
}

// ---------------- cast f32 -> bf16 ----------------
__global__ __launch_bounds__(256) void cast_bf16_kernel(const float* __restrict__ in,
                                                        __hip_bfloat16* __restrict__ out,
                                                        int n4) {
  int i = blockIdx.x * 256 + threadIdx.x;
  if (i < n4) {
    float4 v = ((const float4*)in)[i];
    __hip_bfloat16* o = out + (size_t)i * 4;
    o[0] = __float2bfloat16(v.x);
    o[1] = __float2bfloat16(v.y);
    o[2] = __float2bfloat16(v.z);
    o[3] = __float2bfloat16(v.w);
  }
}

// ---------------- transpose + cast: out[c][r] = in[r][c] ----------------
__global__ __launch_bounds__(256) void transpose_cast_kernel(const float* __restrict__ in,
                                                             __hip_bfloat16* __restrict__ out,
                                                             int in_stride, int out_stride) {
  __shared__ float tile[32][33];
  int c0 = blockIdx.x * 32, r0 = blockIdx.y * 32;
  int tx = threadIdx.x, ty = threadIdx.y;
#pragma unroll
  for (int i = 0; i < 32; i += 8)
    tile[ty + i][tx] = in[(size_t)(r0 + ty + i) * in_stride + c0 + tx];
  __syncthreads();
#pragma unroll
  for (int i = 0; i < 32; i += 8)
    out[(size_t)(c0 + ty + i) * out_stride + r0 + tx] = __float2bfloat16(tile[tx][ty + i]);
}

// ---------------- bf16 GEMM (m97 structure) ----------------
__global__ __launch_bounds__(256) void gemm_bf16_kernel(const __hip_bfloat16* __restrict__ A,
                                                        const __hip_bfloat16* __restrict__ Bt,
                                                        float* __restrict__ C,
                                                        int M, int N, int K) {
  __shared__ __align__(16) __hip_bfloat16 As[128 * 32];
  __shared__ __align__(16) __hip_bfloat16 Bs[128 * 32];
  const int tid = threadIdx.x;
  const int lane = tid & 63;
  const int wid = tid >> 6;
  const int wm = wid >> 1, wn = wid & 1;
  const int ntile = N >> 7;
  const int tm = blockIdx.x / ntile, tn = blockIdx.x % ntile;
  const int row0 = tm << 7, col0 = tn << 7;

  const int fr = lane & 15;
  const int kg = (lane >> 4) * 8;

  f32x4 acc[4][4] = {};

  for (int k0 = 0; k0 < K; k0 += 32) {
    __syncthreads();
#pragma unroll
    for (int i = 0; i < 2; ++i) {
      int f = i * 256 + tid;
      int r = f >> 2, s = f & 3;
      gload_lds16(A + (size_t)(row0 + r) * K + k0 + s * 8,
                  (char*)As + (i * 256 + wid * 64) * 16);
      gload_lds16(Bt + (size_t)(col0 + r) * K + k0 + s * 8,
                  (char*)Bs + (i * 256 + wid * 64) * 16);
    }
    __syncthreads();
    bf16x8 af[4], bfr[4];
#pragma unroll
    for (int m = 0; m < 4; ++m)
      af[m] = *(const bf16x8*)(As + (wm * 64 + m * 16 + fr) * 32 + kg);
#pragma unroll
    for (int n = 0; n < 4; ++n)
      bfr[n] = *(const bf16x8*)(Bs + (wn * 64 + n * 16 + fr) * 32 + kg);
#pragma unroll
    for (int m = 0; m < 4; ++m)
#pragma unroll
      for (int n = 0; n < 4; ++n)
        acc[m][n] = MFMA_BF16(af[m], bfr[n], acc[m][n]);
  }

  const int cr = (lane >> 4) * 4;
#pragma unroll
  for (int m = 0; m < 4; ++m)
#pragma unroll
    for (int n = 0; n < 4; ++n) {
      int col = col0 + wn * 64 + n * 16 + fr;
#pragma unroll
      for (int r = 0; r < 4; ++r) {
        int row = row0 + wm * 64 + m * 16 + cr + r;
        C[(size_t)row * N + col] = acc[m][n][r];
      }
    }
}

// ---------------- RoPE + RMS; q gets QSCALE folded in ----------------
__global__ __launch_bounds__(256) void rope_rms_kernel(const float* __restrict__ qkv,
                                                       const float* __restrict__ cosb,
                                                       const float* __restrict__ sinb,
                                                       __hip_bfloat16* __restrict__ qT,
                                                       __hip_bfloat16* __restrict__ kT) {
  int lane = threadIdx.x & 63, wid = threadIdx.x >> 6;
  int task = blockIdx.x * 4 + wid;
  int bt = task / 20, j = task - bt * 20;
  int b = bt >> 11, t = bt & 2047;
  const float* src;
  __hip_bfloat16* dst;
  float oscale;
  if (j < 16) {
    src = qkv + (size_t)bt * 3072 + j * 128;
    dst = qT + ((size_t)(b * 16 + j) * 2048 + t) * 128;
    oscale = QSCALE;
  } else {
    src = qkv + (size_t)bt * 3072 + 2048 + (j - 16) * 128;
    dst = kT + ((size_t)(b * 4 + (j - 16)) * 2048 + t) * 128;
    oscale = 1.0f;
  }
  float x1 = src[lane], x2 = src[lane + 64];
  float c = cosb[t * 64 + lane], s = sinb[t * 64 + lane];
  float o1 = x1 * c - x2 * s;
  float o2 = x1 * s + x2 * c;
  float ss = o1 * o1 + o2 * o2;
#pragma unroll
  for (int off = 1; off < 64; off <<= 1) ss += __shfl_xor(ss, off);
  float rn = rsqrtf(ss * (1.f / 128.f) + 1e-6f) * oscale;
  dst[lane] = __float2bfloat16(o1 * rn);
  dst[lane + 64] = __float2bfloat16(o2 * rn);
}

// block decode shared by both attention passes:
// bi in [0,512): u=bi&255, half=bi>>8. g=u&7 = (b*4+kvh) -> XCD-local K/V set under
// rr dispatch (XCD=bi%8). pslot=(u>>3)&7, bhlow=u>>6, bh=g*4+bhlow.
// half 0 -> j=pslot (nt=2j+2); half 1 -> j=15-pslot (nt=32-2pslot). bi and bi+256
// (the two halves of a balanced pair, 34 steps total) land on the same CU under
// rr dispatch (CU=(bi/8)%32): per-CU balance at 2 blocks/CU.

// ---------------- attention pass 1 ----------------
// 512 blocks x 512 threads (8 waves x 16 q-rows = 128-row q-block).
// LDS 64KB (K dbuf + single V + P) -> 2 blocks/CU (4 waves/SIMD).
// Single-V schedule: issue V(s),K(s+1) at step start; QK+softmax+P while they fly;
// vmcnt(2) + raw barrier before PV (waits V only, K stays in flight).
__global__ __launch_bounds__(512, 4) void attn_pass1_kernel(
    const __hip_bfloat16* __restrict__ qT,   // (B,H,T,HD), q pre-scaled
    const __hip_bfloat16* __restrict__ kT,   // (B,HK,T,HD)
    const __hip_bfloat16* __restrict__ vt,   // (B,HK,HD,T)
    __hip_bfloat16* __restrict__ y1n,        // (B,H,T,HD)
    __hip_bfloat16* __restrict__ y1t,        // (B,H,HD,T)
    float* __restrict__ Mb,                  // (B,H,T)  (exp2 domain)
    float* __restrict__ Lb) {
  __shared__ __align__(16) __hip_bfloat16 Ks[2][64 * 128];
  __shared__ __align__(16) __hip_bfloat16 Vs[128 * 64];
  __shared__ __align__(16) __hip_bfloat16 Ps[8][16 * 64];
  const int tid = threadIdx.x, lane = tid & 63, wid = tid >> 6;
  const int bi = blockIdx.x;
  const int u = bi & 255, half = bi >> 8;
  const int g = u & 7;
  const int pslot = (u >> 3) & 7;
  const int bh = g * 4 + (u >> 6);
  const int j = half ? (15 - pslot) : pslot;
  const int q0 = j * 128;
  const int nt = 2 * j + 2;
  const int sd = 2 * j + (wid >> 2);   // this wave's diagonal step
  const __hip_bfloat16* Kp = kT + (size_t)g * 2048 * 128;
  const __hip_bfloat16* Vp = vt + (size_t)g * 128 * 2048;
  const int fr = lane & 15, hi = lane >> 4;
  const int kg = hi * 8;
  const int qg = q0 + wid * 16 + hi * 4;

  bf16x8 qf[4];
  {
    const __hip_bfloat16* Qp = qT + ((size_t)bh * 2048 + q0 + wid * 16) * 128;
#pragma unroll
    for (int dc = 0; dc < 4; ++dc)
      qf[dc] = *(const bf16x8*)(Qp + fr * 128 + dc * 32 + kg);
  }

  f32x4 accO[8] = {};
  float m[4], l[4];
#pragma unroll
  for (int r = 0; r < 4; ++r) { m[r] = -1e30f; l[r] = 0.f; }

  __hip_bfloat16* Pw = Ps[wid];

  auto STAGE_K = [&](int buf, int kt) {
    const int k0 = kt * 64;
#pragma unroll
    for (int i = 0; i < 2; ++i) {
      int f = i * 512 + tid;
      int r = f >> 4, s = f & 15, sx = s ^ (r & 7);
      gload_lds16(Kp + (size_t)(k0 + r) * 128 + sx * 8,
                  (char*)Ks[buf] + (i * 512 + wid * 64) * 16);
    }
  };
  auto STAGE_V = [&](int kt) {
    const int k0 = kt * 64;
#pragma unroll
    for (int i = 0; i < 2; ++i) {
      int f = i * 512 + tid;
      int r = f >> 3, s = f & 7, sx = s ^ (r & 7);
      gload_lds16(Vp + (size_t)r * 2048 + k0 + sx * 8,
                  (char*)Vs + (i * 512 + wid * 64) * 16);
    }
  };

  STAGE_K(0, 0);
  __syncthreads();
  int cur = 0;
  for (int s = 0; s < nt; ++s) {
    STAGE_V(s);
    __builtin_amdgcn_sched_barrier(0);    // pin V-issue before K-issue (vmcnt order)
    if (s + 1 < nt) STAGE_K(cur ^ 1, s + 1);
    __builtin_amdgcn_sched_barrier(0);

    // ---- QK on Ks[cur] ----
    const char* Kc = (const char*)Ks[cur];
    f32x4 sf[4] = {};
#pragma unroll
    for (int c = 0; c < 4; ++c) {
      const int krow = c * 16 + fr;
#pragma unroll
      for (int dc = 0; dc < 4; ++dc) {
        int slot = (dc * 4 + hi) ^ (krow & 7);
        bf16x8 kf = *(const bf16x8*)(Kc + krow * 256 + slot * 16);
        sf[c] = MFMA_BF16(qf[dc], kf, sf[c]);
      }
    }
    // ---- mask + row max ----
    float rmax[4] = {-1e30f, -1e30f, -1e30f, -1e30f};
    if (s >= sd) {  // diagonal (s==sd) or fully-masked (s>sd, harmless zero contribution)
#pragma unroll
      for (int c = 0; c < 4; ++c) {
        int kcol = s * 64 + c * 16 + fr;
#pragma unroll
        for (int r = 0; r < 4; ++r) {
          float sv = (kcol <= qg + r) ? sf[c][r] : -1e30f;
          sf[c][r] = sv;
          rmax[r] = fmaxf(rmax[r], sv);
        }
      }
    } else {
#pragma unroll
      for (int c = 0; c < 4; ++c)
#pragma unroll
        for (int r = 0; r < 4; ++r) rmax[r] = fmaxf(rmax[r], sf[c][r]);
    }
#pragma unroll
    for (int r = 0; r < 4; ++r) rmax[r] = red16_max(rmax[r]);
    // T13 defer-max: rescale only when a row max grows by >8 (exp2 domain; p <= 256)
    bool grow = (rmax[0] > m[0] + 8.f) | (rmax[1] > m[1] + 8.f) |
                (rmax[2] > m[2] + 8.f) | (rmax[3] > m[3] + 8.f);
    if (__any(grow)) {
#pragma unroll
      for (int r = 0; r < 4; ++r) {
        float mn = fmaxf(m[r], rmax[r]);
        float a = __builtin_amdgcn_exp2f(m[r] - mn);
        m[r] = mn;
        l[r] *= a;
#pragma unroll
        for (int f = 0; f < 8; ++f) accO[f][r] *= a;
      }
    }
    float rsum[4] = {0.f, 0.f, 0.f, 0.f};
#pragma unroll
    for (int c = 0; c < 4; ++c)
#pragma unroll
      for (int r = 0; r < 4; ++r) {
        float p = __builtin_amdgcn_exp2f(sf[c][r] - m[r]);
        sf[c][r] = p;
        rsum[r] += p;
      }
#pragma unroll
    for (int r = 0; r < 4; ++r) l[r] += red16_sum(rsum[r]);
    // ---- P -> LDS (bf16, swizzled), wave-local; read back A-frags ----
#pragma unroll
    for (int c = 0; c < 4; ++c) {
      int col = c * 16 + fr;
      int sseg = col >> 3;
#pragma unroll
      for (int r = 0; r < 4; ++r) {
        int prow = hi * 4 + r;
        int slot = sseg ^ (prow & 7);
        Pw[prow * 64 + slot * 8 + (col & 7)] = __float2bfloat16(sf[c][r]);
      }
    }
    bf16x8 pf[2];
#pragma unroll
    for (int kc = 0; kc < 2; ++kc) {
      int slot = (kc * 4 + hi) ^ (fr & 7);
      pf[kc] = *(const bf16x8*)(Pw + fr * 64 + slot * 8);
    }
    // ---- mid-step: V staged (own vmcnt) + all waves (barrier); K(s+1) stays in flight
    if (s + 1 < nt) asm volatile("s_waitcnt vmcnt(2)" ::: "memory");
    else            asm volatile("s_waitcnt vmcnt(0)" ::: "memory");
    __builtin_amdgcn_s_barrier();
    __builtin_amdgcn_sched_barrier(0);
    // ---- PV on Vs ----
#pragma unroll
    for (int kc = 0; kc < 2; ++kc)
#pragma unroll
      for (int f = 0; f < 8; ++f) {
        int vrow = f * 16 + fr;
        int vslot = (kc * 4 + hi) ^ (vrow & 7);
        bf16x8 vf = *(const bf16x8*)(Vs + vrow * 64 + vslot * 8);
        accO[f] = MFMA_BF16(pf[kc], vf, accO[f]);
      }
    __syncthreads();
    cur ^= 1;
  }

  float rl[4];
#pragma unroll
  for (int r = 0; r < 4; ++r) rl[r] = 1.f / l[r];
  const size_t qb = (size_t)bh * 2048 + q0 + wid * 16;
#pragma unroll
  for (int f = 0; f < 8; ++f) {
    int d = f * 16 + fr;
#pragma unroll
    for (int r = 0; r < 4; ++r) {
      int ql = hi * 4 + r;
      __hip_bfloat16 yb = __float2bfloat16(accO[f][r] * rl[r]);
      y1n[(qb + ql) * 128 + d] = yb;
      y1t[((size_t)bh * 128 + d) * 2048 + q0 + wid * 16 + ql] = yb;
    }
  }
  if (fr == 0) {
#pragma unroll
    for (int r = 0; r < 4; ++r) {
      Mb[qb + hi * 4 + r] = m[r];
      Lb[qb + hi * 4 + r] = l[r];
    }
  }
}

// ---------------- attention pass 2: y2 = att @ y1 ; ymix = mix1*y1 + mix2*y2 ----------------
__global__ __launch_bounds__(512, 4) void attn_pass2_kernel(
    const __hip_bfloat16* __restrict__ qT,
    const __hip_bfloat16* __restrict__ kT,
    const __hip_bfloat16* __restrict__ y1t,  // (B,H,HD,T)
    const __hip_bfloat16* __restrict__ y1n,  // (B,H,T,HD)
    const float* __restrict__ Mb,
    const float* __restrict__ Lb,
    const float* __restrict__ mix1p,
    const float* __restrict__ mix2p,
    __hip_bfloat16* __restrict__ ymix) {     // (B,T,C)
  __shared__ __align__(16) __hip_bfloat16 Ks[2][64 * 128];
  __shared__ __align__(16) __hip_bfloat16 Vs[128 * 64];
  __shared__ __align__(16) __hip_bfloat16 Ps[8][16 * 64];
  const int tid = threadIdx.x, lane = tid & 63, wid = tid >> 6;
  const int bi = blockIdx.x;
  const int u = bi & 255, half = bi >> 8;
  const int g = u & 7;
  const int pslot = (u >> 3) & 7;
  const int bh = g * 4 + (u >> 6);
  const int h = bh & 15, b = bh >> 4;
  const int j = half ? (15 - pslot) : pslot;
  const int q0 = j * 128;
  const int nt = 2 * j + 2;
  const int sd = 2 * j + (wid >> 2);
  const __hip_bfloat16* Kp = kT + (size_t)g * 2048 * 128;
  const __hip_bfloat16* Yp = y1t + (size_t)bh * 128 * 2048;
  const int fr = lane & 15, hi = lane >> 4;
  const int kg = hi * 8;
  const int qg = q0 + wid * 16 + hi * 4;

  bf16x8 qf[4];
  float mr[4], rl[4];
  {
    const __hip_bfloat16* Qp = qT + ((size_t)bh * 2048 + q0 + wid * 16) * 128;
#pragma unroll
    for (int dc = 0; dc < 4; ++dc)
      qf[dc] = *(const bf16x8*)(Qp + fr * 128 + dc * 32 + kg);
    const size_t qb = (size_t)bh * 2048 + q0 + wid * 16;
#pragma unroll
    for (int r = 0; r < 4; ++r) {
      mr[r] = Mb[qb + hi * 4 + r];
      rl[r] = 1.f / Lb[qb + hi * 4 + r];
    }
  }

  f32x4 accO[8] = {};
  __hip_bfloat16* Pw = Ps[wid];

  auto STAGE_K = [&](int buf, int kt) {
    const int k0 = kt * 64;
#pragma unroll
    for (int i = 0; i < 2; ++i) {
      int f = i * 512 + tid;
      int r = f >> 4, s = f & 15, sx = s ^ (r & 7);
      gload_lds16(Kp + (size_t)(k0 + r) * 128 + sx * 8,
                  (char*)Ks[buf] + (i * 512 + wid * 64) * 16);
    }
  };
  auto STAGE_V = [&](int kt) {
    const int k0 = kt * 64;
#pragma unroll
    for (int i = 0; i < 2; ++i) {
      int f = i * 512 + tid;
      int r = f >> 3, s = f & 7, sx = s ^ (r & 7);
      gload_lds16(Yp + (size_t)r * 2048 + k0 + sx * 8,
                  (char*)Vs + (i * 512 + wid * 64) * 16);
    }
  };

  STAGE_K(0, 0);
  __syncthreads();
  int cur = 0;
  for (int s = 0; s < nt; ++s) {
    STAGE_V(s);
    __builtin_amdgcn_sched_barrier(0);
    if (s + 1 < nt) STAGE_K(cur ^ 1, s + 1);
    __builtin_amdgcn_sched_barrier(0);

    const char* Kc = (const char*)Ks[cur];
    f32x4 sf[4] = {};
#pragma unroll
    for (int c = 0; c < 4; ++c) {
      const int krow = c * 16 + fr;
#pragma unroll
      for (int dc = 0; dc < 4; ++dc) {
        int slot = (dc * 4 + hi) ^ (krow & 7);
        bf16x8 kf = *(const bf16x8*)(Kc + krow * 256 + slot * 16);
        sf[c] = MFMA_BF16(qf[dc], kf, sf[c]);
      }
    }
    if (s >= sd) {
#pragma unroll
      for (int c = 0; c < 4; ++c) {
        int kcol = s * 64 + c * 16 + fr;
#pragma unroll
        for (int r = 0; r < 4; ++r)
          sf[c][r] = (kcol <= qg + r)
                         ? __builtin_amdgcn_exp2f(sf[c][r] - mr[r]) * rl[r] : 0.f;
      }
    } else {
#pragma unroll
      for (int c = 0; c < 4; ++c)
#pragma unroll
        for (int r = 0; r < 4; ++r)
          sf[c][r] = __builtin_amdgcn_exp2f(sf[c][r] - mr[r]) * rl[r];
    }
#pragma unroll
    for (int c = 0; c < 4; ++c) {
      int col = c * 16 + fr;
      int sseg = col >> 3;
#pragma unroll
      for (int r = 0; r < 4; ++r) {
        int prow = hi * 4 + r;
        int slot = sseg ^ (prow & 7);
        Pw[prow * 64 + slot * 8 + (col & 7)] = __float2bfloat16(sf[c][r]);
      }
    }
    bf16x8 pf[2];
#pragma unroll
    for (int kc = 0; kc < 2; ++kc) {
      int slot = (kc * 4 + hi) ^ (fr & 7);
      pf[kc] = *(const bf16x8*)(Pw + fr * 64 + slot * 8);
    }
    if (s + 1 < nt) asm volatile("s_waitcnt vmcnt(2)" ::: "memory");
    else            asm volatile("s_waitcnt vmcnt(0)" ::: "memory");
    __builtin_amdgcn_s_barrier();
    __builtin_amdgcn_sched_barrier(0);
#pragma unroll
    for (int kc = 0; kc < 2; ++kc)
#pragma unroll
      for (int f = 0; f < 8; ++f) {
        int vrow = f * 16 + fr;
        int vslot = (kc * 4 + hi) ^ (vrow & 7);
        bf16x8 vf = *(const bf16x8*)(Vs + vrow * 64 + vslot * 8);
        accO[f] = MFMA_BF16(pf[kc], vf, accO[f]);
      }
    __syncthreads();
    cur ^= 1;
  }

  const float m1 = *mix1p, m2 = *mix2p;
  const size_t qb = (size_t)bh * 2048 + q0 + wid * 16;
#pragma unroll
  for (int f = 0; f < 8; ++f) {
    int d = f * 16 + fr;
#pragma unroll
    for (int r = 0; r < 4; ++r) {
      int ql = hi * 4 + r;
      float y1v = __bfloat162float(y1n[(qb + ql) * 128 + d]);
      float yv = m1 * y1v + m2 * accO[f][r];
      int q = q0 + wid * 16 + ql;
      ymix[((size_t)b * 2048 + q) * 2048 + h * 128 + d] = __float2bfloat16(yv);
    }
  }
}

// ---------------- launch ----------------
extern "C" void kernel_launch(void* const* d_in, const int* in_sizes, int n_in,
                              void* d_out, int out_size, void* d_ws, size_t ws_size,
                              hipStream_t stream) {
  const float* x    = (const float*)d_in[0];
  const float* cosb = (const float*)d_in[1];
  const float* sinb = (const float*)d_in[2];
  const float* Wq   = (const float*)d_in[3];
  const float* Wk   = (const float*)d_in[4];
  const float* Wv   = (const float*)d_in[5];
  const float* Wp   = (const float*)d_in[6];
  const float* mix1 = (const float*)d_in[7];
  const float* mix2 = (const float*)d_in[8];
  float* out = (float*)d_out;
  char* ws = (char*)d_ws;

  __hip_bfloat16* xb   = (__hip_bfloat16*)(ws + 0);           // 16.78 MB, reused as ymix
  __hip_bfloat16* WTa  = (__hip_bfloat16*)(ws + 16777216);    // 12.58 MB (3072x2048)
  __hip_bfloat16* WpT  = (__hip_bfloat16*)(ws + 29360128);    // 8.39 MB
  float*          qkv  = (float*)(ws + 37748736);             // 50.33 MB (4096x3072 f32)
  __hip_bfloat16* y1n  = (__hip_bfloat16*)(ws + 37748736);    // reuse qkv after rope/v-transpose
  __hip_bfloat16* y1t  = (__hip_bfloat16*)(ws + 54525952);
  float*          Mb   = (float*)(ws + 71303168);
  float*          Lb   = (float*)(ws + 71565312);
  __hip_bfloat16* qTb  = (__hip_bfloat16*)(ws + 88080384);    // (B,H,T,HD)
  __hip_bfloat16* kTb  = (__hip_bfloat16*)(ws + 104857600);   // (B,HK,T,HD)
  __hip_bfloat16* vtb  = (__hip_bfloat16*)(ws + 109051904);   // (B,HK,HD,T)
  __hip_bfloat16* ymix = (__hip_bfloat16*)(ws + 0);

  dim3 tb(32, 8);
  cast_bf16_kernel<<<8192, 256, 0, stream>>>(x, xb, 2097152);
  transpose_cast_kernel<<<dim3(64, 64), tb, 0, stream>>>(Wq, WTa, 2048, 2048);
  transpose_cast_kernel<<<dim3(16, 64), tb, 0, stream>>>(Wk, WTa + (size_t)2048 * 2048, 512, 2048);
  transpose_cast_kernel<<<dim3(16, 64), tb, 0, stream>>>(Wv, WTa + (size_t)2560 * 2048, 512, 2048);
  transpose_cast_kernel<<<dim3(64, 64), tb, 0, stream>>>(Wp, WpT, 2048, 2048);

  gemm_bf16_kernel<<<32 * 24, 256, 0, stream>>>(xb, WTa, qkv, 4096, 3072, 2048);

  rope_rms_kernel<<<20480, 256, 0, stream>>>(qkv, cosb, sinb, qTb, kTb);
  transpose_cast_kernel<<<dim3(16, 64), tb, 0, stream>>>(qkv + 2560, vtb, 3072, 2048);
  transpose_cast_kernel<<<dim3(16, 64), tb, 0, stream>>>(qkv + (size_t)2048 * 3072 + 2560,
                                                         vtb + (size_t)512 * 2048, 3072, 2048);

  attn_pass1_kernel<<<512, 512, 0, stream>>>(qTb, kTb, vtb, y1n, y1t, Mb, Lb);
  attn_pass2_kernel<<<512, 512, 0, stream>>>(qTb, kTb, y1t, y1n, Mb, Lb, mix1, mix2, ymix);

  gemm_bf16_kernel<<<32 * 16, 256, 0, stream>>>(ymix, WpT, out, 4096, 2048, 2048);
}

// Round 5
// 311.966 us; speedup vs baseline: 1.5319x; 1.0237x over previous
//
#include <hip/hip_runtime.h>
#include <hip/hip_bf16.h>
#include <cstdint>
#include <cstddef>

#define AS1 __attribute__((address_space(1)))
#define AS3 __attribute__((address_space(3)))

typedef __attribute__((ext_vector_type(8))) short bf16x8;
typedef __attribute__((ext_vector_type(4))) float f32x4;

__device__ __forceinline__ void gload_lds16(const void* g, void* l) {
  __builtin_amdgcn_global_load_lds((const AS1 void*)g, (AS3 void*)l, 16, 0, 0);
}

#define MFMA_BF16(A, B, C) __builtin_amdgcn_mfma_f32_16x16x32_bf16((A), (B), (C), 0, 0, 0)

// (1/sqrt(128)) * log2(e) — folded into q at rope time; softmax runs in exp2 domain.
#define QSCALE 0.12751744f

// DPP reduce over each 16-lane group
__device__ __forceinline__ float red16_max(float v) {
  int x;
  x = __builtin_amdgcn_update_dpp(0, __builtin_bit_cast(int, v), 0xB1, 0xF, 0xF, true);
  v = fmaxf(v, __builtin_bit_cast(float, x));
  x = __builtin_amdgcn_update_dpp(0, __builtin_bit_cast(int, v), 0x4E, 0xF, 0xF, true);
  v = fmaxf(v, __builtin_bit_cast(float, x));
  x = __builtin_amdgcn_update_dpp(0, __builtin_bit_cast(int, v), 0x141, 0xF, 0xF, true);
  v = fmaxf(v, __builtin_bit_cast(float, x));
  x = __builtin_amdgcn_update_dpp(0, __builtin_bit_cast(int, v), 0x140, 0xF, 0xF, true);
  v = fmaxf(v, __builtin_bit_cast(float, x));
  return v;
}
__device__ __forceinline__ float red16_sum(float v) {
  int x;
  x = __builtin_amdgcn_update_dpp(0, __builtin_bit_cast(int, v), 0xB1, 0xF, 0xF, true);
  v += __builtin_bit_cast(float, x);
  x = __builtin_amdgcn_update_dpp(0, __builtin_bit_cast(int, v), 0x4E, 0xF, 0xF, true);
  v += __builtin_bit_cast(float, x);
  x = __builtin_amdgcn_update_dpp(0, __builtin_bit_cast(int, v), 0x141, 0xF, 0xF, true);
  v += __builtin_bit_cast(float, x);
  x = __builtin_amdgcn_update_dpp(0, __builtin_bit_cast(int, v), 0x140, 0xF, 0xF, true);
  v += __builtin_bit_cast(float, x);
  return v;
}

// ---------------- cast f32 -> bf16 ----------------
__global__ __launch_bounds__(256) void cast_bf16_kernel(const float* __restrict__ in,
                                                        __hip_bfloat16* __restrict__ out,
                                                        int n4) {
  int i = blockIdx.x * 256 + threadIdx.x;
  if (i < n4) {
    float4 v = ((const float4*)in)[i];
    __hip_bfloat16* o = out + (size_t)i * 4;
    o[0] = __float2bfloat16(v.x);
    o[1] = __float2bfloat16(v.y);
    o[2] = __float2bfloat16(v.z);
    o[3] = __float2bfloat16(v.w);
  }
}

// ---------------- merged weight transpose+cast (Wq,Wk,Wv,Wp in one launch) ----------------
__global__ __launch_bounds__(256) void wtrans_kernel(const float* __restrict__ Wq,
                                                     const float* __restrict__ Wk,
                                                     const float* __restrict__ Wv,
                                                     const float* __restrict__ Wp,
                                                     __hip_bfloat16* __restrict__ WTa,
                                                     __hip_bfloat16* __restrict__ WpT) {
  __shared__ float tile[32][33];
  int id = blockIdx.x;
  const float* in; __hip_bfloat16* out; int is, os, bx, by;
  if (id < 4096)      { in = Wq; out = WTa;                          is = 2048; os = 2048; bx = id & 63; by = id >> 6; }
  else if (id < 5120) { int t = id - 4096; in = Wk; out = WTa + (size_t)2048 * 2048; is = 512; os = 2048; bx = t & 15; by = t >> 4; }
  else if (id < 6144) { int t = id - 5120; in = Wv; out = WTa + (size_t)2560 * 2048; is = 512; os = 2048; bx = t & 15; by = t >> 4; }
  else                { int t = id - 6144; in = Wp; out = WpT;       is = 2048; os = 2048; bx = t & 63; by = t >> 6; }
  int c0 = bx * 32, r0 = by * 32;
  int tx = threadIdx.x, ty = threadIdx.y;
#pragma unroll
  for (int i = 0; i < 32; i += 8)
    tile[ty + i][tx] = in[(size_t)(r0 + ty + i) * is + c0 + tx];
  __syncthreads();
#pragma unroll
  for (int i = 0; i < 32; i += 8)
    out[(size_t)(c0 + ty + i) * os + r0 + tx] = __float2bfloat16(tile[tx][ty + i]);
}

// ---------------- v transpose (bf16 qkv -> (B,HK,HD,T)), both b in one launch ----------------
__global__ __launch_bounds__(256) void vtrans_kernel(const __hip_bfloat16* __restrict__ qkv,
                                                     __hip_bfloat16* __restrict__ vt) {
  __shared__ float tile[32][33];
  int b = blockIdx.z;
  const __hip_bfloat16* in = qkv + (size_t)b * 2048 * 3072 + 2560;
  __hip_bfloat16* out = vt + (size_t)b * 512 * 2048;
  int c0 = blockIdx.x * 32, r0 = blockIdx.y * 32;
  int tx = threadIdx.x, ty = threadIdx.y;
#pragma unroll
  for (int i = 0; i < 32; i += 8)
    tile[ty + i][tx] = __bfloat162float(in[(size_t)(r0 + ty + i) * 3072 + c0 + tx]);
  __syncthreads();
#pragma unroll
  for (int i = 0; i < 32; i += 8)
    out[(size_t)(c0 + ty + i) * 2048 + r0 + tx] = __float2bfloat16(tile[tx][ty + i]);
}

// ---------------- bf16 GEMM (m97 structure) + XCD swizzle; CT = float or bf16 ----------------
template <typename CT>
__global__ __launch_bounds__(256) void gemm_bf16_kernel(const __hip_bfloat16* __restrict__ A,
                                                        const __hip_bfloat16* __restrict__ Bt,
                                                        CT* __restrict__ C,
                                                        int M, int N, int K) {
  __shared__ __align__(16) __hip_bfloat16 As[128 * 32];
  __shared__ __align__(16) __hip_bfloat16 Bs[128 * 32];
  const int tid = threadIdx.x;
  const int lane = tid & 63;
  const int wid = tid >> 6;
  const int wm = wid >> 1, wn = wid & 1;
  const int nwg = gridDim.x;                 // multiple of 8
  const int bid = blockIdx.x;
  const int swz = (bid & 7) * (nwg >> 3) + (bid >> 3);   // XCD-contiguous tiles
  const int ntile = N >> 7;
  const int tm = swz / ntile, tn = swz % ntile;
  const int row0 = tm << 7, col0 = tn << 7;

  const int fr = lane & 15;
  const int kg = (lane >> 4) * 8;

  f32x4 acc[4][4] = {};

  for (int k0 = 0; k0 < K; k0 += 32) {
    __syncthreads();
#pragma unroll
    for (int i = 0; i < 2; ++i) {
      int f = i * 256 + tid;
      int r = f >> 2, s = f & 3;
      gload_lds16(A + (size_t)(row0 + r) * K + k0 + s * 8,
                  (char*)As + (i * 256 + wid * 64) * 16);
      gload_lds16(Bt + (size_t)(col0 + r) * K + k0 + s * 8,
                  (char*)Bs + (i * 256 + wid * 64) * 16);
    }
    __syncthreads();
    bf16x8 af[4], bfr[4];
#pragma unroll
    for (int m = 0; m < 4; ++m)
      af[m] = *(const bf16x8*)(As + (wm * 64 + m * 16 + fr) * 32 + kg);
#pragma unroll
    for (int n = 0; n < 4; ++n)
      bfr[n] = *(const bf16x8*)(Bs + (wn * 64 + n * 16 + fr) * 32 + kg);
#pragma unroll
    for (int m = 0; m < 4; ++m)
#pragma unroll
      for (int n = 0; n < 4; ++n)
        acc[m][n] = MFMA_BF16(af[m], bfr[n], acc[m][n]);
  }

  const int cr = (lane >> 4) * 4;
#pragma unroll
  for (int m = 0; m < 4; ++m)
#pragma unroll
    for (int n = 0; n < 4; ++n) {
      int col = col0 + wn * 64 + n * 16 + fr;
#pragma unroll
      for (int r = 0; r < 4; ++r) {
        int row = row0 + wm * 64 + m * 16 + cr + r;
        if constexpr (__is_same(CT, float))
          C[(size_t)row * N + col] = acc[m][n][r];
        else
          C[(size_t)row * N + col] = __float2bfloat16(acc[m][n][r]);
      }
    }
}

// ---------------- RoPE + RMS (bf16 qkv in); q gets QSCALE folded in ----------------
__global__ __launch_bounds__(256) void rope_rms_kernel(const __hip_bfloat16* __restrict__ qkv,
                                                       const float* __restrict__ cosb,
                                                       const float* __restrict__ sinb,
                                                       __hip_bfloat16* __restrict__ qT,
                                                       __hip_bfloat16* __restrict__ kT) {
  int lane = threadIdx.x & 63, wid = threadIdx.x >> 6;
  int task = blockIdx.x * 4 + wid;
  int bt = task / 20, j = task - bt * 20;
  int b = bt >> 11, t = bt & 2047;
  const __hip_bfloat16* src;
  __hip_bfloat16* dst;
  float oscale;
  if (j < 16) {
    src = qkv + (size_t)bt * 3072 + j * 128;
    dst = qT + ((size_t)(b * 16 + j) * 2048 + t) * 128;
    oscale = QSCALE;
  } else {
    src = qkv + (size_t)bt * 3072 + 2048 + (j - 16) * 128;
    dst = kT + ((size_t)(b * 4 + (j - 16)) * 2048 + t) * 128;
    oscale = 1.0f;
  }
  float x1 = __bfloat162float(src[lane]), x2 = __bfloat162float(src[lane + 64]);
  float c = cosb[t * 64 + lane], s = sinb[t * 64 + lane];
  float o1 = x1 * c - x2 * s;
  float o2 = x1 * s + x2 * c;
  float ss = o1 * o1 + o2 * o2;
#pragma unroll
  for (int off = 1; off < 64; off <<= 1) ss += __shfl_xor(ss, off);
  float rn = rsqrtf(ss * (1.f / 128.f) + 1e-6f) * oscale;
  dst[lane] = __float2bfloat16(o1 * rn);
  dst[lane + 64] = __float2bfloat16(o2 * rn);
}

// ---------------- attention pass 1 ----------------
// 512 blocks x 256 threads: 4 fat waves x 32 q-rows = 128-row q-block.
// Each K/V LDS fragment read feeds TWO 16-row accumulator sets (halves LDS pipe load).
// LDS 64KB -> 2 blocks/CU. Single-V schedule with counted vmcnt.
__global__ __launch_bounds__(256, 2) void attn_pass1_kernel(
    const __hip_bfloat16* __restrict__ qT,   // (B,H,T,HD), q pre-scaled
    const __hip_bfloat16* __restrict__ kT,   // (B,HK,T,HD)
    const __hip_bfloat16* __restrict__ vt,   // (B,HK,HD,T)
    __hip_bfloat16* __restrict__ y1n,        // (B,H,T,HD)
    __hip_bfloat16* __restrict__ y1t,        // (B,H,HD,T)
    float* __restrict__ Mb,                  // (B,H,T)  (exp2 domain)
    float* __restrict__ Lb) {
  __shared__ __align__(16) __hip_bfloat16 Ks[2][64 * 128];
  __shared__ __align__(16) __hip_bfloat16 Vs[128 * 64];
  __shared__ __align__(16) __hip_bfloat16 Ps[4][32 * 64];
  const int tid = threadIdx.x, lane = tid & 63, wid = tid >> 6;   // wid 0..3
  const int bi = blockIdx.x;
  const int u = bi & 255, half = bi >> 8;
  const int g = u & 7;                       // (b*4+kvh): XCD-local K/V under rr dispatch
  const int pslot = (u >> 3) & 7;
  const int bh = g * 4 + (u >> 6);
  const int j = half ? (15 - pslot) : pslot;
  const int q0 = j * 128;
  const int nt = 2 * j + 2;
  const int sd = 2 * j + (wid >> 1);         // wave's diagonal k-tile (rows wid*32..+31)
  const __hip_bfloat16* Kp = kT + (size_t)g * 2048 * 128;
  const __hip_bfloat16* Vp = vt + (size_t)g * 128 * 2048;
  const int fr = lane & 15, hi = lane >> 4;

  bf16x8 qf[2][4];
  {
    const __hip_bfloat16* Qp = qT + ((size_t)bh * 2048 + q0 + wid * 32) * 128;
#pragma unroll
    for (int rr = 0; rr < 2; ++rr)
#pragma unroll
      for (int dc = 0; dc < 4; ++dc)
        qf[rr][dc] = *(const bf16x8*)(Qp + (rr * 16 + fr) * 128 + dc * 32 + hi * 8);
  }

  f32x4 accO[2][8] = {};
  float m[2][4], l[2][4];
#pragma unroll
  for (int rr = 0; rr < 2; ++rr)
#pragma unroll
    for (int r = 0; r < 4; ++r) { m[rr][r] = -1e30f; l[rr][r] = 0.f; }

  __hip_bfloat16* Pw = Ps[wid];

  auto STAGE_K = [&](int buf, int kt) {
    const int k0 = kt * 64;
#pragma unroll
    for (int i = 0; i < 4; ++i) {
      int f = i * 256 + tid;
      int r = f >> 4, s = f & 15, sx = s ^ (r & 7);
      gload_lds16(Kp + (size_t)(k0 + r) * 128 + sx * 8,
                  (char*)Ks[buf] + (i * 256 + wid * 64) * 16);
    }
  };
  auto STAGE_V = [&](int kt) {
    const int k0 = kt * 64;
#pragma unroll
    for (int i = 0; i < 4; ++i) {
      int f = i * 256 + tid;
      int r = f >> 3, s = f & 7, sx = s ^ (r & 7);
      gload_lds16(Vp + (size_t)r * 2048 + k0 + sx * 8,
                  (char*)Vs + (i * 256 + wid * 64) * 16);
    }
  };

  STAGE_K(0, 0);
  __syncthreads();
  int cur = 0;
  for (int s = 0; s < nt; ++s) {
    STAGE_V(s);
    __builtin_amdgcn_sched_barrier(0);       // pin V-issue before K-issue (vmcnt order)
    if (s + 1 < nt) STAGE_K(cur ^ 1, s + 1);
    __builtin_amdgcn_sched_barrier(0);

    const bool active = (s <= sd);
    bf16x8 pf[2][2];
    if (active) {
      // ---- QK: 16 shared kf reads, 32 MFMA ----
      const char* Kc = (const char*)Ks[cur];
      f32x4 sf[2][4] = {};
#pragma unroll
      for (int c = 0; c < 4; ++c) {
        const int krow = c * 16 + fr;
#pragma unroll
        for (int dc = 0; dc < 4; ++dc) {
          int slot = (dc * 4 + hi) ^ (krow & 7);
          bf16x8 kf = *(const bf16x8*)(Kc + krow * 256 + slot * 16);
          sf[0][c] = MFMA_BF16(qf[0][dc], kf, sf[0][c]);
          sf[1][c] = MFMA_BF16(qf[1][dc], kf, sf[1][c]);
        }
      }
      // ---- mask + row max ----
      float rmax[2][4];
#pragma unroll
      for (int rr = 0; rr < 2; ++rr)
#pragma unroll
        for (int r = 0; r < 4; ++r) rmax[rr][r] = -1e30f;
      if (s == sd) {
#pragma unroll
        for (int rr = 0; rr < 2; ++rr) {
          const int qgr = q0 + wid * 32 + rr * 16 + hi * 4;
#pragma unroll
          for (int c = 0; c < 4; ++c) {
            int kcol = s * 64 + c * 16 + fr;
#pragma unroll
            for (int r = 0; r < 4; ++r) {
              float sv = (kcol <= qgr + r) ? sf[rr][c][r] : -1e30f;
              sf[rr][c][r] = sv;
              rmax[rr][r] = fmaxf(rmax[rr][r], sv);
            }
          }
        }
      } else {
#pragma unroll
        for (int rr = 0; rr < 2; ++rr)
#pragma unroll
          for (int c = 0; c < 4; ++c)
#pragma unroll
            for (int r = 0; r < 4; ++r) rmax[rr][r] = fmaxf(rmax[rr][r], sf[rr][c][r]);
      }
#pragma unroll
      for (int rr = 0; rr < 2; ++rr)
#pragma unroll
        for (int r = 0; r < 4; ++r) rmax[rr][r] = red16_max(rmax[rr][r]);
      // T13 defer-max
      bool grow = false;
#pragma unroll
      for (int rr = 0; rr < 2; ++rr)
#pragma unroll
        for (int r = 0; r < 4; ++r) grow |= (rmax[rr][r] > m[rr][r] + 8.f);
      if (__any(grow)) {
#pragma unroll
        for (int rr = 0; rr < 2; ++rr)
#pragma unroll
          for (int r = 0; r < 4; ++r) {
            float mn = fmaxf(m[rr][r], rmax[rr][r]);
            float a = __builtin_amdgcn_exp2f(m[rr][r] - mn);
            m[rr][r] = mn;
            l[rr][r] *= a;
#pragma unroll
            for (int f = 0; f < 8; ++f) accO[rr][f][r] *= a;
          }
      }
      float rsum[2][4] = {};
#pragma unroll
      for (int rr = 0; rr < 2; ++rr)
#pragma unroll
        for (int c = 0; c < 4; ++c)
#pragma unroll
          for (int r = 0; r < 4; ++r) {
            float p = __builtin_amdgcn_exp2f(sf[rr][c][r] - m[rr][r]);
            sf[rr][c][r] = p;
            rsum[rr][r] += p;
          }
#pragma unroll
      for (int rr = 0; rr < 2; ++rr)
#pragma unroll
        for (int r = 0; r < 4; ++r) l[rr][r] += red16_sum(rsum[rr][r]);
      // ---- P -> LDS (wave-local, swizzled) + A-frag readback ----
#pragma unroll
      for (int rr = 0; rr < 2; ++rr)
#pragma unroll
        for (int c = 0; c < 4; ++c) {
          int col = c * 16 + fr;
          int sseg = col >> 3;
#pragma unroll
          for (int r = 0; r < 4; ++r) {
            int prow = rr * 16 + hi * 4 + r;
            int slot = sseg ^ ((hi * 4 + r) & 7);
            Pw[prow * 64 + slot * 8 + (col & 7)] = __float2bfloat16(sf[rr][c][r]);
          }
        }
#pragma unroll
      for (int rr = 0; rr < 2; ++rr)
#pragma unroll
        for (int kc = 0; kc < 2; ++kc) {
          int slot = (kc * 4 + hi) ^ (fr & 7);
          pf[rr][kc] = *(const bf16x8*)(Pw + (rr * 16 + fr) * 64 + slot * 8);
        }
    }
    // ---- mid-step: V landed (own 4 loads) + barrier; K(s+1) stays in flight ----
    if (s + 1 < nt) asm volatile("s_waitcnt vmcnt(4)" ::: "memory");
    else            asm volatile("s_waitcnt vmcnt(0)" ::: "memory");
    __builtin_amdgcn_s_barrier();
    __builtin_amdgcn_sched_barrier(0);
    if (active) {
      // ---- PV: 16 shared vf reads, 32 MFMA ----
#pragma unroll
      for (int kc = 0; kc < 2; ++kc)
#pragma unroll
        for (int f = 0; f < 8; ++f) {
          int vrow = f * 16 + fr;
          int vslot = (kc * 4 + hi) ^ (fr & 7);
          bf16x8 vf = *(const bf16x8*)(Vs + vrow * 64 + vslot * 8);
          accO[0][f] = MFMA_BF16(pf[0][kc], vf, accO[0][f]);
          accO[1][f] = MFMA_BF16(pf[1][kc], vf, accO[1][f]);
        }
    }
    __syncthreads();
    cur ^= 1;
  }

#pragma unroll
  for (int rr = 0; rr < 2; ++rr) {
    float rl[4];
#pragma unroll
    for (int r = 0; r < 4; ++r) rl[r] = 1.f / l[rr][r];
    const size_t qb = (size_t)bh * 2048 + q0 + wid * 32 + rr * 16;
#pragma unroll
    for (int f = 0; f < 8; ++f) {
      int d = f * 16 + fr;
#pragma unroll
      for (int r = 0; r < 4; ++r) {
        int ql = hi * 4 + r;
        __hip_bfloat16 yb = __float2bfloat16(accO[rr][f][r] * rl[r]);
        y1n[(qb + ql) * 128 + d] = yb;
        y1t[((size_t)bh * 128 + d) * 2048 + q0 + wid * 32 + rr * 16 + ql] = yb;
      }
    }
    if (fr == 0) {
#pragma unroll
      for (int r = 0; r < 4; ++r) {
        Mb[qb + hi * 4 + r] = m[rr][r];
        Lb[qb + hi * 4 + r] = l[rr][r];
      }
    }
  }
}

// ---------------- attention pass 2: y2 = att @ y1 ; ymix = mix1*y1 + mix2*y2 ----------------
__global__ __launch_bounds__(256, 2) void attn_pass2_kernel(
    const __hip_bfloat16* __restrict__ qT,
    const __hip_bfloat16* __restrict__ kT,
    const __hip_bfloat16* __restrict__ y1t,  // (B,H,HD,T)
    const __hip_bfloat16* __restrict__ y1n,  // (B,H,T,HD)
    const float* __restrict__ Mb,
    const float* __restrict__ Lb,
    const float* __restrict__ mix1p,
    const float* __restrict__ mix2p,
    __hip_bfloat16* __restrict__ ymix) {     // (B,T,C)
  __shared__ __align__(16) __hip_bfloat16 Ks[2][64 * 128];
  __shared__ __align__(16) __hip_bfloat16 Vs[128 * 64];
  __shared__ __align__(16) __hip_bfloat16 Ps[4][32 * 64];
  const int tid = threadIdx.x, lane = tid & 63, wid = tid >> 6;
  const int bi = blockIdx.x;
  const int u = bi & 255, half = bi >> 8;
  const int g = u & 7;
  const int pslot = (u >> 3) & 7;
  const int bh = g * 4 + (u >> 6);
  const int h = bh & 15, b = bh >> 4;
  const int j = half ? (15 - pslot) : pslot;
  const int q0 = j * 128;
  const int nt = 2 * j + 2;
  const int sd = 2 * j + (wid >> 1);
  const __hip_bfloat16* Kp = kT + (size_t)g * 2048 * 128;
  const __hip_bfloat16* Yp = y1t + (size_t)bh * 128 * 2048;
  const int fr = lane & 15, hi = lane >> 4;

  bf16x8 qf[2][4];
  float mr[2][4], rl[2][4];
  {
    const __hip_bfloat16* Qp = qT + ((size_t)bh * 2048 + q0 + wid * 32) * 128;
#pragma unroll
    for (int rr = 0; rr < 2; ++rr)
#pragma unroll
      for (int dc = 0; dc < 4; ++dc)
        qf[rr][dc] = *(const bf16x8*)(Qp + (rr * 16 + fr) * 128 + dc * 32 + hi * 8);
#pragma unroll
    for (int rr = 0; rr < 2; ++rr) {
      const size_t qb = (size_t)bh * 2048 + q0 + wid * 32 + rr * 16;
#pragma unroll
      for (int r = 0; r < 4; ++r) {
        mr[rr][r] = Mb[qb + hi * 4 + r];
        rl[rr][r] = 1.f / Lb[qb + hi * 4 + r];
      }
    }
  }

  f32x4 accO[2][8] = {};
  __hip_bfloat16* Pw = Ps[wid];

  auto STAGE_K = [&](int buf, int kt) {
    const int k0 = kt * 64;
#pragma unroll
    for (int i = 0; i < 4; ++i) {
      int f = i * 256 + tid;
      int r = f >> 4, s = f & 15, sx = s ^ (r & 7);
      gload_lds16(Kp + (size_t)(k0 + r) * 128 + sx * 8,
                  (char*)Ks[buf] + (i * 256 + wid * 64) * 16);
    }
  };
  auto STAGE_V = [&](int kt) {
    const int k0 = kt * 64;
#pragma unroll
    for (int i = 0; i < 4; ++i) {
      int f = i * 256 + tid;
      int r = f >> 3, s = f & 7, sx = s ^ (r & 7);
      gload_lds16(Yp + (size_t)r * 2048 + k0 + sx * 8,
                  (char*)Vs + (i * 256 + wid * 64) * 16);
    }
  };

  STAGE_K(0, 0);
  __syncthreads();
  int cur = 0;
  for (int s = 0; s < nt; ++s) {
    STAGE_V(s);
    __builtin_amdgcn_sched_barrier(0);
    if (s + 1 < nt) STAGE_K(cur ^ 1, s + 1);
    __builtin_amdgcn_sched_barrier(0);

    const bool active = (s <= sd);
    bf16x8 pf[2][2];
    if (active) {
      const char* Kc = (const char*)Ks[cur];
      f32x4 sf[2][4] = {};
#pragma unroll
      for (int c = 0; c < 4; ++c) {
        const int krow = c * 16 + fr;
#pragma unroll
        for (int dc = 0; dc < 4; ++dc) {
          int slot = (dc * 4 + hi) ^ (krow & 7);
          bf16x8 kf = *(const bf16x8*)(Kc + krow * 256 + slot * 16);
          sf[0][c] = MFMA_BF16(qf[0][dc], kf, sf[0][c]);
          sf[1][c] = MFMA_BF16(qf[1][dc], kf, sf[1][c]);
        }
      }
      if (s == sd) {
#pragma unroll
        for (int rr = 0; rr < 2; ++rr) {
          const int qgr = q0 + wid * 32 + rr * 16 + hi * 4;
#pragma unroll
          for (int c = 0; c < 4; ++c) {
            int kcol = s * 64 + c * 16 + fr;
#pragma unroll
            for (int r = 0; r < 4; ++r)
              sf[rr][c][r] = (kcol <= qgr + r)
                  ? __builtin_amdgcn_exp2f(sf[rr][c][r] - mr[rr][r]) * rl[rr][r] : 0.f;
          }
        }
      } else {
#pragma unroll
        for (int rr = 0; rr < 2; ++rr)
#pragma unroll
          for (int c = 0; c < 4; ++c)
#pragma unroll
            for (int r = 0; r < 4; ++r)
              sf[rr][c][r] = __builtin_amdgcn_exp2f(sf[rr][c][r] - mr[rr][r]) * rl[rr][r];
      }
#pragma unroll
      for (int rr = 0; rr < 2; ++rr)
#pragma unroll
        for (int c = 0; c < 4; ++c) {
          int col = c * 16 + fr;
          int sseg = col >> 3;
#pragma unroll
          for (int r = 0; r < 4; ++r) {
            int prow = rr * 16 + hi * 4 + r;
            int slot = sseg ^ ((hi * 4 + r) & 7);
            Pw[prow * 64 + slot * 8 + (col & 7)] = __float2bfloat16(sf[rr][c][r]);
          }
        }
#pragma unroll
      for (int rr = 0; rr < 2; ++rr)
#pragma unroll
        for (int kc = 0; kc < 2; ++kc) {
          int slot = (kc * 4 + hi) ^ (fr & 7);
          pf[rr][kc] = *(const bf16x8*)(Pw + (rr * 16 + fr) * 64 + slot * 8);
        }
    }
    if (s + 1 < nt) asm volatile("s_waitcnt vmcnt(4)" ::: "memory");
    else            asm volatile("s_waitcnt vmcnt(0)" ::: "memory");
    __builtin_amdgcn_s_barrier();
    __builtin_amdgcn_sched_barrier(0);
    if (active) {
#pragma unroll
      for (int kc = 0; kc < 2; ++kc)
#pragma unroll
        for (int f = 0; f < 8; ++f) {
          int vrow = f * 16 + fr;
          int vslot = (kc * 4 + hi) ^ (fr & 7);
          bf16x8 vf = *(const bf16x8*)(Vs + vrow * 64 + vslot * 8);
          accO[0][f] = MFMA_BF16(pf[0][kc], vf, accO[0][f]);
          accO[1][f] = MFMA_BF16(pf[1][kc], vf, accO[1][f]);
        }
    }
    __syncthreads();
    cur ^= 1;
  }

  const float m1 = *mix1p, m2 = *mix2p;
#pragma unroll
  for (int rr = 0; rr < 2; ++rr) {
    const size_t qb = (size_t)bh * 2048 + q0 + wid * 32 + rr * 16;
#pragma unroll
    for (int f = 0; f < 8; ++f) {
      int d = f * 16 + fr;
#pragma unroll
      for (int r = 0; r < 4; ++r) {
        int ql = hi * 4 + r;
        float y1v = __bfloat162float(y1n[(qb + ql) * 128 + d]);
        float yv = m1 * y1v + m2 * accO[rr][f][r];
        int q = q0 + wid * 32 + rr * 16 + ql;
        ymix[((size_t)b * 2048 + q) * 2048 + h * 128 + d] = __float2bfloat16(yv);
      }
    }
  }
}

// ---------------- launch ----------------
extern "C" void kernel_launch(void* const* d_in, const int* in_sizes, int n_in,
                              void* d_out, int out_size, void* d_ws, size_t ws_size,
                              hipStream_t stream) {
  const float* x    = (const float*)d_in[0];
  const float* cosb = (const float*)d_in[1];
  const float* sinb = (const float*)d_in[2];
  const float* Wq   = (const float*)d_in[3];
  const float* Wk   = (const float*)d_in[4];
  const float* Wv   = (const float*)d_in[5];
  const float* Wp   = (const float*)d_in[6];
  const float* mix1 = (const float*)d_in[7];
  const float* mix2 = (const float*)d_in[8];
  float* out = (float*)d_out;
  char* ws = (char*)d_ws;

  __hip_bfloat16* xb   = (__hip_bfloat16*)(ws + 0);           // 16.78 MB, reused as ymix
  __hip_bfloat16* WTa  = (__hip_bfloat16*)(ws + 16777216);    // 12.58 MB (3072x2048)
  __hip_bfloat16* WpT  = (__hip_bfloat16*)(ws + 29360128);    // 8.39 MB
  __hip_bfloat16* qkvb = (__hip_bfloat16*)(ws + 37748736);    // 25.2 MB (4096x3072 bf16)
  __hip_bfloat16* y1n  = (__hip_bfloat16*)(ws + 37748736);    // reuse qkv after rope/v-trans
  __hip_bfloat16* y1t  = (__hip_bfloat16*)(ws + 54525952);
  float*          Mb   = (float*)(ws + 71303168);
  float*          Lb   = (float*)(ws + 71565312);
  __hip_bfloat16* qTb  = (__hip_bfloat16*)(ws + 88080384);    // (B,H,T,HD)
  __hip_bfloat16* kTb  = (__hip_bfloat16*)(ws + 104857600);   // (B,HK,T,HD)
  __hip_bfloat16* vtb  = (__hip_bfloat16*)(ws + 109051904);   // (B,HK,HD,T)
  __hip_bfloat16* ymix = (__hip_bfloat16*)(ws + 0);

  dim3 tb(32, 8);
  cast_bf16_kernel<<<8192, 256, 0, stream>>>(x, xb, 2097152);
  wtrans_kernel<<<10240, tb, 0, stream>>>(Wq, Wk, Wv, Wp, WTa, WpT);

  gemm_bf16_kernel<__hip_bfloat16><<<768, 256, 0, stream>>>(xb, WTa, qkvb, 4096, 3072, 2048);

  rope_rms_kernel<<<20480, 256, 0, stream>>>(qkvb, cosb, sinb, qTb, kTb);
  vtrans_kernel<<<dim3(16, 64, 2), tb, 0, stream>>>(qkvb, vtb);

  attn_pass1_kernel<<<512, 256, 0, stream>>>(qTb, kTb, vtb, y1n, y1t, Mb, Lb);
  attn_pass2_kernel<<<512, 256, 0, stream>>>(qTb, kTb, y1t, y1n, Mb, Lb, mix1, mix2, ymix);

  gemm_bf16_kernel<float><<<512, 256, 0, stream>>>(ymix, WpT, out, 4096, 2048, 2048);
}

// Round 6
// 302.344 us; speedup vs baseline: 1.5806x; 1.0318x over previous
//
#include <hip/hip_runtime.h>
#include <hip/hip_bf16.h>
#include <cstdint>
#include <cstddef>

#define AS1 __attribute__((address_space(1)))
#define AS3 __attribute__((address_space(3)))

typedef __attribute__((ext_vector_type(8))) short bf16x8;
typedef __attribute__((ext_vector_type(4))) float f32x4;

__device__ __forceinline__ void gload_lds16(const void* g, void* l) {
  __builtin_amdgcn_global_load_lds((const AS1 void*)g, (AS3 void*)l, 16, 0, 0);
}

#define MFMA_BF16(A, B, C) __builtin_amdgcn_mfma_f32_16x16x32_bf16((A), (B), (C), 0, 0, 0)

// (1/sqrt(128)) * log2(e) — folded into q at rope time; softmax runs in exp2 domain.
#define QSCALE 0.12751744f

// DPP reduce over each 16-lane group
__device__ __forceinline__ float red16_max(float v) {
  int x;
  x = __builtin_amdgcn_update_dpp(0, __builtin_bit_cast(int, v), 0xB1, 0xF, 0xF, true);
  v = fmaxf(v, __builtin_bit_cast(float, x));
  x = __builtin_amdgcn_update_dpp(0, __builtin_bit_cast(int, v), 0x4E, 0xF, 0xF, true);
  v = fmaxf(v, __builtin_bit_cast(float, x));
  x = __builtin_amdgcn_update_dpp(0, __builtin_bit_cast(int, v), 0x141, 0xF, 0xF, true);
  v = fmaxf(v, __builtin_bit_cast(float, x));
  x = __builtin_amdgcn_update_dpp(0, __builtin_bit_cast(int, v), 0x140, 0xF, 0xF, true);
  v = fmaxf(v, __builtin_bit_cast(float, x));
  return v;
}
__device__ __forceinline__ float red16_sum(float v) {
  int x;
  x = __builtin_amdgcn_update_dpp(0, __builtin_bit_cast(int, v), 0xB1, 0xF, 0xF, true);
  v += __builtin_bit_cast(float, x);
  x = __builtin_amdgcn_update_dpp(0, __builtin_bit_cast(int, v), 0x4E, 0xF, 0xF, true);
  v += __builtin_bit_cast(float, x);
  x = __builtin_amdgcn_update_dpp(0, __builtin_bit_cast(int, v), 0x141, 0xF, 0xF, true);
  v += __builtin_bit_cast(float, x);
  x = __builtin_amdgcn_update_dpp(0, __builtin_bit_cast(int, v), 0x140, 0xF, 0xF, true);
  v += __builtin_bit_cast(float, x);
  return v;
}

// ---------------- cast f32 -> bf16 ----------------
__global__ __launch_bounds__(256) void cast_bf16_kernel(const float* __restrict__ in,
                                                        __hip_bfloat16* __restrict__ out,
                                                        int n4) {
  int i = blockIdx.x * 256 + threadIdx.x;
  if (i < n4) {
    float4 v = ((const float4*)in)[i];
    __hip_bfloat16* o = out + (size_t)i * 4;
    o[0] = __float2bfloat16(v.x);
    o[1] = __float2bfloat16(v.y);
    o[2] = __float2bfloat16(v.z);
    o[3] = __float2bfloat16(v.w);
  }
}

// ---------------- merged weight transpose+cast (Wq,Wk,Wv,Wp in one launch) ----------------
__global__ __launch_bounds__(256) void wtrans_kernel(const float* __restrict__ Wq,
                                                     const float* __restrict__ Wk,
                                                     const float* __restrict__ Wv,
                                                     const float* __restrict__ Wp,
                                                     __hip_bfloat16* __restrict__ WTa,
                                                     __hip_bfloat16* __restrict__ WpT) {
  __shared__ float tile[32][33];
  int id = blockIdx.x;
  const float* in; __hip_bfloat16* out; int is, os, bx, by;
  if (id < 4096)      { in = Wq; out = WTa;                          is = 2048; os = 2048; bx = id & 63; by = id >> 6; }
  else if (id < 5120) { int t = id - 4096; in = Wk; out = WTa + (size_t)2048 * 2048; is = 512; os = 2048; bx = t & 15; by = t >> 4; }
  else if (id < 6144) { int t = id - 5120; in = Wv; out = WTa + (size_t)2560 * 2048; is = 512; os = 2048; bx = t & 15; by = t >> 4; }
  else                { int t = id - 6144; in = Wp; out = WpT;       is = 2048; os = 2048; bx = t & 63; by = t >> 6; }
  int c0 = bx * 32, r0 = by * 32;
  int tx = threadIdx.x, ty = threadIdx.y;
#pragma unroll
  for (int i = 0; i < 32; i += 8)
    tile[ty + i][tx] = in[(size_t)(r0 + ty + i) * is + c0 + tx];
  __syncthreads();
#pragma unroll
  for (int i = 0; i < 32; i += 8)
    out[(size_t)(c0 + ty + i) * os + r0 + tx] = __float2bfloat16(tile[tx][ty + i]);
}

// ---------------- v transpose (bf16 qkv -> (B,HK,HD,T)), both b in one launch ----------------
__global__ __launch_bounds__(256) void vtrans_kernel(const __hip_bfloat16* __restrict__ qkv,
                                                     __hip_bfloat16* __restrict__ vt) {
  __shared__ float tile[32][33];
  int b = blockIdx.z;
  const __hip_bfloat16* in = qkv + (size_t)b * 2048 * 3072 + 2560;
  __hip_bfloat16* out = vt + (size_t)b * 512 * 2048;
  int c0 = blockIdx.x * 32, r0 = blockIdx.y * 32;
  int tx = threadIdx.x, ty = threadIdx.y;
#pragma unroll
  for (int i = 0; i < 32; i += 8)
    tile[ty + i][tx] = __bfloat162float(in[(size_t)(r0 + ty + i) * 3072 + c0 + tx]);
  __syncthreads();
#pragma unroll
  for (int i = 0; i < 32; i += 8)
    out[(size_t)(c0 + ty + i) * 2048 + r0 + tx] = __float2bfloat16(tile[tx][ty + i]);
}

// ---------------- bf16 GEMM (m97 structure) + XCD swizzle; CT = float or bf16 ----------------
template <typename CT>
__global__ __launch_bounds__(256) void gemm_bf16_kernel(const __hip_bfloat16* __restrict__ A,
                                                        const __hip_bfloat16* __restrict__ Bt,
                                                        CT* __restrict__ C,
                                                        int M, int N, int K) {
  __shared__ __align__(16) __hip_bfloat16 As[128 * 32];
  __shared__ __align__(16) __hip_bfloat16 Bs[128 * 32];
  const int tid = threadIdx.x;
  const int lane = tid & 63;
  const int wid = tid >> 6;
  const int wm = wid >> 1, wn = wid & 1;
  const int nwg = gridDim.x;                 // multiple of 8
  const int bid = blockIdx.x;
  const int swz = (bid & 7) * (nwg >> 3) + (bid >> 3);   // XCD-contiguous tiles
  const int ntile = N >> 7;
  const int tm = swz / ntile, tn = swz % ntile;
  const int row0 = tm << 7, col0 = tn << 7;

  const int fr = lane & 15;
  const int kg = (lane >> 4) * 8;

  f32x4 acc[4][4] = {};

  for (int k0 = 0; k0 < K; k0 += 32) {
    __syncthreads();
#pragma unroll
    for (int i = 0; i < 2; ++i) {
      int f = i * 256 + tid;
      int r = f >> 2, s = f & 3;
      gload_lds16(A + (size_t)(row0 + r) * K + k0 + s * 8,
                  (char*)As + (i * 256 + wid * 64) * 16);
      gload_lds16(Bt + (size_t)(col0 + r) * K + k0 + s * 8,
                  (char*)Bs + (i * 256 + wid * 64) * 16);
    }
    __syncthreads();
    bf16x8 af[4], bfr[4];
#pragma unroll
    for (int m = 0; m < 4; ++m)
      af[m] = *(const bf16x8*)(As + (wm * 64 + m * 16 + fr) * 32 + kg);
#pragma unroll
    for (int n = 0; n < 4; ++n)
      bfr[n] = *(const bf16x8*)(Bs + (wn * 64 + n * 16 + fr) * 32 + kg);
#pragma unroll
    for (int m = 0; m < 4; ++m)
#pragma unroll
      for (int n = 0; n < 4; ++n)
        acc[m][n] = MFMA_BF16(af[m], bfr[n], acc[m][n]);
  }

  const int cr = (lane >> 4) * 4;
#pragma unroll
  for (int m = 0; m < 4; ++m)
#pragma unroll
    for (int n = 0; n < 4; ++n) {
      int col = col0 + wn * 64 + n * 16 + fr;
#pragma unroll
      for (int r = 0; r < 4; ++r) {
        int row = row0 + wm * 64 + m * 16 + cr + r;
        if constexpr (__is_same(CT, float))
          C[(size_t)row * N + col] = acc[m][n][r];
        else
          C[(size_t)row * N + col] = __float2bfloat16(acc[m][n][r]);
      }
    }
}

// ---------------- RoPE + RMS (bf16 qkv in); q gets QSCALE folded in ----------------
__global__ __launch_bounds__(256) void rope_rms_kernel(const __hip_bfloat16* __restrict__ qkv,
                                                       const float* __restrict__ cosb,
                                                       const float* __restrict__ sinb,
                                                       __hip_bfloat16* __restrict__ qT,
                                                       __hip_bfloat16* __restrict__ kT) {
  int lane = threadIdx.x & 63, wid = threadIdx.x >> 6;
  int task = blockIdx.x * 4 + wid;
  int bt = task / 20, j = task - bt * 20;
  int b = bt >> 11, t = bt & 2047;
  const __hip_bfloat16* src;
  __hip_bfloat16* dst;
  float oscale;
  if (j < 16) {
    src = qkv + (size_t)bt * 3072 + j * 128;
    dst = qT + ((size_t)(b * 16 + j) * 2048 + t) * 128;
    oscale = QSCALE;
  } else {
    src = qkv + (size_t)bt * 3072 + 2048 + (j - 16) * 128;
    dst = kT + ((size_t)(b * 4 + (j - 16)) * 2048 + t) * 128;
    oscale = 1.0f;
  }
  float x1 = __bfloat162float(src[lane]), x2 = __bfloat162float(src[lane + 64]);
  float c = cosb[t * 64 + lane], s = sinb[t * 64 + lane];
  float o1 = x1 * c - x2 * s;
  float o2 = x1 * s + x2 * c;
  float ss = o1 * o1 + o2 * o2;
#pragma unroll
  for (int off = 1; off < 64; off <<= 1) ss += __shfl_xor(ss, off);
  float rn = rsqrtf(ss * (1.f / 128.f) + 1e-6f) * oscale;
  dst[lane] = __float2bfloat16(o1 * rn);
  dst[lane + 64] = __float2bfloat16(o2 * rn);
}

// block decode shared by both attention passes:
// bi in [0,512): u=bi&255, half=bi>>8. g=u&7 = (b*4+kvh) -> XCD-local K/V set under
// rr dispatch. bi and bi+256 (two halves of a balanced pair, 34 steps total) land on
// the same CU under rr dispatch: per-CU balance at 2 blocks/CU.

// ---------------- attention pass 1 ----------------
// 512 blocks x 256 threads: 4 fat waves x 32 q-rows = 128-row q-block.
// Fully double-buffered K AND V (80KB LDS, 2 blocks/CU). Two RAW barriers per step,
// counted vmcnt(8) — no full vmcnt(0) drain in the loop, so the 8 prefetch loads
// for step s+1 stay in flight under step s's compute (T3/T4 pattern).
__global__ __launch_bounds__(256, 2) void attn_pass1_kernel(
    const __hip_bfloat16* __restrict__ qT,   // (B,H,T,HD), q pre-scaled
    const __hip_bfloat16* __restrict__ kT,   // (B,HK,T,HD)
    const __hip_bfloat16* __restrict__ vt,   // (B,HK,HD,T)
    __hip_bfloat16* __restrict__ y1n,        // (B,H,T,HD)
    __hip_bfloat16* __restrict__ y1t,        // (B,H,HD,T)
    float* __restrict__ Mb,                  // (B,H,T)  (exp2 domain)
    float* __restrict__ Lb) {
  __shared__ __align__(16) __hip_bfloat16 Ks[2][64 * 128];
  __shared__ __align__(16) __hip_bfloat16 Vs[2][128 * 64];
  __shared__ __align__(16) __hip_bfloat16 Ps[4][32 * 64];
  const int tid = threadIdx.x, lane = tid & 63, wid = tid >> 6;   // wid 0..3
  const int bi = blockIdx.x;
  const int u = bi & 255, half = bi >> 8;
  const int g = u & 7;
  const int pslot = (u >> 3) & 7;
  const int bh = g * 4 + (u >> 6);
  const int j = half ? (15 - pslot) : pslot;
  const int q0 = j * 128;
  const int nt = 2 * j + 2;
  const int sd = 2 * j + (wid >> 1);         // wave's diagonal k-tile (rows wid*32..+31)
  const __hip_bfloat16* Kp = kT + (size_t)g * 2048 * 128;
  const __hip_bfloat16* Vp = vt + (size_t)g * 128 * 2048;
  const int fr = lane & 15, hi = lane >> 4;

  bf16x8 qf[2][4];
  {
    const __hip_bfloat16* Qp = qT + ((size_t)bh * 2048 + q0 + wid * 32) * 128;
#pragma unroll
    for (int rr = 0; rr < 2; ++rr)
#pragma unroll
      for (int dc = 0; dc < 4; ++dc)
        qf[rr][dc] = *(const bf16x8*)(Qp + (rr * 16 + fr) * 128 + dc * 32 + hi * 8);
  }

  f32x4 accO[2][8] = {};
  float m[2][4], l[2][4];
#pragma unroll
  for (int rr = 0; rr < 2; ++rr)
#pragma unroll
    for (int r = 0; r < 4; ++r) { m[rr][r] = -1e30f; l[rr][r] = 0.f; }

  __hip_bfloat16* Pw = Ps[wid];

  auto STAGE = [&](int buf, int kt) {       // 8 global_load_lds (4 K + 4 V)
    const int k0 = kt * 64;
#pragma unroll
    for (int i = 0; i < 4; ++i) {
      int f = i * 256 + tid;
      int r = f >> 4, s = f & 15, sx = s ^ (r & 7);
      gload_lds16(Kp + (size_t)(k0 + r) * 128 + sx * 8,
                  (char*)Ks[buf] + (i * 256 + wid * 64) * 16);
    }
#pragma unroll
    for (int i = 0; i < 4; ++i) {
      int f = i * 256 + tid;
      int r = f >> 3, s = f & 7, sx = s ^ (r & 7);
      gload_lds16(Vp + (size_t)r * 2048 + k0 + sx * 8,
                  (char*)Vs[buf] + (i * 256 + wid * 64) * 16);
    }
  };

  STAGE(0, 0);
  int cur = 0;
  for (int s = 0; s < nt; ++s) {
    if (s > 0) __builtin_amdgcn_s_barrier();   // G: compute(s-1) closed; buf[cur^1] free
    __builtin_amdgcn_sched_barrier(0);
    if (s + 1 < nt) STAGE(cur ^ 1, s + 1);     // prefetch next tile (8 loads in flight)
    __builtin_amdgcn_sched_barrier(0);
    if (s + 1 < nt) asm volatile("s_waitcnt vmcnt(8)" ::: "memory");  // own K(s),V(s) landed
    else            asm volatile("s_waitcnt vmcnt(0)" ::: "memory");
    __builtin_amdgcn_s_barrier();              // C: ALL waves' K(s),V(s) landed
    __builtin_amdgcn_sched_barrier(0);

    const bool active = (s <= sd);
    if (active) {
      // ---- QK: 16 shared kf reads, 32 MFMA ----
      const char* Kc = (const char*)Ks[cur];
      f32x4 sf[2][4] = {};
#pragma unroll
      for (int c = 0; c < 4; ++c) {
        const int krow = c * 16 + fr;
#pragma unroll
        for (int dc = 0; dc < 4; ++dc) {
          int slot = (dc * 4 + hi) ^ (krow & 7);
          bf16x8 kf = *(const bf16x8*)(Kc + krow * 256 + slot * 16);
          sf[0][c] = MFMA_BF16(qf[0][dc], kf, sf[0][c]);
          sf[1][c] = MFMA_BF16(qf[1][dc], kf, sf[1][c]);
        }
      }
      // ---- mask + row max ----
      float rmax[2][4];
#pragma unroll
      for (int rr = 0; rr < 2; ++rr)
#pragma unroll
        for (int r = 0; r < 4; ++r) rmax[rr][r] = -1e30f;
      if (s == sd) {
#pragma unroll
        for (int rr = 0; rr < 2; ++rr) {
          const int qgr = q0 + wid * 32 + rr * 16 + hi * 4;
#pragma unroll
          for (int c = 0; c < 4; ++c) {
            int kcol = s * 64 + c * 16 + fr;
#pragma unroll
            for (int r = 0; r < 4; ++r) {
              float sv = (kcol <= qgr + r) ? sf[rr][c][r] : -1e30f;
              sf[rr][c][r] = sv;
              rmax[rr][r] = fmaxf(rmax[rr][r], sv);
            }
          }
        }
      } else {
#pragma unroll
        for (int rr = 0; rr < 2; ++rr)
#pragma unroll
          for (int c = 0; c < 4; ++c)
#pragma unroll
            for (int r = 0; r < 4; ++r) rmax[rr][r] = fmaxf(rmax[rr][r], sf[rr][c][r]);
      }
#pragma unroll
      for (int rr = 0; rr < 2; ++rr)
#pragma unroll
        for (int r = 0; r < 4; ++r) rmax[rr][r] = red16_max(rmax[rr][r]);
      // T13 defer-max
      bool grow = false;
#pragma unroll
      for (int rr = 0; rr < 2; ++rr)
#pragma unroll
        for (int r = 0; r < 4; ++r) grow |= (rmax[rr][r] > m[rr][r] + 8.f);
      if (__any(grow)) {
#pragma unroll
        for (int rr = 0; rr < 2; ++rr)
#pragma unroll
          for (int r = 0; r < 4; ++r) {
            float mn = fmaxf(m[rr][r], rmax[rr][r]);
            float a = __builtin_amdgcn_exp2f(m[rr][r] - mn);
            m[rr][r] = mn;
            l[rr][r] *= a;
#pragma unroll
            for (int f = 0; f < 8; ++f) accO[rr][f][r] *= a;
          }
      }
      float rsum[2][4] = {};
#pragma unroll
      for (int rr = 0; rr < 2; ++rr)
#pragma unroll
        for (int c = 0; c < 4; ++c)
#pragma unroll
          for (int r = 0; r < 4; ++r) {
            float p = __builtin_amdgcn_exp2f(sf[rr][c][r] - m[rr][r]);
            sf[rr][c][r] = p;
            rsum[rr][r] += p;
          }
#pragma unroll
      for (int rr = 0; rr < 2; ++rr)
#pragma unroll
        for (int r = 0; r < 4; ++r) l[rr][r] += red16_sum(rsum[rr][r]);
      // ---- P -> LDS (wave-local, swizzled) + A-frag readback ----
#pragma unroll
      for (int rr = 0; rr < 2; ++rr)
#pragma unroll
        for (int c = 0; c < 4; ++c) {
          int col = c * 16 + fr;
          int sseg = col >> 3;
#pragma unroll
          for (int r = 0; r < 4; ++r) {
            int prow = rr * 16 + hi * 4 + r;
            int slot = sseg ^ ((hi * 4 + r) & 7);
            Pw[prow * 64 + slot * 8 + (col & 7)] = __float2bfloat16(sf[rr][c][r]);
          }
        }
      bf16x8 pf[2][2];
#pragma unroll
      for (int rr = 0; rr < 2; ++rr)
#pragma unroll
        for (int kc = 0; kc < 2; ++kc) {
          int slot = (kc * 4 + hi) ^ (fr & 7);
          pf[rr][kc] = *(const bf16x8*)(Pw + (rr * 16 + fr) * 64 + slot * 8);
        }
      // ---- PV: 16 shared vf reads, 32 MFMA ----
      const __hip_bfloat16* Vc = Vs[cur];
#pragma unroll
      for (int kc = 0; kc < 2; ++kc)
#pragma unroll
        for (int f = 0; f < 8; ++f) {
          int vrow = f * 16 + fr;
          int vslot = (kc * 4 + hi) ^ (fr & 7);
          bf16x8 vf = *(const bf16x8*)(Vc + vrow * 64 + vslot * 8);
          accO[0][f] = MFMA_BF16(pf[0][kc], vf, accO[0][f]);
          accO[1][f] = MFMA_BF16(pf[1][kc], vf, accO[1][f]);
        }
    }
    cur ^= 1;
  }

#pragma unroll
  for (int rr = 0; rr < 2; ++rr) {
    float rl[4];
#pragma unroll
    for (int r = 0; r < 4; ++r) rl[r] = 1.f / l[rr][r];
    const size_t qb = (size_t)bh * 2048 + q0 + wid * 32 + rr * 16;
#pragma unroll
    for (int f = 0; f < 8; ++f) {
      int d = f * 16 + fr;
#pragma unroll
      for (int r = 0; r < 4; ++r) {
        int ql = hi * 4 + r;
        __hip_bfloat16 yb = __float2bfloat16(accO[rr][f][r] * rl[r]);
        y1n[(qb + ql) * 128 + d] = yb;
        y1t[((size_t)bh * 128 + d) * 2048 + q0 + wid * 32 + rr * 16 + ql] = yb;
      }
    }
    if (fr == 0) {
#pragma unroll
      for (int r = 0; r < 4; ++r) {
        Mb[qb + hi * 4 + r] = m[rr][r];
        Lb[qb + hi * 4 + r] = l[rr][r];
      }
    }
  }
}

// ---------------- attention pass 2: y2 = att @ y1 ; ymix = mix1*y1 + mix2*y2 ----------------
__global__ __launch_bounds__(256, 2) void attn_pass2_kernel(
    const __hip_bfloat16* __restrict__ qT,
    const __hip_bfloat16* __restrict__ kT,
    const __hip_bfloat16* __restrict__ y1t,  // (B,H,HD,T)
    const __hip_bfloat16* __restrict__ y1n,  // (B,H,T,HD)
    const float* __restrict__ Mb,
    const float* __restrict__ Lb,
    const float* __restrict__ mix1p,
    const float* __restrict__ mix2p,
    __hip_bfloat16* __restrict__ ymix) {     // (B,T,C)
  __shared__ __align__(16) __hip_bfloat16 Ks[2][64 * 128];
  __shared__ __align__(16) __hip_bfloat16 Vs[2][128 * 64];
  __shared__ __align__(16) __hip_bfloat16 Ps[4][32 * 64];
  const int tid = threadIdx.x, lane = tid & 63, wid = tid >> 6;
  const int bi = blockIdx.x;
  const int u = bi & 255, half = bi >> 8;
  const int g = u & 7;
  const int pslot = (u >> 3) & 7;
  const int bh = g * 4 + (u >> 6);
  const int h = bh & 15, b = bh >> 4;
  const int j = half ? (15 - pslot) : pslot;
  const int q0 = j * 128;
  const int nt = 2 * j + 2;
  const int sd = 2 * j + (wid >> 1);
  const __hip_bfloat16* Kp = kT + (size_t)g * 2048 * 128;
  const __hip_bfloat16* Yp = y1t + (size_t)bh * 128 * 2048;
  const int fr = lane & 15, hi = lane >> 4;

  bf16x8 qf[2][4];
  float mr[2][4], rl[2][4];
  {
    const __hip_bfloat16* Qp = qT + ((size_t)bh * 2048 + q0 + wid * 32) * 128;
#pragma unroll
    for (int rr = 0; rr < 2; ++rr)
#pragma unroll
      for (int dc = 0; dc < 4; ++dc)
        qf[rr][dc] = *(const bf16x8*)(Qp + (rr * 16 + fr) * 128 + dc * 32 + hi * 8);
#pragma unroll
    for (int rr = 0; rr < 2; ++rr) {
      const size_t qb = (size_t)bh * 2048 + q0 + wid * 32 + rr * 16;
#pragma unroll
      for (int r = 0; r < 4; ++r) {
        mr[rr][r] = Mb[qb + hi * 4 + r];
        rl[rr][r] = 1.f / Lb[qb + hi * 4 + r];
      }
    }
  }

  f32x4 accO[2][8] = {};
  __hip_bfloat16* Pw = Ps[wid];

  auto STAGE = [&](int buf, int kt) {
    const int k0 = kt * 64;
#pragma unroll
    for (int i = 0; i < 4; ++i) {
      int f = i * 256 + tid;
      int r = f >> 4, s = f & 15, sx = s ^ (r & 7);
      gload_lds16(Kp + (size_t)(k0 + r) * 128 + sx * 8,
                  (char*)Ks[buf] + (i * 256 + wid * 64) * 16);
    }
#pragma unroll
    for (int i = 0; i < 4; ++i) {
      int f = i * 256 + tid;
      int r = f >> 3, s = f & 7, sx = s ^ (r & 7);
      gload_lds16(Yp + (size_t)r * 2048 + k0 + sx * 8,
                  (char*)Vs[buf] + (i * 256 + wid * 64) * 16);
    }
  };

  STAGE(0, 0);
  int cur = 0;
  for (int s = 0; s < nt; ++s) {
    if (s > 0) __builtin_amdgcn_s_barrier();
    __builtin_amdgcn_sched_barrier(0);
    if (s + 1 < nt) STAGE(cur ^ 1, s + 1);
    __builtin_amdgcn_sched_barrier(0);
    if (s + 1 < nt) asm volatile("s_waitcnt vmcnt(8)" ::: "memory");
    else            asm volatile("s_waitcnt vmcnt(0)" ::: "memory");
    __builtin_amdgcn_s_barrier();
    __builtin_amdgcn_sched_barrier(0);

    const bool active = (s <= sd);
    if (active) {
      const char* Kc = (const char*)Ks[cur];
      f32x4 sf[2][4] = {};
#pragma unroll
      for (int c = 0; c < 4; ++c) {
        const int krow = c * 16 + fr;
#pragma unroll
        for (int dc = 0; dc < 4; ++dc) {
          int slot = (dc * 4 + hi) ^ (krow & 7);
          bf16x8 kf = *(const bf16x8*)(Kc + krow * 256 + slot * 16);
          sf[0][c] = MFMA_BF16(qf[0][dc], kf, sf[0][c]);
          sf[1][c] = MFMA_BF16(qf[1][dc], kf, sf[1][c]);
        }
      }
      if (s == sd) {
#pragma unroll
        for (int rr = 0; rr < 2; ++rr) {
          const int qgr = q0 + wid * 32 + rr * 16 + hi * 4;
#pragma unroll
          for (int c = 0; c < 4; ++c) {
            int kcol = s * 64 + c * 16 + fr;
#pragma unroll
            for (int r = 0; r < 4; ++r)
              sf[rr][c][r] = (kcol <= qgr + r)
                  ? __builtin_amdgcn_exp2f(sf[rr][c][r] - mr[rr][r]) * rl[rr][r] : 0.f;
          }
        }
      } else {
#pragma unroll
        for (int rr = 0; rr < 2; ++rr)
#pragma unroll
          for (int c = 0; c < 4; ++c)
#pragma unroll
            for (int r = 0; r < 4; ++r)
              sf[rr][c][r] = __builtin_amdgcn_exp2f(sf[rr][c][r] - mr[rr][r]) * rl[rr][r];
      }
#pragma unroll
      for (int rr = 0; rr < 2; ++rr)
#pragma unroll
        for (int c = 0; c < 4; ++c) {
          int col = c * 16 + fr;
          int sseg = col >> 3;
#pragma unroll
          for (int r = 0; r < 4; ++r) {
            int prow = rr * 16 + hi * 4 + r;
            int slot = sseg ^ ((hi * 4 + r) & 7);
            Pw[prow * 64 + slot * 8 + (col & 7)] = __float2bfloat16(sf[rr][c][r]);
          }
        }
      bf16x8 pf[2][2];
#pragma unroll
      for (int rr = 0; rr < 2; ++rr)
#pragma unroll
        for (int kc = 0; kc < 2; ++kc) {
          int slot = (kc * 4 + hi) ^ (fr & 7);
          pf[rr][kc] = *(const bf16x8*)(Pw + (rr * 16 + fr) * 64 + slot * 8);
        }
      const __hip_bfloat16* Vc = Vs[cur];
#pragma unroll
      for (int kc = 0; kc < 2; ++kc)
#pragma unroll
        for (int f = 0; f < 8; ++f) {
          int vrow = f * 16 + fr;
          int vslot = (kc * 4 + hi) ^ (fr & 7);
          bf16x8 vf = *(const bf16x8*)(Vc + vrow * 64 + vslot * 8);
          accO[0][f] = MFMA_BF16(pf[0][kc], vf, accO[0][f]);
          accO[1][f] = MFMA_BF16(pf[1][kc], vf, accO[1][f]);
        }
    }
    cur ^= 1;
  }

  const float m1 = *mix1p, m2 = *mix2p;
#pragma unroll
  for (int rr = 0; rr < 2; ++rr) {
    const size_t qb = (size_t)bh * 2048 + q0 + wid * 32 + rr * 16;
#pragma unroll
    for (int f = 0; f < 8; ++f) {
      int d = f * 16 + fr;
#pragma unroll
      for (int r = 0; r < 4; ++r) {
        int ql = hi * 4 + r;
        float y1v = __bfloat162float(y1n[(qb + ql) * 128 + d]);
        float yv = m1 * y1v + m2 * accO[rr][f][r];
        int q = q0 + wid * 32 + rr * 16 + ql;
        ymix[((size_t)b * 2048 + q) * 2048 + h * 128 + d] = __float2bfloat16(yv);
      }
    }
  }
}

// ---------------- launch ----------------
extern "C" void kernel_launch(void* const* d_in, const int* in_sizes, int n_in,
                              void* d_out, int out_size, void* d_ws, size_t ws_size,
                              hipStream_t stream) {
  const float* x    = (const float*)d_in[0];
  const float* cosb = (const float*)d_in[1];
  const float* sinb = (const float*)d_in[2];
  const float* Wq   = (const float*)d_in[3];
  const float* Wk   = (const float*)d_in[4];
  const float* Wv   = (const float*)d_in[5];
  const float* Wp   = (const float*)d_in[6];
  const float* mix1 = (const float*)d_in[7];
  const float* mix2 = (const float*)d_in[8];
  float* out = (float*)d_out;
  char* ws = (char*)d_ws;

  __hip_bfloat16* xb   = (__hip_bfloat16*)(ws + 0);           // 16.78 MB, reused as ymix
  __hip_bfloat16* WTa  = (__hip_bfloat16*)(ws + 16777216);    // 12.58 MB (3072x2048)
  __hip_bfloat16* WpT  = (__hip_bfloat16*)(ws + 29360128);    // 8.39 MB
  __hip_bfloat16* qkvb = (__hip_bfloat16*)(ws + 37748736);    // 25.2 MB (4096x3072 bf16)
  __hip_bfloat16* y1n  = (__hip_bfloat16*)(ws + 37748736);    // reuse qkv after rope/v-trans
  __hip_bfloat16* y1t  = (__hip_bfloat16*)(ws + 54525952);
  float*          Mb   = (float*)(ws + 71303168);
  float*          Lb   = (float*)(ws + 71565312);
  __hip_bfloat16* qTb  = (__hip_bfloat16*)(ws + 88080384);    // (B,H,T,HD)
  __hip_bfloat16* kTb  = (__hip_bfloat16*)(ws + 104857600);   // (B,HK,T,HD)
  __hip_bfloat16* vtb  = (__hip_bfloat16*)(ws + 109051904);   // (B,HK,HD,T)
  __hip_bfloat16* ymix = (__hip_bfloat16*)(ws + 0);

  dim3 tb(32, 8);
  cast_bf16_kernel<<<8192, 256, 0, stream>>>(x, xb, 2097152);
  wtrans_kernel<<<10240, tb, 0, stream>>>(Wq, Wk, Wv, Wp, WTa, WpT);

  gemm_bf16_kernel<__hip_bfloat16><<<768, 256, 0, stream>>>(xb, WTa, qkvb, 4096, 3072, 2048);

  rope_rms_kernel<<<20480, 256, 0, stream>>>(qkvb, cosb, sinb, qTb, kTb);
  vtrans_kernel<<<dim3(16, 64, 2), tb, 0, stream>>>(qkvb, vtb);

  attn_pass1_kernel<<<512, 256, 0, stream>>>(qTb, kTb, vtb, y1n, y1t, Mb, Lb);
  attn_pass2_kernel<<<512, 256, 0, stream>>>(qTb, kTb, y1t, y1n, Mb, Lb, mix1, mix2, ymix);

  gemm_bf16_kernel<float><<<512, 256, 0, stream>>>(ymix, WpT, out, 4096, 2048, 2048);
}

// Round 7
// 291.044 us; speedup vs baseline: 1.6420x; 1.0388x over previous
//
#include <hip/hip_runtime.h>
#include <hip/hip_bf16.h>
#include <cstdint>
#include <cstddef>

#define AS1 __attribute__((address_space(1)))
#define AS3 __attribute__((address_space(3)))

typedef __attribute__((ext_vector_type(8))) short bf16x8;
typedef __attribute__((ext_vector_type(4))) float f32x4;

__device__ __forceinline__ void gload_lds16(const void* g, void* l) {
  __builtin_amdgcn_global_load_lds((const AS1 void*)g, (AS3 void*)l, 16, 0, 0);
}

#define MFMA_BF16(A, B, C) __builtin_amdgcn_mfma_f32_16x16x32_bf16((A), (B), (C), 0, 0, 0)

// (1/sqrt(128)) * log2(e) — folded into q at rope time; softmax runs in exp2 domain.
#define QSCALE 0.12751744f

__device__ __forceinline__ uint32_t pk2(float a, float b) {
  uint32_t ua = (uint32_t)__builtin_bit_cast(unsigned short, __float2bfloat16(a));
  uint32_t ub = (uint32_t)__builtin_bit_cast(unsigned short, __float2bfloat16(b));
  return ua | (ub << 16);
}
__device__ __forceinline__ float b2f(unsigned short u) {
  return __builtin_bit_cast(float, (uint32_t)u << 16);
}

// ---------------- cast f32 -> bf16 ----------------
__global__ __launch_bounds__(256) void cast_bf16_kernel(const float* __restrict__ in,
                                                        __hip_bfloat16* __restrict__ out,
                                                        int n4) {
  int i = blockIdx.x * 256 + threadIdx.x;
  if (i < n4) {
    float4 v = ((const float4*)in)[i];
    __hip_bfloat16* o = out + (size_t)i * 4;
    o[0] = __float2bfloat16(v.x);
    o[1] = __float2bfloat16(v.y);
    o[2] = __float2bfloat16(v.z);
    o[3] = __float2bfloat16(v.w);
  }
}

// ---------------- merged weight transpose+cast (Wq,Wk,Wv,Wp in one launch) ----------------
__global__ __launch_bounds__(256) void wtrans_kernel(const float* __restrict__ Wq,
                                                     const float* __restrict__ Wk,
                                                     const float* __restrict__ Wv,
                                                     const float* __restrict__ Wp,
                                                     __hip_bfloat16* __restrict__ WTa,
                                                     __hip_bfloat16* __restrict__ WpT) {
  __shared__ float tile[32][33];
  int id = blockIdx.x;
  const float* in; __hip_bfloat16* out; int is, os, bx, by;
  if (id < 4096)      { in = Wq; out = WTa;                          is = 2048; os = 2048; bx = id & 63; by = id >> 6; }
  else if (id < 5120) { int t = id - 4096; in = Wk; out = WTa + (size_t)2048 * 2048; is = 512; os = 2048; bx = t & 15; by = t >> 4; }
  else if (id < 6144) { int t = id - 5120; in = Wv; out = WTa + (size_t)2560 * 2048; is = 512; os = 2048; bx = t & 15; by = t >> 4; }
  else                { int t = id - 6144; in = Wp; out = WpT;       is = 2048; os = 2048; bx = t & 63; by = t >> 6; }
  int c0 = bx * 32, r0 = by * 32;
  int tx = threadIdx.x, ty = threadIdx.y;
#pragma unroll
  for (int i = 0; i < 32; i += 8)
    tile[ty + i][tx] = in[(size_t)(r0 + ty + i) * is + c0 + tx];
  __syncthreads();
#pragma unroll
  for (int i = 0; i < 32; i += 8)
    out[(size_t)(c0 + ty + i) * os + r0 + tx] = __float2bfloat16(tile[tx][ty + i]);
}

// ---------------- v transpose (bf16 qkv -> (B,HK,HD,T)), both b in one launch ----------------
__global__ __launch_bounds__(256) void vtrans_kernel(const __hip_bfloat16* __restrict__ qkv,
                                                     __hip_bfloat16* __restrict__ vt) {
  __shared__ float tile[32][33];
  int b = blockIdx.z;
  const __hip_bfloat16* in = qkv + (size_t)b * 2048 * 3072 + 2560;
  __hip_bfloat16* out = vt + (size_t)b * 512 * 2048;
  int c0 = blockIdx.x * 32, r0 = blockIdx.y * 32;
  int tx = threadIdx.x, ty = threadIdx.y;
#pragma unroll
  for (int i = 0; i < 32; i += 8)
    tile[ty + i][tx] = __bfloat162float(in[(size_t)(r0 + ty + i) * 3072 + c0 + tx]);
  __syncthreads();
#pragma unroll
  for (int i = 0; i < 32; i += 8)
    out[(size_t)(c0 + ty + i) * 2048 + r0 + tx] = __float2bfloat16(tile[tx][ty + i]);
}

// ---------------- bf16 GEMM (m97 structure) + XCD swizzle; CT = float or bf16 ----------------
template <typename CT>
__global__ __launch_bounds__(256) void gemm_bf16_kernel(const __hip_bfloat16* __restrict__ A,
                                                        const __hip_bfloat16* __restrict__ Bt,
                                                        CT* __restrict__ C,
                                                        int M, int N, int K) {
  __shared__ __align__(16) __hip_bfloat16 As[128 * 32];
  __shared__ __align__(16) __hip_bfloat16 Bs[128 * 32];
  const int tid = threadIdx.x;
  const int lane = tid & 63;
  const int wid = tid >> 6;
  const int wm = wid >> 1, wn = wid & 1;
  const int nwg = gridDim.x;
  const int bid = blockIdx.x;
  const int swz = (bid & 7) * (nwg >> 3) + (bid >> 3);
  const int ntile = N >> 7;
  const int tm = swz / ntile, tn = swz % ntile;
  const int row0 = tm << 7, col0 = tn << 7;

  const int fr = lane & 15;
  const int kg = (lane >> 4) * 8;

  f32x4 acc[4][4] = {};

  for (int k0 = 0; k0 < K; k0 += 32) {
    __syncthreads();
#pragma unroll
    for (int i = 0; i < 2; ++i) {
      int f = i * 256 + tid;
      int r = f >> 2, s = f & 3;
      gload_lds16(A + (size_t)(row0 + r) * K + k0 + s * 8,
                  (char*)As + (i * 256 + wid * 64) * 16);
      gload_lds16(Bt + (size_t)(col0 + r) * K + k0 + s * 8,
                  (char*)Bs + (i * 256 + wid * 64) * 16);
    }
    __syncthreads();
    bf16x8 af[4], bfr[4];
#pragma unroll
    for (int m = 0; m < 4; ++m)
      af[m] = *(const bf16x8*)(As + (wm * 64 + m * 16 + fr) * 32 + kg);
#pragma unroll
    for (int n = 0; n < 4; ++n)
      bfr[n] = *(const bf16x8*)(Bs + (wn * 64 + n * 16 + fr) * 32 + kg);
#pragma unroll
    for (int m = 0; m < 4; ++m)
#pragma unroll
      for (int n = 0; n < 4; ++n)
        acc[m][n] = MFMA_BF16(af[m], bfr[n], acc[m][n]);
  }

  const int cr = (lane >> 4) * 4;
#pragma unroll
  for (int m = 0; m < 4; ++m)
#pragma unroll
    for (int n = 0; n < 4; ++n) {
      int col = col0 + wn * 64 + n * 16 + fr;
#pragma unroll
      for (int r = 0; r < 4; ++r) {
        int row = row0 + wm * 64 + m * 16 + cr + r;
        if constexpr (__is_same(CT, float))
          C[(size_t)row * N + col] = acc[m][n][r];
        else
          C[(size_t)row * N + col] = __float2bfloat16(acc[m][n][r]);
      }
    }
}

// ---------------- RoPE + RMS (bf16 qkv in); q gets QSCALE folded in ----------------
__global__ __launch_bounds__(256) void rope_rms_kernel(const __hip_bfloat16* __restrict__ qkv,
                                                       const float* __restrict__ cosb,
                                                       const float* __restrict__ sinb,
                                                       __hip_bfloat16* __restrict__ qT,
                                                       __hip_bfloat16* __restrict__ kT) {
  int lane = threadIdx.x & 63, wid = threadIdx.x >> 6;
  int task = blockIdx.x * 4 + wid;
  int bt = task / 20, j = task - bt * 20;
  int b = bt >> 11, t = bt & 2047;
  const __hip_bfloat16* src;
  __hip_bfloat16* dst;
  float oscale;
  if (j < 16) {
    src = qkv + (size_t)bt * 3072 + j * 128;
    dst = qT + ((size_t)(b * 16 + j) * 2048 + t) * 128;
    oscale = QSCALE;
  } else {
    src = qkv + (size_t)bt * 3072 + 2048 + (j - 16) * 128;
    dst = kT + ((size_t)(b * 4 + (j - 16)) * 2048 + t) * 128;
    oscale = 1.0f;
  }
  float x1 = __bfloat162float(src[lane]), x2 = __bfloat162float(src[lane + 64]);
  float c = cosb[t * 64 + lane], s = sinb[t * 64 + lane];
  float o1 = x1 * c - x2 * s;
  float o2 = x1 * s + x2 * c;
  float ss = o1 * o1 + o2 * o2;
#pragma unroll
  for (int off = 1; off < 64; off <<= 1) ss += __shfl_xor(ss, off);
  float rn = rsqrtf(ss * (1.f / 128.f) + 1e-6f) * oscale;
  dst[lane] = __float2bfloat16(o1 * rn);
  dst[lane + 64] = __float2bfloat16(o2 * rn);
}

// block decode (both passes): bi in [0,512): u=bi&255, half=bi>>8. g=u&7 = (b*4+kvh).
// bi and bi+256 (two halves of a balanced 34-step pair) land on the same CU under rr
// dispatch: per-CU balance at 2 blocks/CU.
//
// SWAPPED-QK layout: sf = mfma(K_frag, Q_frag) -> sf[rr][c][r] = S[q=rr*16+fr][k=c*16+hi*4+r].
// Per-lane row-reductions are in-lane (16 values) + shfl_xor(16/32).
// P stored to LDS as packed b64 (4 k-consecutive bf16), 16B-slot XOR swizzle by (row&7);
// read back as A-frags via ds_read_b128 (2-way conflicts only).

// ---------------- attention pass 1: y1 = softmax(qk^T) v ; writes u = mix1*v + mix2*y1 ----------------
__global__ __launch_bounds__(256, 2) void attn_pass1_kernel(
    const __hip_bfloat16* __restrict__ qT,   // (B,H,T,HD), q pre-scaled
    const __hip_bfloat16* __restrict__ kT,   // (B,HK,T,HD)
    const __hip_bfloat16* __restrict__ vt,   // (B,HK,HD,T)
    __hip_bfloat16* __restrict__ y1u,        // (B,H,HD,T)  u = mix1*v + mix2*y1
    float* __restrict__ Mb,                  // (B,H,T)  (exp2 domain)
    float* __restrict__ Lb,
    const float* __restrict__ mix1p,
    const float* __restrict__ mix2p) {
  __shared__ __align__(16) __hip_bfloat16 Ks[2][64 * 128];
  __shared__ __align__(16) __hip_bfloat16 Vs[2][128 * 64];
  __shared__ __align__(16) char Ps[4][32 * 128];
  const int tid = threadIdx.x, lane = tid & 63, wid = tid >> 6;   // wid 0..3
  const int bi = blockIdx.x;
  const int u = bi & 255, half = bi >> 8;
  const int g = u & 7;
  const int pslot = (u >> 3) & 7;
  const int bh = g * 4 + (u >> 6);
  const int j = half ? (15 - pslot) : pslot;
  const int q0 = j * 128;
  const int nt = 2 * j + 2;
  const int sd = 2 * j + (wid >> 1);         // wave's diagonal k-tile (rows wid*32..+31)
  const __hip_bfloat16* Kp = kT + (size_t)g * 2048 * 128;
  const __hip_bfloat16* Vp = vt + (size_t)g * 128 * 2048;
  const int fr = lane & 15, hi = lane >> 4;

  bf16x8 qf[2][4];
  {
    const __hip_bfloat16* Qp = qT + ((size_t)bh * 2048 + q0 + wid * 32) * 128;
#pragma unroll
    for (int rr = 0; rr < 2; ++rr)
#pragma unroll
      for (int dc = 0; dc < 4; ++dc)
        qf[rr][dc] = *(const bf16x8*)(Qp + (rr * 16 + fr) * 128 + dc * 32 + hi * 8);
  }

  f32x4 accO[2][8] = {};                     // accO[rr][f][r]: q=rr*16+hi*4+r, d=f*16+fr
  float m[2], l[2];                          // per q-row rr*16+fr (uniform across hi)
  m[0] = m[1] = -1e30f; l[0] = l[1] = 0.f;

  char* Pb = Ps[wid];

  auto STAGE = [&](int buf, int kt) {        // 8 global_load_lds (4 K + 4 V)
    const int k0 = kt * 64;
#pragma unroll
    for (int i = 0; i < 4; ++i) {
      int f = i * 256 + tid;
      int r = f >> 4, s = f & 15, sx = s ^ (r & 7);
      gload_lds16(Kp + (size_t)(k0 + r) * 128 + sx * 8,
                  (char*)Ks[buf] + (i * 256 + wid * 64) * 16);
    }
#pragma unroll
    for (int i = 0; i < 4; ++i) {
      int f = i * 256 + tid;
      int r = f >> 3, s = f & 7, sx = s ^ (r & 7);
      gload_lds16(Vp + (size_t)r * 2048 + k0 + sx * 8,
                  (char*)Vs[buf] + (i * 256 + wid * 64) * 16);
    }
  };

  STAGE(0, 0);
  int cur = 0;
  for (int s = 0; s < nt; ++s) {
    if (s > 0) __builtin_amdgcn_s_barrier();   // WAR: compute(s-1) closed
    __builtin_amdgcn_sched_barrier(0);
    if (s + 1 < nt) STAGE(cur ^ 1, s + 1);
    __builtin_amdgcn_sched_barrier(0);
    if (s + 1 < nt) asm volatile("s_waitcnt vmcnt(8)" ::: "memory");
    else            asm volatile("s_waitcnt vmcnt(0)" ::: "memory");
    __builtin_amdgcn_s_barrier();              // K(s),V(s) landed for all waves
    __builtin_amdgcn_sched_barrier(0);

    const bool active = (s <= sd);
    if (active) {
      // ---- QK (swapped): sf[rr][c][r] = S[q=rr*16+fr][k=c*16+hi*4+r] ----
      const char* Kc = (const char*)Ks[cur];
      f32x4 sf[2][4] = {};
#pragma unroll
      for (int c = 0; c < 4; ++c) {
        const int krow = c * 16 + fr;
#pragma unroll
        for (int dc = 0; dc < 4; ++dc) {
          int slot = (dc * 4 + hi) ^ (krow & 7);
          bf16x8 kf = *(const bf16x8*)(Kc + krow * 256 + slot * 16);
          sf[0][c] = MFMA_BF16(kf, qf[0][dc], sf[0][c]);
          sf[1][c] = MFMA_BF16(kf, qf[1][dc], sf[1][c]);
        }
      }
      // ---- mask (diagonal) + in-lane row max + cross-hi reduce ----
      float rmax[2];
#pragma unroll
      for (int rr = 0; rr < 2; ++rr) {
        if (s == sd) {
          const int qq = q0 + wid * 32 + rr * 16 + fr;
#pragma unroll
          for (int c = 0; c < 4; ++c) {
            const int kb = s * 64 + c * 16 + hi * 4;
#pragma unroll
            for (int r = 0; r < 4; ++r)
              if (kb + r > qq) sf[rr][c][r] = -1e30f;
          }
        }
        float v = -1e30f;
#pragma unroll
        for (int c = 0; c < 4; ++c)
#pragma unroll
          for (int r = 0; r < 4; ++r) v = fmaxf(v, sf[rr][c][r]);
        v = fmaxf(v, __shfl_xor(v, 16));
        v = fmaxf(v, __shfl_xor(v, 32));
        rmax[rr] = v;
      }
      // ---- T13 defer-max ----
      bool grow = (rmax[0] > m[0] + 8.f) | (rmax[1] > m[1] + 8.f);
      if (__any(grow)) {
        float a[2];
#pragma unroll
        for (int rr = 0; rr < 2; ++rr) {
          float mn = fmaxf(m[rr], rmax[rr]);
          a[rr] = __builtin_amdgcn_exp2f(m[rr] - mn);
          m[rr] = mn;
          l[rr] *= a[rr];
        }
#pragma unroll
        for (int rr = 0; rr < 2; ++rr)
#pragma unroll
          for (int r = 0; r < 4; ++r) {
            float aq = __shfl(a[rr], hi * 4 + r);   // a for q-row rr*16+hi*4+r
#pragma unroll
            for (int f = 0; f < 8; ++f) accO[rr][f][r] *= aq;
          }
      }
      // ---- exp2 + in-lane sum + cross-hi reduce ----
#pragma unroll
      for (int rr = 0; rr < 2; ++rr) {
        float rs = 0.f;
#pragma unroll
        for (int c = 0; c < 4; ++c)
#pragma unroll
          for (int r = 0; r < 4; ++r) {
            float p = __builtin_amdgcn_exp2f(sf[rr][c][r] - m[rr]);
            sf[rr][c][r] = p;
            rs += p;
          }
        rs += __shfl_xor(rs, 16);
        rs += __shfl_xor(rs, 32);
        l[rr] += rs;
      }
      // ---- P -> LDS: 8 packed b64 writes (swizzled 16B slots), read 4 b128 A-frags ----
#pragma unroll
      for (int rr = 0; rr < 2; ++rr) {
        const int row = rr * 16 + fr;
        char* Prow = Pb + row * 128;
#pragma unroll
        for (int c = 0; c < 4; ++c) {
          uint32_t w0 = pk2(sf[rr][c][0], sf[rr][c][1]);
          uint32_t w1 = pk2(sf[rr][c][2], sf[rr][c][3]);
          int sl = (c * 2 + (hi >> 1)) ^ (row & 7);
          *(uint2*)(Prow + sl * 16 + (hi & 1) * 8) = make_uint2(w0, w1);
        }
      }
      bf16x8 pf[2][2];
#pragma unroll
      for (int rr = 0; rr < 2; ++rr) {
        const int row = rr * 16 + fr;
#pragma unroll
        for (int kc = 0; kc < 2; ++kc) {
          int sl = (kc * 4 + hi) ^ (row & 7);
          pf[rr][kc] = *(const bf16x8*)(Pb + row * 128 + sl * 16);
        }
      }
      // ---- PV ----
      const __hip_bfloat16* Vc = Vs[cur];
#pragma unroll
      for (int kc = 0; kc < 2; ++kc)
#pragma unroll
        for (int f = 0; f < 8; ++f) {
          int vrow = f * 16 + fr;
          int vslot = (kc * 4 + hi) ^ (fr & 7);
          bf16x8 vf = *(const bf16x8*)(Vc + vrow * 64 + vslot * 8);
          accO[0][f] = MFMA_BF16(pf[0][kc], vf, accO[0][f]);
          accO[1][f] = MFMA_BF16(pf[1][kc], vf, accO[1][f]);
        }
    }
    cur ^= 1;
  }

  // ---- epilogue: u = mix1*v + mix2*(accO/l), d-major; store m,l ----
  const float m1v = mix1p[0], m2v = mix2p[0];
  float rlq[2][4];
#pragma unroll
  for (int rr = 0; rr < 2; ++rr) {
    float inv = 1.f / l[rr];
#pragma unroll
    for (int r = 0; r < 4; ++r) rlq[rr][r] = __shfl(inv, hi * 4 + r);
  }
  const int t0 = q0 + wid * 32;
#pragma unroll
  for (int rr = 0; rr < 2; ++rr) {
    const int tb = t0 + rr * 16 + hi * 4;
#pragma unroll
    for (int f = 0; f < 8; ++f) {
      const int d = f * 16 + fr;
      const ushort4 v4 = *(const ushort4*)(vt + ((size_t)g * 128 + d) * 2048 + tb);
      float u0 = m1v * b2f(v4.x) + m2v * (accO[rr][f][0] * rlq[rr][0]);
      float u1 = m1v * b2f(v4.y) + m2v * (accO[rr][f][1] * rlq[rr][1]);
      float u2 = m1v * b2f(v4.z) + m2v * (accO[rr][f][2] * rlq[rr][2]);
      float u3 = m1v * b2f(v4.w) + m2v * (accO[rr][f][3] * rlq[rr][3]);
      *(uint2*)(y1u + ((size_t)bh * 128 + d) * 2048 + tb) =
          make_uint2(pk2(u0, u1), pk2(u2, u3));
    }
  }
  if (hi == 0) {
#pragma unroll
    for (int rr = 0; rr < 2; ++rr) {
      Mb[(size_t)bh * 2048 + t0 + rr * 16 + fr] = m[rr];
      Lb[(size_t)bh * 2048 + t0 + rr * 16 + fr] = l[rr];
    }
  }
}

// ---------------- attention pass 2: ymix = att @ u  (direct final output) ----------------
__global__ __launch_bounds__(256, 2) void attn_pass2_kernel(
    const __hip_bfloat16* __restrict__ qT,
    const __hip_bfloat16* __restrict__ kT,
    const __hip_bfloat16* __restrict__ y1u,  // (B,H,HD,T)
    const float* __restrict__ Mb,
    const float* __restrict__ Lb,
    __hip_bfloat16* __restrict__ ymix) {     // (B,T,C)
  __shared__ __align__(16) __hip_bfloat16 Ks[2][64 * 128];
  __shared__ __align__(16) __hip_bfloat16 Vs[2][128 * 64];
  __shared__ __align__(16) char Ps[4][32 * 128];
  const int tid = threadIdx.x, lane = tid & 63, wid = tid >> 6;
  const int bi = blockIdx.x;
  const int u = bi & 255, half = bi >> 8;
  const int g = u & 7;
  const int pslot = (u >> 3) & 7;
  const int bh = g * 4 + (u >> 6);
  const int h = bh & 15, b = bh >> 4;
  const int j = half ? (15 - pslot) : pslot;
  const int q0 = j * 128;
  const int nt = 2 * j + 2;
  const int sd = 2 * j + (wid >> 1);
  const __hip_bfloat16* Kp = kT + (size_t)g * 2048 * 128;
  const __hip_bfloat16* Yp = y1u + (size_t)bh * 128 * 2048;
  const int fr = lane & 15, hi = lane >> 4;

  bf16x8 qf[2][4];
  float mr[2], rl[2];
  {
    const __hip_bfloat16* Qp = qT + ((size_t)bh * 2048 + q0 + wid * 32) * 128;
#pragma unroll
    for (int rr = 0; rr < 2; ++rr)
#pragma unroll
      for (int dc = 0; dc < 4; ++dc)
        qf[rr][dc] = *(const bf16x8*)(Qp + (rr * 16 + fr) * 128 + dc * 32 + hi * 8);
    const size_t qb = (size_t)bh * 2048 + q0 + wid * 32;
    mr[0] = Mb[qb + fr];        mr[1] = Mb[qb + 16 + fr];
    rl[0] = 1.f / Lb[qb + fr];  rl[1] = 1.f / Lb[qb + 16 + fr];
  }

  f32x4 accO[2][8] = {};
  char* Pb = Ps[wid];

  auto STAGE = [&](int buf, int kt) {
    const int k0 = kt * 64;
#pragma unroll
    for (int i = 0; i < 4; ++i) {
      int f = i * 256 + tid;
      int r = f >> 4, s = f & 15, sx = s ^ (r & 7);
      gload_lds16(Kp + (size_t)(k0 + r) * 128 + sx * 8,
                  (char*)Ks[buf] + (i * 256 + wid * 64) * 16);
    }
#pragma unroll
    for (int i = 0; i < 4; ++i) {
      int f = i * 256 + tid;
      int r = f >> 3, s = f & 7, sx = s ^ (r & 7);
      gload_lds16(Yp + (size_t)r * 2048 + k0 + sx * 8,
                  (char*)Vs[buf] + (i * 256 + wid * 64) * 16);
    }
  };

  STAGE(0, 0);
  int cur = 0;
  for (int s = 0; s < nt; ++s) {
    if (s > 0) __builtin_amdgcn_s_barrier();
    __builtin_amdgcn_sched_barrier(0);
    if (s + 1 < nt) STAGE(cur ^ 1, s + 1);
    __builtin_amdgcn_sched_barrier(0);
    if (s + 1 < nt) asm volatile("s_waitcnt vmcnt(8)" ::: "memory");
    else            asm volatile("s_waitcnt vmcnt(0)" ::: "memory");
    __builtin_amdgcn_s_barrier();
    __builtin_amdgcn_sched_barrier(0);

    const bool active = (s <= sd);
    if (active) {
      const char* Kc = (const char*)Ks[cur];
      f32x4 sf[2][4] = {};
#pragma unroll
      for (int c = 0; c < 4; ++c) {
        const int krow = c * 16 + fr;
#pragma unroll
        for (int dc = 0; dc < 4; ++dc) {
          int slot = (dc * 4 + hi) ^ (krow & 7);
          bf16x8 kf = *(const bf16x8*)(Kc + krow * 256 + slot * 16);
          sf[0][c] = MFMA_BF16(kf, qf[0][dc], sf[0][c]);
          sf[1][c] = MFMA_BF16(kf, qf[1][dc], sf[1][c]);
        }
      }
      // normalize P directly from stored stats (all fr-indexed, no shuffles)
#pragma unroll
      for (int rr = 0; rr < 2; ++rr) {
        if (s == sd) {
          const int qq = q0 + wid * 32 + rr * 16 + fr;
#pragma unroll
          for (int c = 0; c < 4; ++c) {
            const int kb = s * 64 + c * 16 + hi * 4;
#pragma unroll
            for (int r = 0; r < 4; ++r)
              if (kb + r > qq) sf[rr][c][r] = -1e30f;
          }
        }
#pragma unroll
        for (int c = 0; c < 4; ++c)
#pragma unroll
          for (int r = 0; r < 4; ++r)
            sf[rr][c][r] = __builtin_amdgcn_exp2f(sf[rr][c][r] - mr[rr]) * rl[rr];
      }
#pragma unroll
      for (int rr = 0; rr < 2; ++rr) {
        const int row = rr * 16 + fr;
        char* Prow = Pb + row * 128;
#pragma unroll
        for (int c = 0; c < 4; ++c) {
          uint32_t w0 = pk2(sf[rr][c][0], sf[rr][c][1]);
          uint32_t w1 = pk2(sf[rr][c][2], sf[rr][c][3]);
          int sl = (c * 2 + (hi >> 1)) ^ (row & 7);
          *(uint2*)(Prow + sl * 16 + (hi & 1) * 8) = make_uint2(w0, w1);
        }
      }
      bf16x8 pf[2][2];
#pragma unroll
      for (int rr = 0; rr < 2; ++rr) {
        const int row = rr * 16 + fr;
#pragma unroll
        for (int kc = 0; kc < 2; ++kc) {
          int sl = (kc * 4 + hi) ^ (row & 7);
          pf[rr][kc] = *(const bf16x8*)(Pb + row * 128 + sl * 16);
        }
      }
      const __hip_bfloat16* Vc = Vs[cur];
#pragma unroll
      for (int kc = 0; kc < 2; ++kc)
#pragma unroll
        for (int f = 0; f < 8; ++f) {
          int vrow = f * 16 + fr;
          int vslot = (kc * 4 + hi) ^ (fr & 7);
          bf16x8 vf = *(const bf16x8*)(Vc + vrow * 64 + vslot * 8);
          accO[0][f] = MFMA_BF16(pf[0][kc], vf, accO[0][f]);
          accO[1][f] = MFMA_BF16(pf[1][kc], vf, accO[1][f]);
        }
    }
    cur ^= 1;
  }

  // accO already IS the final mixed output (P pre-normalized, u pre-mixed)
#pragma unroll
  for (int rr = 0; rr < 2; ++rr) {
#pragma unroll
    for (int f = 0; f < 8; ++f) {
      const int d = f * 16 + fr;
#pragma unroll
      for (int r = 0; r < 4; ++r) {
        int q = q0 + wid * 32 + rr * 16 + hi * 4 + r;
        ymix[((size_t)b * 2048 + q) * 2048 + h * 128 + d] = __float2bfloat16(accO[rr][f][r]);
      }
    }
  }
}

// ---------------- launch ----------------
extern "C" void kernel_launch(void* const* d_in, const int* in_sizes, int n_in,
                              void* d_out, int out_size, void* d_ws, size_t ws_size,
                              hipStream_t stream) {
  const float* x    = (const float*)d_in[0];
  const float* cosb = (const float*)d_in[1];
  const float* sinb = (const float*)d_in[2];
  const float* Wq   = (const float*)d_in[3];
  const float* Wk   = (const float*)d_in[4];
  const float* Wv   = (const float*)d_in[5];
  const float* Wp   = (const float*)d_in[6];
  const float* mix1 = (const float*)d_in[7];
  const float* mix2 = (const float*)d_in[8];
  float* out = (float*)d_out;
  char* ws = (char*)d_ws;

  // workspace layout (bytes), peak ~105.4 MB
  __hip_bfloat16* xb   = (__hip_bfloat16*)(ws + 0);            // 16.78 MB; reused as ymix
  __hip_bfloat16* WTa  = (__hip_bfloat16*)(ws + 16777216);     // 12.58 MB
  __hip_bfloat16* WpT  = (__hip_bfloat16*)(ws + 29360128);     // 8.39 MB
  __hip_bfloat16* qkvb = (__hip_bfloat16*)(ws + 37748736);     // 25.17 MB (ends 62.91M)
  __hip_bfloat16* y1u  = (__hip_bfloat16*)(ws + 62914560);     // 16.78 MB
  float*          Mb   = (float*)(ws + 79691776);              // 0.26 MB
  float*          Lb   = (float*)(ws + 79953920);              // 0.26 MB
  __hip_bfloat16* qTb  = (__hip_bfloat16*)(ws + 80216064);     // 16.78 MB
  __hip_bfloat16* kTb  = (__hip_bfloat16*)(ws + 96993280);     // 4.19 MB
  __hip_bfloat16* vtb  = (__hip_bfloat16*)(ws + 101187584);    // 4.19 MB
  __hip_bfloat16* ymix = (__hip_bfloat16*)(ws + 0);

  dim3 tb(32, 8);
  cast_bf16_kernel<<<8192, 256, 0, stream>>>(x, xb, 2097152);
  wtrans_kernel<<<10240, tb, 0, stream>>>(Wq, Wk, Wv, Wp, WTa, WpT);

  gemm_bf16_kernel<__hip_bfloat16><<<768, 256, 0, stream>>>(xb, WTa, qkvb, 4096, 3072, 2048);

  rope_rms_kernel<<<20480, 256, 0, stream>>>(qkvb, cosb, sinb, qTb, kTb);
  vtrans_kernel<<<dim3(16, 64, 2), tb, 0, stream>>>(qkvb, vtb);

  attn_pass1_kernel<<<512, 256, 0, stream>>>(qTb, kTb, vtb, y1u, Mb, Lb, mix1, mix2);
  attn_pass2_kernel<<<512, 256, 0, stream>>>(qTb, kTb, y1u, Mb, Lb, ymix);

  gemm_bf16_kernel<float><<<512, 256, 0, stream>>>(ymix, WpT, out, 4096, 2048, 2048);
}